// Round 9
// baseline (941.767 us; speedup 1.0000x reference)
//
#include <hip/hip_runtime.h>
#include <cstddef>

#define DEV __device__ __forceinline__
DEV float lrelu(float x){ return x >= 0.0f ? x : 0.2f*x; }
typedef _Float16 f16;
typedef _Float16 f16x8 __attribute__((ext_vector_type(8)));
typedef float f32x4 __attribute__((ext_vector_type(4)));

DEV f16x8 splat8(f16 s){ f16x8 v = {s,s,s,s,s,s,s,s}; return v; }
// packed BN + lrelu in f16: lrelu(v*sc+sh) with exact max/min formulation
DEV f16x8 bnl8(f16x8 v, f16x8 sc, f16x8 sh){
    f16x8 t = v*sc + sh;                       // v_pk_fma_f16
    f16x8 z = splat8((f16)0.0f);
    f16x8 mx = __builtin_elementwise_max(t, z);
    f16x8 mn = __builtin_elementwise_min(t, z);
    return mx + mn*splat8((f16)0.2f);
}

// async global->LDS, 16B per lane (raw staging, no VGPR roundtrip)
DEV void gload_lds16(const f16* src, f16* dst){
    __builtin_amdgcn_global_load_lds(
        (const __attribute__((address_space(1))) void*)src,
        (__attribute__((address_space(3))) void*)dst, 16, 0, 0);
}

// stage a 128x32 tile half-pair: slots t (rows 0..63) and 256+t (rows 64..127).
DEV void dma_pair(const f16* g0, const f16* g1, f16* ldsbase, int t){
    gload_lds16(g0, ldsbase + t*8);
    gload_lds16(g1, ldsbase + 2048 + t*8);
}
// reader-side swizzled f16 index for (row r, k-granule g)
DEV int swz_off(int r, int g){ return r*32 + ((g ^ ((r>>1)&3))<<3); }

#define SCHED0 __builtin_amdgcn_sched_barrier(0)
#define BARRIER __builtin_amdgcn_s_barrier()

// Problem dims: B=512, IN=512, CB=8, HD=256, CH=2048, CC=2560, EXP=128, FC1=1024, OUT=512
constexpr int NXPT = 512*512;     // dense support points (b,l<512)

// ---------------- workspace layout (float offsets) ----------------
constexpr size_t O_H1  = 0;                       // 512x1024 f32
constexpr size_t O_H2  = O_H1 + 512*1024;         // 512x1024 f32
constexpr size_t O_L   = O_H2 + 512*1024;         // 512x2048 f32 (c3 logits; dead after k_sel)
constexpr size_t O_SEL = O_L  + 512*2048;         // int32 512x256
constexpr size_t O_S   = O_SEL + 512*256;
constexpr size_t O_S2  = O_S + 512;
constexpr size_t O_VAL = O_S2 + 512;
constexpr size_t O_PRM = O_VAL + 512;
// params sub-offsets (within PRM)
constexpr size_t P_SC1=0, P_SH1=1024, P_SC2=2048, P_SH2=3072, P_SC3=4096, P_SH3=6144;
constexpr size_t P_A1=8192, P_C1=8224, P_EW2T=8256 /*2048*/;
constexpr size_t P_ACC2=18496 /*128*/, P_ACC3=18624 /*256*/;
constexpr size_t P_SCE2=18880, P_SHE2=18944, P_SCE3=19008, P_SHE3=19136;
constexpr size_t P_U0=19264 /*128*/, P_FTOT=19392 /*1024*/;
constexpr size_t P_SCF1=20416, P_SHF1=21440;
constexpr size_t P_SCD1=22464, P_SHD1=22528, P_SCD2=22592, P_SHD2=22624;
// f16 copies of BN affine params (for packed-f16 MFMA staging)
constexpr size_t P_SCE3H=22656, P_SHE3H=22720;    // 128 f16 each (64 floats)
constexpr size_t P_SCF1H=22784, P_SHF1H=23296;    // 1024 f16 each (512 floats)
constexpr size_t P_SCE2H=23808, P_SHE2H=23840;    // 64 f16 each (32 floats)
constexpr size_t PRM_SIZE = 32768;
// stats partial buffers (all alias dead regions)
constexpr size_t O_PF  = O_H1;                    // fw1 stats partials: 4096 x 256 f32 (H1+H2)
constexpr size_t O_PD1 = O_H2;                    // d1 stats partials: 2048 x 128 f32 (after pF dead)
constexpr size_t O_PD2 = O_H2 + 262144;           // d2 stats partials: 4096 x 64 f32
// weight copies + V2s ALIAS the dead L buffer (written after k_sel)
constexpr size_t O_FW1H = O_L;                    // f16 1024x512   (262144 floats)
constexpr size_t O_FW2H = O_L + 262144;           // f16 512x1024   (262144 floats)
constexpr size_t O_ACCF = O_L + 524288;           // f32 2048 (legacy zero region)
constexpr size_t O_DW1H = O_L + 528384;           // f16 64x128  (4096 floats)
constexpr size_t O_EW3H = O_L + 532480;           // f16 128x64  (4096 floats)
constexpr size_t O_V2SS = O_L + 536576;           // f32 513x64  (32832 floats)
constexpr size_t O_U1  = O_PRM + PRM_SIZE;        // 512x128 f32
constexpr size_t O_P1  = O_U1 + 512*128;          // 512x1024 f32; ALSO stats2d partials (before k_p1)
constexpr size_t O_FZT = O_P1 + 512*1024;         // 2048x1024 f32 (fW1 z-part T); pE3 aliases after k_p1
constexpr size_t O_V3S = O_FZT + (size_t)2048*1024;   // 513x128 f32
constexpr size_t O_BIG1= O_V3S + 513*128;             // f16 512*128*512  (V3xT; d1p aliases after fw1)
constexpr size_t O_BIG2= O_BIG1 + (size_t)512*512*128/2; // f16 512*128*1024 (out6T); V2x aliases
constexpr size_t O_D1  = O_BIG1;                      // f16 512*64*512 (aliases V3xT, dead after fw1)
constexpr size_t O_D2  = O_BIG2 + (size_t)512*64*512; // f32 512*32*512
constexpr size_t O_END = O_BIG2 + (size_t)512*1024*128/2;   // ~211 MB

#define FMA44(av,bv) do{ \
  acc[0][0]=fmaf(av.x,bv.x,acc[0][0]); acc[0][1]=fmaf(av.x,bv.y,acc[0][1]); \
  acc[0][2]=fmaf(av.x,bv.z,acc[0][2]); acc[0][3]=fmaf(av.x,bv.w,acc[0][3]); \
  acc[1][0]=fmaf(av.y,bv.x,acc[1][0]); acc[1][1]=fmaf(av.y,bv.y,acc[1][1]); \
  acc[1][2]=fmaf(av.y,bv.z,acc[1][2]); acc[1][3]=fmaf(av.y,bv.w,acc[1][3]); \
  acc[2][0]=fmaf(av.z,bv.x,acc[2][0]); acc[2][1]=fmaf(av.z,bv.y,acc[2][1]); \
  acc[2][2]=fmaf(av.z,bv.z,acc[2][2]); acc[2][3]=fmaf(av.z,bv.w,acc[2][3]); \
  acc[3][0]=fmaf(av.w,bv.x,acc[3][0]); acc[3][1]=fmaf(av.w,bv.y,acc[3][1]); \
  acc[3][2]=fmaf(av.w,bv.z,acc[3][2]); acc[3][3]=fmaf(av.w,bv.w,acc[3][3]); \
}while(0)

__global__ void k_sentinel(float* out){ out[blockIdx.x*256 + threadIdx.x] = 1.0e6f; }

// prep: f16 weight copies, zero legacy accumulators. Runs AFTER k_sel (aliases L).
__global__ __launch_bounds__(256) void k_prep(
    const float* __restrict__ fW1, const float* __restrict__ fW2,
    const float* __restrict__ dW1, const float* __restrict__ eW3,
    f16* __restrict__ fW1h, f16* __restrict__ fW2h, f16* __restrict__ dW1h,
    f16* __restrict__ eW3h, float* __restrict__ accAll)
{
    const int i = blockIdx.x*256 + threadIdx.x;   // 524288 threads
    int f = i >> 9, l = i & 511;
    fW1h[i] = (f16)fW1[(size_t)f*2560 + l];       // x-part only (cols 0..511)
    fW2h[i] = (f16)fW2[i];
    if (i < 8192) { dW1h[i] = (f16)dW1[i]; eW3h[i] = (f16)eW3[i]; }
    if (i < 4096) accAll[i] = 0.f;
}

// ---------------- c-layers (NT, fp32: feeds argmax) ----------------
__global__ __launch_bounds__(256) void k_gemm_c(
    const float* __restrict__ A, const float* __restrict__ W, float* __restrict__ C,
    int N, int K, const float* __restrict__ sc, const float* __restrict__ sh)
{
    __shared__ __align__(16) float As[16][68];
    __shared__ __align__(16) float Ws[16][68];
    const int n0 = blockIdx.x * 64, m0 = blockIdx.y * 64;
    const int t = threadIdx.x;
    const int kk = t & 15, ri = t >> 4;
    const int tx = t & 15, ty = t >> 4;
    float acc[4][4] = {{0.f,0.f,0.f,0.f},{0.f,0.f,0.f,0.f},{0.f,0.f,0.f,0.f},{0.f,0.f,0.f,0.f}};
    for (int k0 = 0; k0 < K; k0 += 16) {
        float scv = 0.f, shv = 0.f;
        if (sc) { scv = sc[k0+kk]; shv = sh[k0+kk]; }
        #pragma unroll
        for (int mm = 0; mm < 4; ++mm) {
            float v = A[(size_t)(m0 + ri + mm*16) * K + k0 + kk];
            if (sc) v = lrelu(fmaf(v, scv, shv));
            As[kk][ri + mm*16] = v;
        }
        #pragma unroll
        for (int nn = 0; nn < 4; ++nn)
            Ws[kk][ri + nn*16] = W[(size_t)(n0 + ri + nn*16) * K + k0 + kk];
        __syncthreads();
        #pragma unroll
        for (int kq = 0; kq < 16; ++kq) {
            const float4 av = *reinterpret_cast<const float4*>(&As[kq][ty*4]);
            const float4 bv = *reinterpret_cast<const float4*>(&Ws[kq][tx*4]);
            FMA44(av, bv);
        }
        __syncthreads();
    }
    #pragma unroll
    for (int i = 0; i < 4; ++i)
        #pragma unroll
        for (int j = 0; j < 4; ++j)
            C[(size_t)(m0 + ty*4 + i) * N + n0 + tx*4 + j] = acc[i][j];
}

// coalesced column-stats partials for f32 buf[512][C]
__global__ __launch_bounds__(256) void k_stats2d_p(
    const float* __restrict__ buf, int C, float* __restrict__ part)
{
    const int t = threadIdx.x;
    const int r0 = blockIdx.x*16;
    const int c0 = blockIdx.y*1024;
    float s[4]={0.f,0.f,0.f,0.f}, s2[4]={0.f,0.f,0.f,0.f};
    for (int rr = 0; rr < 16; ++rr) {
        float4 v = *reinterpret_cast<const float4*>(buf + (size_t)(r0+rr)*C + c0 + t*4);
        s[0]+=v.x; s[1]+=v.y; s[2]+=v.z; s[3]+=v.w;
        s2[0]+=v.x*v.x; s2[1]+=v.y*v.y; s2[2]+=v.z*v.z; s2[3]+=v.w*v.w;
    }
    float* d0 = part + (size_t)blockIdx.x*2*C + c0 + t*4;
    *reinterpret_cast<float4*>(d0)     = (float4){s[0],s[1],s[2],s[3]};
    *reinterpret_cast<float4*>(d0 + C) = (float4){s2[0],s2[1],s2[2],s2[3]};
}

__global__ __launch_bounds__(256) void k_sel(
    const float* __restrict__ Lpre, const float* __restrict__ gumbel,
    const float* __restrict__ sc, const float* __restrict__ sh, int* __restrict__ sel)
{
    const int b = blockIdx.x, hd = threadIdx.x;
    float best = -3.0e38f; int bi = 0;
    #pragma unroll
    for (int cb = 0; cb < 8; ++cb) {
        int c = cb*256 + hd;
        float v = lrelu(fmaf(Lpre[(size_t)b*2048 + c], sc[c], sh[c])) + gumbel[(size_t)b*2048 + c];
        if (v > best) { best = v; bi = cb; }
    }
    sel[b*256 + hd] = bi;
}

__global__ __launch_bounds__(256) void k_val(const float* __restrict__ x,
    float* __restrict__ S, float* __restrict__ S2, float* __restrict__ val)
{
    const int b = blockIdx.x, t = threadIdx.x;
    float v0 = x[b*512 + t], v1 = x[b*512 + t + 256];
    __shared__ float ls[256], ls2[256];
    ls[t] = v0 + v1; ls2[t] = v0*v0 + v1*v1;
    __syncthreads();
    for (int off = 128; off; off >>= 1) { if (t < off) { ls[t]+=ls[t+off]; ls2[t]+=ls2[t+off]; } __syncthreads(); }
    if (t == 0) { float s = ls[0], s2 = ls2[0]; S[b]=s; S2[b]=s2; val[b]=0.5f*(s*s - s2); }
}

__global__ __launch_bounds__(256) void k_e1params(
    const float* __restrict__ S, const float* __restrict__ S2, const float* __restrict__ val,
    const float* __restrict__ eW1, const float* __restrict__ eg1, const float* __restrict__ eb1,
    float* __restrict__ A1, float* __restrict__ C1, float* __restrict__ accs /*384*/)
{
    const int t = threadIdx.x;
    accs[t] = 0.f; if (t < 128) accs[256 + t] = 0.f;
    __shared__ float ls[256], ls2[256];
    float s = 0.f, s2 = 0.f;
    for (int b = t; b < 512; b += 256) {
        float vb = val[b];
        s  += S[b]  + 256.f*vb;
        s2 += S2[b] + 256.f*vb*vb;
    }
    ls[t] = s; ls2[t] = s2; __syncthreads();
    for (int off = 128; off; off >>= 1) { if (t < off) { ls[t]+=ls[t+off]; ls2[t]+=ls2[t+off]; } __syncthreads(); }
    if (t < 32) {
        const float invn = 1.0f/1310720.f;
        float mu = ls[0]*invn;
        float var = fmaxf(ls2[0]*invn - mu*mu, 0.f);
        float w = eW1[t];
        float rs = 1.0f / sqrtf(w*w*var + 1e-5f);
        float a = w * eg1[t] * rs;
        A1[t] = a; C1[t] = eb1[t] - mu*a;
    }
}

// transpose eW2 (64x32)->(32x64)
__global__ void k_wtrans2(const float* __restrict__ eW2, float* __restrict__ eW2T)
{
    const int t = threadIdx.x;
    for (int i = t; i < 2048; i += 256) { int p = i >> 5, o = i & 31; eW2T[o*64 + p] = eW2[i]; }
}

__global__ __launch_bounds__(256) void k_transpose_fz(const float* __restrict__ fW1, float* __restrict__ fzT)
{
    __shared__ float tile[64][65];
    const int z0 = blockIdx.x*64, f0 = blockIdx.y*64;
    const int j = threadIdx.x & 63, i0 = threadIdx.x >> 6;
    #pragma unroll
    for (int ii = 0; ii < 16; ++ii) {
        int fi = i0*16 + ii;
        tile[fi][j] = fW1[(size_t)(f0+fi)*2560 + 512 + z0 + j];
    }
    __syncthreads();
    #pragma unroll
    for (int ii = 0; ii < 16; ++ii) {
        int zi = i0*16 + ii;
        fzT[(size_t)(z0+zi)*1024 + f0 + j] = tile[j][zi];
    }
}

__global__ __launch_bounds__(256) void k_ftot(const float* __restrict__ fzT, float* __restrict__ Ftot)
{
    const int f = blockIdx.x*256 + threadIdx.x;
    float s = 0.f;
    for (int z = 0; z < 2048; ++z) s += fzT[(size_t)z*1024 + f];
    Ftot[f] = s;
}

__global__ __launch_bounds__(256) void k_p1(const float* __restrict__ fzT, const int* __restrict__ sel,
                                            float* __restrict__ P1)
{
    const int b = blockIdx.x, t = threadIdx.x;
    float a0=0.f, a1=0.f, a2=0.f, a3=0.f;
    for (int hd = 0; hd < 256; ++hd) {
        int col = sel[b*256 + hd]*256 + hd;
        const float* r = fzT + (size_t)col*1024;
        a0 += r[t]; a1 += r[t+256]; a2 += r[t+512]; a3 += r[t+768];
    }
    P1[b*1024 + t] = a0; P1[b*1024 + t + 256] = a1; P1[b*1024 + t + 512] = a2; P1[b*1024 + t + 768] = a3;
}

// e2 main points: v2 = eW2 * lrelu(A1*x+C1); write V2x[pt][d] f16. NO stats.
__global__ __launch_bounds__(256) void k_epass2(
    const float* __restrict__ x,
    const float* __restrict__ A1, const float* __restrict__ C1,
    const float* __restrict__ eW2T, f16* __restrict__ V2x)
{
    __shared__ float sW[2048], sA[32], sC[32];
    const int t = threadIdx.x;
    #pragma unroll
    for (int i = 0; i < 8; ++i) sW[t + 256*i] = eW2T[t + 256*i];
    if (t < 32) { sA[t] = A1[t]; sC[t] = C1[t]; }
    __syncthreads();
    const int pt = blockIdx.x*256 + t;
    float phi = x[pt];
    float v2[64];
    #pragma unroll
    for (int p = 0; p < 64; ++p) v2[p] = 0.f;
    for (int o = 0; o < 32; ++o) {
        float t1 = lrelu(fmaf(sA[o], phi, sC[o]));
        #pragma unroll
        for (int p = 0; p < 64; ++p) v2[p] = fmaf(sW[o*64 + p], t1, v2[p]);
    }
    f16* dst = V2x + (size_t)pt*64;
    #pragma unroll
    for (int dd = 0; dd < 64; dd += 8) {
        f16x8 o;
        #pragma unroll
        for (int e = 0; e < 8; ++e) o[e] = (f16)v2[dd+e];
        *reinterpret_cast<f16x8*>(dst + dd) = o;
    }
}

// e2 support points
__global__ __launch_bounds__(64) void k_esupport2(
    const float* __restrict__ val,
    const float* __restrict__ A1, const float* __restrict__ C1,
    const float* __restrict__ eW2T, float* __restrict__ V2s)
{
    const int idx = blockIdx.x, d = threadIdx.x;
    float phi = (idx < 512) ? val[idx] : 0.f;
    __shared__ float t1s[32];
    if (d < 32) t1s[d] = lrelu(fmaf(A1[d], phi, C1[d]));
    __syncthreads();
    float s = 0.f;
    #pragma unroll
    for (int o = 0; o < 32; ++o) s = fmaf(eW2T[o*64 + d], t1s[o], s);
    V2s[idx*64 + d] = s;
}

// weighted column stats over V[513][C]: grid C blocks x 64 threads; 2 atomics/block
__global__ __launch_bounds__(64) void k_wstats(
    const float* __restrict__ V, int C, float* __restrict__ acc)
{
    const int c = blockIdx.x, lane = threadIdx.x;
    float s = 0.f, s2 = 0.f;
    for (int i = lane; i < 513; i += 64) {
        float w = (i < 512) ? 256.f : 917504.f;
        float v = V[(size_t)i*C + c];
        s += w*v; s2 += w*v*v;
    }
    #pragma unroll
    for (int off = 32; off; off >>= 1) { s += __shfl_xor(s, off); s2 += __shfl_xor(s2, off); }
    if (lane == 0) { atomicAdd(&acc[c], s); atomicAdd(&acc[C + c], s2); }
}

// e2 stats scan over V2x (262144 pts x 64 ch, f16). 64 blocks; 128 atomics/block.
__global__ __launch_bounds__(256) void k_stats_v2scan(const f16* __restrict__ V2x, float* __restrict__ acc2)
{
    const int t = threadIdx.x;
    const int wave = t >> 6, lane = t & 63;
    const int g = t & 7;
    const int slot = blockIdx.x*32 + (t >> 3);
    float s[8] = {0,0,0,0,0,0,0,0}, s2[8] = {0,0,0,0,0,0,0,0};
    for (int p = slot; p < NXPT; p += 2048) {
        f16x8 v = *reinterpret_cast<const f16x8*>(V2x + (size_t)p*64 + g*8);
        #pragma unroll
        for (int e = 0; e < 8; ++e) { float f = (float)v[e]; s[e] += f; s2[e] += f*f; }
    }
    #pragma unroll
    for (int off = 8; off <= 32; off <<= 1) {
        #pragma unroll
        for (int e = 0; e < 8; ++e) { s[e] += __shfl_xor(s[e], off); s2[e] += __shfl_xor(s2[e], off); }
    }
    __shared__ float red[4*128];
    if (lane < 8) {
        #pragma unroll
        for (int e = 0; e < 8; ++e) {
            red[wave*128 + lane*16 + e]     = s[e];
            red[wave*128 + lane*16 + 8 + e] = s2[e];
        }
    }
    __syncthreads();
    if (t < 128) {
        float v = red[t] + red[128 + t] + red[256 + t] + red[384 + t];
        int gg = t >> 4, k = t & 15;
        if (k < 8) atomicAdd(&acc2[gg*8 + k], v);
        else       atomicAdd(&acc2[64 + gg*8 + (k - 8)], v);
    }
}

__global__ void k_finalize(const float* __restrict__ acc, int C, float invn,
                           const float* __restrict__ g, const float* __restrict__ bb,
                           float* __restrict__ sc, float* __restrict__ sh,
                           f16* __restrict__ sch, f16* __restrict__ shh)
{
    const int idx = blockIdx.x*blockDim.x + threadIdx.x;
    if (idx < C) {
        float m = acc[idx] * invn;
        float var = fmaxf(acc[C + idx] * invn - m*m, 0.f);
        float r = 1.0f / sqrtf(var + 1e-5f);
        float s = g[idx] * r;
        float h = bb[idx] - m*s;
        sc[idx] = s; sh[idx] = h;
        if (sch) { sch[idx] = (f16)s; shh[idx] = (f16)h; }
    }
}

// finalize from contention-free partials: P = [nPart][2C] rows
__global__ void k_finalize_p(const float* __restrict__ P, int C, int nPart, float invn,
                             const float* __restrict__ g, const float* __restrict__ bb,
                             float* __restrict__ sc, float* __restrict__ sh,
                             f16* __restrict__ sch, f16* __restrict__ shh)
{
    const int idx = blockIdx.x*blockDim.x + threadIdx.x;
    if (idx < C) {
        float s = 0.f, s2 = 0.f;
        for (int p = 0; p < nPart; ++p) {
            s  += P[(size_t)p*2*C + idx];
            s2 += P[(size_t)p*2*C + C + idx];
        }
        float m = s * invn;
        float var = fmaxf(s2 * invn - m*m, 0.f);
        float r = 1.0f / sqrtf(var + 1e-5f);
        float sv = g[idx] * r;
        float h = bb[idx] - m*sv;
        sc[idx] = sv; sh[idx] = h;
        if (sch) { sch[idx] = (f16)sv; shh[idx] = (f16)h; }
    }
}

// finalize e3 BN: sum pE3 [2048][256] partials + wstats row accw[256]
__global__ __launch_bounds__(256) void k_finalize_e3(
    const float* __restrict__ P, const float* __restrict__ accw,
    const float* __restrict__ g, const float* __restrict__ bb,
    float* __restrict__ sc, float* __restrict__ sh,
    f16* __restrict__ sch, f16* __restrict__ shh)
{
    const int t = threadIdx.x, q = t & 127, h = t >> 7;
    float s = 0.f, s2 = 0.f;
    for (int p = h*1024; p < h*1024 + 1024; ++p) {
        s  += P[(size_t)p*256 + q];
        s2 += P[(size_t)p*256 + 128 + q];
    }
    __shared__ float red[2][2][128];
    red[h][0][q] = s; red[h][1][q] = s2;
    __syncthreads();
    if (t < 128) {
        float ss  = red[0][0][q] + red[1][0][q] + accw[q];
        float ss2 = red[0][1][q] + red[1][1][q] + accw[128 + q];
        const float invn = 1.0f/1310720.f;
        float m = ss * invn;
        float var = fmaxf(ss2 * invn - m*m, 0.f);
        float r = 1.0f / sqrtf(var + 1e-5f);
        float sv = g[q] * r, hh = bb[q] - m*sv;
        sc[q] = sv; sh[q] = hh; sch[q] = (f16)sv; shh[q] = (f16)hh;
    }
}

// finalize f-BN from pF [8 fblk][512 b][256]
__global__ __launch_bounds__(256) void k_finalize_f(
    const float* __restrict__ P,
    const float* __restrict__ g, const float* __restrict__ bb,
    float* __restrict__ sc, float* __restrict__ sh,
    f16* __restrict__ sch, f16* __restrict__ shh)
{
    const int f = blockIdx.x*256 + threadIdx.x;
    const int fb = f >> 7, c = f & 127;
    const float* base = P + (size_t)fb*512*256 + c;
    float s = 0.f, s2 = 0.f;
    for (int b = 0; b < 512; ++b) {
        s  += base[(size_t)b*256];
        s2 += base[(size_t)b*256 + 128];
    }
    float m = s*(1.0f/65536.f);
    float var = fmaxf(s2*(1.0f/65536.f) - m*m, 0.f);
    float r = 1.0f/sqrtf(var + 1e-5f);
    float sv = g[f]*r, h = bb[f] - m*sv;
    sc[f] = sv; sh[f] = h; sch[f] = (f16)sv; shh[f] = (f16)h;
}

// finalize d1-BN from pD1 [2048][128]
__global__ __launch_bounds__(256) void k_finalize_d1(
    const float* __restrict__ P,
    const float* __restrict__ g, const float* __restrict__ bb,
    float* __restrict__ sc, float* __restrict__ sh)
{
    const int t = threadIdx.x, d = t & 63, gr = t >> 6;  // 4 groups x 512 rows
    float s = 0.f, s2 = 0.f;
    for (int p = gr*512; p < gr*512 + 512; ++p) {
        s  += P[(size_t)p*128 + d];
        s2 += P[(size_t)p*128 + 64 + d];
    }
    __shared__ float red[4][2][64];
    red[gr][0][d] = s; red[gr][1][d] = s2;
    __syncthreads();
    if (t < 64) {
        float ss  = red[0][0][t]+red[1][0][t]+red[2][0][t]+red[3][0][t];
        float ss2 = red[0][1][t]+red[1][1][t]+red[2][1][t]+red[3][1][t];
        float m = ss*(1.0f/262144.f);
        float var = fmaxf(ss2*(1.0f/262144.f) - m*m, 0.f);
        float r = 1.0f/sqrtf(var + 1e-5f);
        float sv = g[t]*r;
        sc[t] = sv; sh[t] = bb[t] - m*sv;
    }
}

// finalize d2-BN from pD2 [4096][64] rows ([32 sums][32 sumsq])
__global__ __launch_bounds__(256) void k_finalize_d2(
    const float* __restrict__ P,
    const float* __restrict__ g, const float* __restrict__ bb,
    float* __restrict__ sc, float* __restrict__ sh)
{
    const int t = threadIdx.x, e = t & 31, gr = t >> 5;  // 8 groups x 512 rows
    float s = 0.f, s2 = 0.f;
    for (int p = gr*512; p < gr*512 + 512; ++p) {
        s  += P[(size_t)p*64 + e];
        s2 += P[(size_t)p*64 + 32 + e];
    }
    __shared__ float red[8][2][32];
    red[gr][0][e] = s; red[gr][1][e] = s2;
    __syncthreads();
    if (t < 32) {
        float ss = 0.f, ss2 = 0.f;
        #pragma unroll
        for (int k2 = 0; k2 < 8; ++k2) { ss += red[k2][0][t]; ss2 += red[k2][1][t]; }
        float m = ss*(1.0f/262144.f);
        float var = fmaxf(ss2*(1.0f/262144.f) - m*m, 0.f);
        float r = 1.0f/sqrtf(var + 1e-5f);
        float sv = g[t]*r;
        sc[t] = sv; sh[t] = bb[t] - m*sv;
    }
}

// MFMA e3 + fused V3xT stats partials; packed-f16 BN on V2x (sc2h/sh2h f16)
__global__ __launch_bounds__(256) void k_mfma_e3(
    const f16* __restrict__ eW3h, const f16* __restrict__ V2x,
    const f16* __restrict__ sc2h, const f16* __restrict__ sh2h,
    f16* __restrict__ V3xT, float* __restrict__ pE3)
{
    __shared__ __align__(16) f16 As[128][76];   // eW3 rows q, cols d
    __shared__ __align__(16) f16 Bs[128][76];   // t2 rows point, cols d
    __shared__ float rede[256];
    const int b = blockIdx.y, l0 = blockIdx.x * 128;
    const int t = threadIdx.x;
    const int wave = t >> 6, lane = t & 63;
    const int quad = lane >> 4, l16 = lane & 15;
    const int row = t >> 1, half = t & 1;
    #pragma unroll
    for (int c = 0; c < 4; ++c)
        *reinterpret_cast<f16x8*>(&As[row][half*32 + c*8]) =
            *reinterpret_cast<const f16x8*>(eW3h + row*64 + half*32 + c*8);
    const f16* src = V2x + ((size_t)(b*512 + l0 + row))*64 + half*32;
    #pragma unroll
    for (int c = 0; c < 4; ++c) {
        f16x8 v = *reinterpret_cast<const f16x8*>(src + c*8);
        const f16x8 csc = *reinterpret_cast<const f16x8*>(sc2h + half*32 + c*8);
        const f16x8 csh = *reinterpret_cast<const f16x8*>(sh2h + half*32 + c*8);
        *reinterpret_cast<f16x8*>(&Bs[row][half*32 + c*8]) = bnl8(v, csc, csh);
    }
    __syncthreads();
    f32x4 acc[2][8];
    #pragma unroll
    for (int i = 0; i < 2; ++i)
        #pragma unroll
        for (int j = 0; j < 8; ++j) acc[i][j] = (f32x4){0.f,0.f,0.f,0.f};
    f16x8 a0  = *reinterpret_cast<const f16x8*>(&As[32*wave + l16][quad*8]);
    f16x8 a0b = *reinterpret_cast<const f16x8*>(&As[32*wave + l16][32 + quad*8]);
    f16x8 a1  = *reinterpret_cast<const f16x8*>(&As[32*wave + 16 + l16][quad*8]);
    f16x8 a1b = *reinterpret_cast<const f16x8*>(&As[32*wave + 16 + l16][32 + quad*8]);
    #pragma unroll
    for (int j = 0; j < 8; ++j) {
        f16x8 bj  = *reinterpret_cast<const f16x8*>(&Bs[16*j + l16][quad*8]);
        f16x8 bjb = *reinterpret_cast<const f16x8*>(&Bs[16*j + l16][32 + quad*8]);
        acc[0][j] = __builtin_amdgcn_mfma_f32_16x16x32_f16(a0,  bj,  acc[0][j], 0, 0, 0);
        acc[0][j] = __builtin_amdgcn_mfma_f32_16x16x32_f16(a0b, bjb, acc[0][j], 0, 0, 0);
        acc[1][j] = __builtin_amdgcn_mfma_f32_16x16x32_f16(a1,  bj,  acc[1][j], 0, 0, 0);
        acc[1][j] = __builtin_amdgcn_mfma_f32_16x16x32_f16(a1b, bjb, acc[1][j], 0, 0, 0);
    }
    float se[8] = {0,0,0,0,0,0,0,0}, s2e[8] = {0,0,0,0,0,0,0,0};
    #pragma unroll
    for (int i = 0; i < 2; ++i) {
        #pragma unroll
        for (int r = 0; r < 4; ++r) {
            int q = 32*wave + 16*i + quad*4 + r;
            #pragma unroll
            for (int j = 0; j < 8; ++j) {
                float v = acc[i][j][r];
                V3xT[((size_t)b*128 + q)*512 + l0 + 16*j + l16] = (f16)v;
                se[i*4+r] += v; s2e[i*4+r] += v*v;
            }
        }
    }
    #pragma unroll
    for (int k = 0; k < 8; ++k) {
        se[k]  += __shfl_xor(se[k],1);  se[k]  += __shfl_xor(se[k],2);
        se[k]  += __shfl_xor(se[k],4);  se[k]  += __shfl_xor(se[k],8);
        s2e[k] += __shfl_xor(s2e[k],1); s2e[k] += __shfl_xor(s2e[k],2);
        s2e[k] += __shfl_xor(s2e[k],4); s2e[k] += __shfl_xor(s2e[k],8);
    }
    if (l16 == 0) {
        #pragma unroll
        for (int i = 0; i < 2; ++i)
            #pragma unroll
            for (int r = 0; r < 4; ++r) {
                int qq = 32*wave + 16*i + quad*4 + r;
                rede[qq] = se[i*4+r];
            }
    }
    __syncthreads();
    if (t < 128) pE3[((size_t)(blockIdx.x*512 + b))*256 + t] = rede[t];
    __syncthreads();
    if (l16 == 0) {
        #pragma unroll
        for (int i = 0; i < 2; ++i)
            #pragma unroll
            for (int r = 0; r < 4; ++r) {
                int qq = 32*wave + 16*i + quad*4 + r;
                rede[qq] = s2e[i*4+r];
            }
    }
    __syncthreads();
    if (t < 128) pE3[((size_t)(blockIdx.x*512 + b))*256 + 128 + t] = rede[t];
}

// e3 support points
__global__ __launch_bounds__(128) void k_esupport3(
    const float* __restrict__ V2s, const float* __restrict__ sc2, const float* __restrict__ sh2,
    const float* __restrict__ eW3, float* __restrict__ V3s)
{
    const int idx = blockIdx.x, q = threadIdx.x;
    __shared__ float t2s[64];
    if (q < 64) t2s[q] = lrelu(fmaf(sc2[q], V2s[idx*64 + q], sh2[q]));
    __syncthreads();
    float s = 0.f;
    #pragma unroll
    for (int d = 0; d < 64; ++d) s = fmaf(eW3[q*64 + d], t2s[d], s);
    V3s[idx*128 + q] = s;
}

__global__ void k_u(const float* __restrict__ V3s, const float* __restrict__ sc3, const float* __restrict__ sh3,
                    float* __restrict__ u1, float* __restrict__ u0)
{
    const int idx = blockIdx.x*256 + threadIdx.x;
    if (idx < 513*128) {
        int i = idx >> 7, q = idx & 127;
        float tv = lrelu(fmaf(sc3[q], V3s[idx], sh3[q]));
        if (i < 512) u1[idx] = tv; else u0[q] = tv;
    }
}

// ---------------- MFMA fw1 (pipeline + fused out6T stats; hoisted epilogue loads) ----------------
__global__ __launch_bounds__(256) void k_mfma_fw1T(
    const f16* __restrict__ fW1h, const f16* __restrict__ V3xT,
    const f16* __restrict__ sceh, const f16* __restrict__ sheh,
    const float* __restrict__ u1, const float* __restrict__ u0,
    const float* __restrict__ P1, const float* __restrict__ Ftot,
    f16* __restrict__ out6T, float* __restrict__ pF)
{
    __shared__ __align__(16) f16 lds[24576];    // 3 sets x (A 4096 + B 4096) f16
    __shared__ float redf[1024];
    const int t = threadIdx.x;
    const int wave = t >> 6, lane = t & 63;
    const int quad = lane >> 4, l16 = lane & 15;
    const int n = blockIdx.x + (blockIdx.y << 3);
    const int b = (n & 7)*64 + (n >> 6);
    const int fblk = (n >> 3) & 7;
    const int f0 = fblk * 128;
    const f16* Aa = V3xT + (size_t)b*65536;
    const f16* Bb = fW1h + (size_t)f0*512;
    const int sg = (t & 3) ^ ((t >> 3) & 3);
    const size_t go0 = (size_t)(t >> 2)*512 + sg*8;
    const size_t go1 = go0 + (size_t)64*512;
    const int rA0 = 32*wave + l16, rA1 = rA0 + 16;
    const f16x8 scA0 = splat8(sceh[rA0]), shA0 = splat8(sheh[rA0]);
    const f16x8 scA1 = splat8(sceh[rA1]), shA1 = splat8(sheh[rA1]);
    const int offA0 = swz_off(rA0, quad);
    const int offA1 = swz_off(rA1, quad);
    int offB[8];
    #pragma unroll
    for (int j = 0; j < 8; ++j) offB[j] = swz_off(16*j + l16, quad);
    // hoisted epilogue operands: latency hides under the whole k-loop
    float p1j[8], p0j[8], u1q[8], u0q[8];
    #pragma unroll
    for (int j = 0; j < 8; ++j) {
        int f = f0 + 16*j + l16;
        p1j[j] = P1[b*1024 + f];
        p0j[j] = Ftot[f] - p1j[j];
    }
    #pragma unroll
    for (int i = 0; i < 2; ++i)
        #pragma unroll
        for (int r = 0; r < 4; ++r) {
            int q = 32*wave + 16*i + quad*4 + r;
            u1q[i*4+r] = u1[b*128 + q];
            u0q[i*4+r] = u0[q];
        }
    f32x4 acc[2][8];
    #pragma unroll
    for (int i = 0; i < 2; ++i)
        #pragma unroll
        for (int j = 0; j < 8; ++j) acc[i][j] = (f32x4){0.f,0.f,0.f,0.f};
    dma_pair(Aa + go0,      Aa + go1,      lds,               t);
    dma_pair(Bb + go0,      Bb + go1,      lds + 4096,        t);
    dma_pair(Aa + 32 + go0, Aa + 32 + go1, lds + 8192,        t);
    dma_pair(Bb + 32 + go0, Bb + 32 + go1, lds + 8192 + 4096, t);
    int m = 0;
    for (int kt = 0; kt < 16; ++kt) {
        SCHED0; BARRIER; SCHED0;
        if (kt <= 13) {
            const int mp = (m >= 1) ? m - 1 : m + 2;
            const int k0 = (kt + 2) * 32;
            dma_pair(Aa + k0 + go0, Aa + k0 + go1, lds + mp*8192,        t);
            dma_pair(Bb + k0 + go0, Bb + k0 + go1, lds + mp*8192 + 4096, t);
            asm volatile("s_waitcnt vmcnt(8)" ::: "memory");
        } else if (kt == 14) {
            asm volatile("s_waitcnt vmcnt(4)" ::: "memory");
        } else {
            asm volatile("s_waitcnt vmcnt(0)" ::: "memory");
        }
        SCHED0; BARRIER; SCHED0;
        const f16* As = lds + m*8192;
        const f16* Bs = As + 4096;
        f16x8 a0 = bnl8(*reinterpret_cast<const f16x8*>(As + offA0), scA0, shA0);
        f16x8 a1 = bnl8(*reinterpret_cast<const f16x8*>(As + offA1), scA1, shA1);
        #pragma unroll
        for (int j = 0; j < 8; ++j) {
            f16x8 bj = *reinterpret_cast<const f16x8*>(Bs + offB[j]);
            acc[0][j] = __builtin_amdgcn_mfma_f32_16x16x32_f16(a0, bj, acc[0][j], 0, 0, 0);
            acc[1][j] = __builtin_amdgcn_mfma_f32_16x16x32_f16(a1, bj, acc[1][j], 0, 0, 0);
        }
        m = (m == 2) ? 0 : m + 1;
    }
    float sj[8], s2j[8];
    #pragma unroll
    for (int j = 0; j < 8; ++j) { sj[j] = 0.f; s2j[j] = 0.f; }
    #pragma unroll
    for (int i = 0; i < 2; ++i) {
        #pragma unroll
        for (int r = 0; r < 4; ++r) {
            int q = 32*wave + 16*i + quad*4 + r;
            #pragma unroll
            for (int j = 0; j < 8; ++j) {
                int f = f0 + 16*j + l16;
                float v = acc[i][j][r] + u1q[i*4+r]*p1j[j] + u0q[i*4+r]*p0j[j];
                out6T[((size_t)b*128 + q)*1024 + f] = (f16)v;
                sj[j] += v; s2j[j] += v*v;
            }
        }
    }
    #pragma unroll
    for (int j = 0; j < 8; ++j) {
        sj[j]  += __shfl_xor(sj[j],16);  sj[j]  += __shfl_xor(sj[j],32);
        s2j[j] += __shfl_xor(s2j[j],16); s2j[j] += __shfl_xor(s2j[j],32);
    }
    if (quad == 0) {
        #pragma unroll
        for (int j = 0; j < 8; ++j) {
            redf[wave*256 + j*16 + l16]       = sj[j];
            redf[wave*256 + 128 + j*16 + l16] = s2j[j];
        }
    }
    __syncthreads();
    {
        float v = redf[t] + redf[256 + t] + redf[512 + t] + redf[768 + t];
        pF[((size_t)(fblk*512 + b))*256 + t] = v;
    }
}

// ---- MFMA fw2 (pipeline + in-place LDS BN) FUSED WITH d1 (out7 never hits HBM) ----
// d1p[b][d][o] = sum_q dW1[d][q] * out7[b][o][q]; K=q=128 fully inside each block.
__global__ __launch_bounds__(256) void k_mfma_fw2T(
    const f16* __restrict__ fW2h, const f16* __restrict__ out6T,
    const f16* __restrict__ scfh, const f16* __restrict__ shfh,
    const float* __restrict__ fbias2, const f16* __restrict__ dW1h,
    f16* __restrict__ d1pre, float* __restrict__ pD1)
{
    __shared__ __align__(16) f16 lds[24576];
    __shared__ __align__(16) f16 scL[1024];
    __shared__ __align__(16) f16 shL[1024];
    const int t = threadIdx.x;
    const int wave = t >> 6, lane = t & 63;
    const int quad = lane >> 4, l16 = lane & 15;
    const int n = blockIdx.x + (blockIdx.y << 2);
    const int b = (n & 7)*64 + (n >> 5);
    const int o0 = ((n >> 3) & 3) * 128;
    const f16* Aa = fW2h + (size_t)o0*1024;
    const f16* Bb = out6T + (size_t)b*131072;
    const int sg = (t & 3) ^ ((t >> 3) & 3);
    const size_t go0 = (size_t)(t >> 2)*1024 + sg*8;
    const size_t go1 = go0 + (size_t)64*1024;
    const int bnO = sg*8;
    const int offA0 = swz_off(32*wave + l16, quad);
    const int offA1 = swz_off(32*wave + 16 + l16, quad);
    int offB[8];
    #pragma unroll
    for (int j = 0; j < 8; ++j) offB[j] = swz_off(16*j + l16, quad);
    // hoisted bias loads
    float biasv[8];
    #pragma unroll
    for (int i = 0; i < 2; ++i)
        #pragma unroll
        for (int r = 0; r < 4; ++r)
            biasv[i*4+r] = fbias2[o0 + 32*wave + 16*i + quad*4 + r];
    f32x4 acc[2][8];
    #pragma unroll
    for (int i = 0; i < 2; ++i)
        #pragma unroll
        for (int j = 0; j < 8; ++j) acc[i][j] = (f32x4){0.f,0.f,0.f,0.f};
    if (t < 128) *reinterpret_cast<f16x8*>(&scL[t*8]) =
        *reinterpret_cast<const f16x8*>(scfh + t*8);
    else         *reinterpret_cast<f16x8*>(&shL[(t-128)*8]) =
        *reinterpret_cast<const f16x8*>(shfh + (t-128)*8);
    __syncthreads();
    dma_pair(Aa + go0,      Aa + go1,      lds,               t);
    dma_pair(Bb + go0,      Bb + go1,      lds + 4096,        t);
    dma_pair(Aa + 32 + go0, Aa + 32 + go1, lds + 8192,        t);
    dma_pair(Bb + 32 + go0, Bb + 32 + go1, lds + 8192 + 4096, t);
    int m = 0;
    for (int kt = 0; kt < 32; ++kt) {
        SCHED0; BARRIER; SCHED0;
        if (kt <= 29) {
            const int mp = (m >= 1) ? m - 1 : m + 2;
            const int k0 = (kt + 2) * 32;
            dma_pair(Aa + k0 + go0, Aa + k0 + go1, lds + mp*8192,        t);
            dma_pair(Bb + k0 + go0, Bb + k0 + go1, lds + mp*8192 + 4096, t);
            asm volatile("s_waitcnt vmcnt(8)" ::: "memory");
        } else if (kt == 30) {
            asm volatile("s_waitcnt vmcnt(4)" ::: "memory");
        } else {
            asm volatile("s_waitcnt vmcnt(0)" ::: "memory");
        }
        SCHED0; BARRIER; SCHED0;
        {
            f16* Bm = lds + m*8192 + 4096;
            const f16x8 csc = *reinterpret_cast<const f16x8*>(&scL[kt*32 + bnO]);
            const f16x8 csh = *reinterpret_cast<const f16x8*>(&shL[kt*32 + bnO]);
            f16x8 v0 = *reinterpret_cast<const f16x8*>(Bm + t*8);
            f16x8 v1 = *reinterpret_cast<const f16x8*>(Bm + 2048 + t*8);
            *reinterpret_cast<f16x8*>(Bm + t*8)        = bnl8(v0, csc, csh);
            *reinterpret_cast<f16x8*>(Bm + 2048 + t*8) = bnl8(v1, csc, csh);
        }
        asm volatile("s_waitcnt lgkmcnt(0)" ::: "memory");
        SCHED0; BARRIER; SCHED0;
        const f16* As = lds + m*8192;
        const f16* Bs = As + 4096;
        f16x8 a0 = *reinterpret_cast<const f16x8*>(As + offA0);
        f16x8 a1 = *reinterpret_cast<const f16x8*>(As + offA1);
        #pragma unroll
        for (int j = 0; j < 8; ++j) {
            f16x8 bj = *reinterpret_cast<const f16x8*>(Bs + offB[j]);
            acc[0][j] = __builtin_amdgcn_mfma_f32_16x16x32_f16(a0, bj, acc[0][j], 0, 0, 0);
            acc[1][j] = __builtin_amdgcn_mfma_f32_16x16x32_f16(a1, bj, acc[1][j], 0, 0, 0);
        }
        m = (m == 2) ? 0 : m + 1;
    }
    // ---- fused d1: out7 tile -> LDS (f16, stride 136), then d1p = dW1 x out7^T ----
    __syncthreads();                       // all k-loop LDS reads complete
    f16* ot = lds;                         // 128 x 136 f16 = 34816 B (fits in 49KB)
    float* redp = (float*)(lds + 128*136); // 4 waves x 128 floats = 2KB (disjoint)
    #pragma unroll
    for (int i = 0; i < 2; ++i) {
        #pragma unroll
        for (int r = 0; r < 4; ++r) {
            int ob = 32*wave + 16*i + quad*4 + r;
            #pragma unroll
            for (int j = 0; j < 8; ++j)
                ot[ob*136 + 16*j + l16] = (f16)(acc[i][j][r] + biasv[i*4+r]);
        }
    }
    __syncthreads();                       // out7 tile visible
    f32x4 dacc[4][2];
    #pragma unroll
    for (int dt = 0; dt < 4; ++dt)
        #pragma unroll
        for (int u = 0; u < 2; ++u) dacc[dt][u] = (f32x4){0.f,0.f,0.f,0.f};
    #pragma unroll
    for (int kq = 0; kq < 4; ++kq) {
        f16x8 bfr[2];
        #pragma unroll
        for (int u = 0; u < 2; ++u) {
            int ob = (2*wave + u)*16 + l16;
            bfr[u] = *reinterpret_cast<const f16x8*>(ot + ob*136 + kq*32 + quad*8);
        }
        #pragma unroll
        for (int dt = 0; dt < 4; ++dt) {
            f16x8 afr = *reinterpret_cast<const f16x8*>(dW1h + (dt*16 + l16)*128 + kq*32 + quad*8);
            #pragma unroll
            for (int u = 0; u < 2; ++u)
                dacc[dt][u] = __builtin_amdgcn_mfma_f32_16x16x32_f16(afr, bfr[u], dacc[dt][u], 0, 0, 0);
        }
    }
    // write d1pre (f16) + per-block stats partials
    float sd = 0.f, s2d = 0.f;             // accumulated per (dt,quad,ri) below
    float sdv[16], s2dv[16];
    #pragma unroll
    for (int dt = 0; dt < 4; ++dt) {
        #pragma unroll
        for (int ri = 0; ri < 4; ++ri) {
            int d = dt*16 + quad*4 + ri;
            float vs = 0.f, v2s = 0.f;
            #pragma unroll
            for (int u = 0; u < 2; ++u) {
                int o = o0 + (2*wave + u)*16 + l16;
                float v = dacc[dt][u][ri];
                d1pre[(size_t)b*32768 + (size_t)d*512 + o] = (f16)v;
                vs += v; v2s += v*v;
            }
            vs  += __shfl_xor(vs,1);  vs  += __shfl_xor(vs,2);
            vs  += __shfl_xor(vs,4);  vs  += __shfl_xor(vs,8);
            v2s += __shfl_xor(v2s,1); v2s += __shfl_xor(v2s,2);
            v2s += __shfl_xor(v2s,4); v2s += __shfl_xor(v2s,8);
            sdv[dt*4+ri] = vs; s2dv[dt*4+ri] = v2s;
        }
    }
    (void)sd; (void)s2d;
    if (l16 == 0) {
        #pragma unroll
        for (int dt = 0; dt < 4; ++dt)
            #pragma unroll
            for (int ri = 0; ri < 4; ++ri) {
                int d = dt*16 + quad*4 + ri;
                redp[wave*128 + d]      = sdv[dt*4+ri];
                redp[wave*128 + 64 + d] = s2dv[dt*4+ri];
            }
    }
    __syncthreads();
    if (t < 128) {
        float v = redp[t] + redp[128 + t] + redp[256 + t] + redp[384 + t];
        pD1[(size_t)n*128 + t] = v;
    }
}

// d2: C[e,o] = sum_d dW2[e,d] * lrelu(sc*d1pre[b][d][o]+sh)  (d1pre f16) + fused stats
__global__ __launch_bounds__(128) void k_gemm_d2(
    const float* __restrict__ dW2, const f16* __restrict__ d1pre,
    const float* __restrict__ scd, const float* __restrict__ shd,
    float* __restrict__ d2pre, float* __restrict__ pD2)
{
    __shared__ __align__(16) float As[16][36];
    __shared__ __align__(16) float Bs[16][68];
    __shared__ float sred[64];
    const int n0 = blockIdx.x * 64, b = blockIdx.y;
    const int t = threadIdx.x;
    const int kk = t & 15, ri = t >> 4;
    const int qv = t & 63, kh = t >> 6;
    const int tx = t & 15, ty = t >> 4;
    float acc[4][4] = {{0.f,0.f,0.f,0.f},{0.f,0.f,0.f,0.f},{0.f,0.f,0.f,0.f},{0.f,0.f,0.f,0.f}};
    for (int k0 = 0; k0 < 64; k0 += 16) {
        #pragma unroll
        for (int mm = 0; mm < 4; ++mm)
            As[kk][ri + mm*8] = dW2[(ri + mm*8)*64 + k0 + kk];
        #pragma unroll
        for (int ki = 0; ki < 8; ++ki) {
            int d = k0 + kh + ki*2;
            float v = (float)d1pre[(size_t)b*32768 + (size_t)d*512 + n0 + qv];
            Bs[kh + ki*2][qv] = lrelu(fmaf(scd[d], v, shd[d]));
        }
        __syncthreads();
        #pragma unroll
        for (int kq = 0; kq < 16; ++kq) {
            const float4 av = *reinterpret_cast<const float4*>(&As[kq][ty*4]);
            const float4 bv = *reinterpret_cast<const float4*>(&Bs[kq][tx*4]);
            FMA44(av, bv);
        }
        __syncthreads();
    }
    #pragma unroll
    for (int i = 0; i < 4; ++i) {
        float s = 0.f, s2 = 0.f;
        #pragma unroll
        for (int j = 0; j < 4; ++j) {
            float v = acc[i][j];
            d2pre[(size_t)b*16384 + (size_t)(ty*4 + i)*512 + n0 + tx*4 + j] = v;
            s += v; s2 += v*v;
        }
        s  += __shfl_xor(s,1);  s  += __shfl_xor(s,2);
        s  += __shfl_xor(s,4);  s  += __shfl_xor(s,8);
        s2 += __shfl_xor(s2,1); s2 += __shfl_xor(s2,2);
        s2 += __shfl_xor(s2,4); s2 += __shfl_xor(s2,8);
        if (tx == 0) {
            int e = ty*4 + i;
            sred[e] = s; sred[32 + e] = s2;
        }
    }
    __syncthreads();
    if (t < 64) pD2[((size_t)(blockIdx.y*8 + blockIdx.x))*64 + t] = sred[t];
}

__global__ __launch_bounds__(256) void k_d3(
    const float* __restrict__ d2pre, const float* __restrict__ dW3,
    const float* __restrict__ sce, const float* __restrict__ she,
    const float* __restrict__ dbias3, float* __restrict__ out)
{
    const int idx = blockIdx.x*256 + threadIdx.x;
    const int b = idx >> 9, o = idx & 511;
    float s = dbias3[0];
    for (int e = 0; e < 32; ++e) {
        float v = d2pre[(size_t)b*16384 + e*512 + o];
        s = fmaf(dW3[e], lrelu(fmaf(v, sce[e], she[e])), s);
    }
    out[idx] = s;
}

extern "C" void kernel_launch(void* const* d_in, const int* in_sizes, int n_in,
                              void* d_out, int out_size, void* d_ws, size_t ws_size,
                              hipStream_t stream)
{
    (void)in_sizes; (void)n_in; (void)out_size;
    const float* x      = (const float*)d_in[0];
    const float* gumbel = (const float*)d_in[1];
    const float* cW1 = (const float*)d_in[2];
    const float* cg1 = (const float*)d_in[3];
    const float* cb1 = (const float*)d_in[4];
    const float* cW2 = (const float*)d_in[5];
    const float* cg2 = (const float*)d_in[6];
    const float* cb2 = (const float*)d_in[7];
    const float* cW3 = (const float*)d_in[8];
    const float* cg3 = (const float*)d_in[9];
    const float* cb3 = (const float*)d_in[10];
    const float* eW1 = (const float*)d_in[11];
    const float* eg1 = (const float*)d_in[12];
    const float* eb1 = (const float*)d_in[13];
    const float* eW2 = (const float*)d_in[14];
    const float* eg2 = (const float*)d_in[15];
    const float* eb2 = (const float*)d_in[16];
    const float* eW3 = (const float*)d_in[17];
    const float* eg3 = (const float*)d_in[18];
    const float* eb3 = (const float*)d_in[19];
    const float* fW1 = (const float*)d_in[20];
    const float* fg1 = (const float*)d_in[21];
    const float* fb1 = (const float*)d_in[22];
    const float* fW2 = (const float*)d_in[23];
    const float* fbias2 = (const float*)d_in[24];
    const float* dW1 = (const float*)d_in[25];
    const float* dg1 = (const float*)d_in[26];
    const float* db1 = (const float*)d_in[27];
    const float* dW2 = (const float*)d_in[28];
    const float* dg2 = (const float*)d_in[29];
    const float* db2 = (const float*)d_in[30];
    const float* dW3 = (const float*)d_in[31];
    const float* dbias3 = (const float*)d_in[32];
    float* out = (float*)d_out;
    float* ws  = (float*)d_ws;

    if (ws_size < O_END * sizeof(float)) {
        k_sentinel<<<1024,256,0,stream>>>(out);
        return;
    }

    float* H1  = ws + O_H1;
    float* H2  = ws + O_H2;
    float* L   = ws + O_L;
    int*   sel = (int*)(ws + O_SEL);
    float* S   = ws + O_S;
    float* S2  = ws + O_S2;
    float* val = ws + O_VAL;
    float* prm = ws + O_PRM;
    f16*   fW1h= (f16*)(ws + O_FW1H);
    f16*   fW2h= (f16*)(ws + O_FW2H);
    float* accF= ws + O_ACCF;
    f16*   dW1h= (f16*)(ws + O_DW1H);
    f16*   eW3h= (f16*)(ws + O_EW3H);
    float* V2s = ws + O_V2SS;
    float* u1  = ws + O_U1;
    float* P1  = ws + O_P1;
    float* fzT = ws + O_FZT;
    float* V3s = ws + O_V3S;
    float* pF  = ws + O_PF;             // fw1 stats partials (H1+H2)
    float* pD1 = ws + O_PD1;            // d1 stats partials (H2; pF dead by then)
    float* pD2 = ws + O_PD2;
    float* p2d = ws + O_P1;             // stats2d partials (P1 written later)
    float* pE3 = ws + O_FZT;            // e3 stats partials (fzT dead after k_p1)
    f16*   V3xT= (f16*)(ws + O_BIG1);
    f16*   out6T=(f16*)(ws + O_BIG2);
    f16*   V2x = (f16*)(ws + O_BIG2);   // aliases out6T
    f16*   d1p = (f16*)(ws + O_D1);     // f16; aliases V3xT (dead after fw1)
    float* d2p = ws + O_D2;

    const float invN_e = 1.0f/1310720.f;

    // ---- c-path (deterministic fp32; feeds argmax) ----
    k_gemm_c<<<dim3(16,8),256,0,stream>>>(x,  cW1, H1, 1024, 512,  nullptr,     nullptr);
    k_stats2d_p<<<dim3(32,1),256,0,stream>>>(H1, 1024, p2d);
    k_finalize_p<<<4,256,0,stream>>>(p2d, 1024, 32, 1.0f/512.f, cg1, cb1,
                                     prm+P_SC1, prm+P_SH1, nullptr, nullptr);
    k_gemm_c<<<dim3(16,8),256,0,stream>>>(H1, cW2, H2, 1024, 1024, prm+P_SC1, prm+P_SH1);
    k_stats2d_p<<<dim3(32,1),256,0,stream>>>(H2, 1024, p2d);
    k_finalize_p<<<4,256,0,stream>>>(p2d, 1024, 32, 1.0f/512.f, cg2, cb2,
                                     prm+P_SC2, prm+P_SH2, nullptr, nullptr);
    k_gemm_c<<<dim3(32,8),256,0,stream>>>(H2, cW3, L,  2048, 1024, prm+P_SC2, prm+P_SH2);
    k_stats2d_p<<<dim3(32,2),256,0,stream>>>(L, 2048, p2d);
    k_finalize_p<<<8,256,0,stream>>>(p2d, 2048, 32, 1.0f/512.f, cg3, cb3,
                                     prm+P_SC3, prm+P_SH3, nullptr, nullptr);
    k_sel<<<512,256,0,stream>>>(L, gumbel, prm+P_SC3, prm+P_SH3, sel);

    // ---- weight prep (overwrites L region) + selection-derived helpers ----
    k_prep<<<2048,256,0,stream>>>(fW1, fW2, dW1, eW3, fW1h, fW2h, dW1h, eW3h, accF);
    k_val<<<512,256,0,stream>>>(x, S, S2, val);
    k_e1params<<<1,256,0,stream>>>(S, S2, val, eW1, eg1, eb1, prm+P_A1, prm+P_C1, prm+P_ACC2);
    k_transpose_fz<<<dim3(32,16),256,0,stream>>>(fW1, fzT);
    k_wtrans2<<<1,256,0,stream>>>(eW2, prm+P_EW2T);
    k_ftot<<<4,256,0,stream>>>(fzT, prm+P_FTOT);
    k_p1<<<512,256,0,stream>>>(fzT, sel, P1);

    // ---- e-path ----
    k_epass2<<<1024,256,0,stream>>>(x, prm+P_A1, prm+P_C1, prm+P_EW2T, V2x);
    k_esupport2<<<513,64,0,stream>>>(val, prm+P_A1, prm+P_C1, prm+P_EW2T, V2s);
    k_stats_v2scan<<<64,256,0,stream>>>(V2x, prm+P_ACC2);
    k_wstats<<<64,64,0,stream>>>(V2s, 64, prm+P_ACC2);
    k_finalize<<<1,256,0,stream>>>(prm+P_ACC2, 64, invN_e, eg2, eb2, prm+P_SCE2, prm+P_SHE2,
                                   (f16*)(prm+P_SCE2H), (f16*)(prm+P_SHE2H));
    k_mfma_e3<<<dim3(4,512),256,0,stream>>>(eW3h, V2x,
                                            (const f16*)(prm+P_SCE2H), (const f16*)(prm+P_SHE2H),
                                            V3xT, pE3);
    k_esupport3<<<513,128,0,stream>>>(V2s, prm+P_SCE2, prm+P_SHE2, eW3, V3s);
    k_wstats<<<128,64,0,stream>>>(V3s, 128, prm+P_ACC3);
    k_finalize_e3<<<1,256,0,stream>>>(pE3, prm+P_ACC3, eg3, eb3, prm+P_SCE3, prm+P_SHE3,
                                      (f16*)(prm+P_SCE3H), (f16*)(prm+P_SHE3H));
    k_u<<<257,256,0,stream>>>(V3s, prm+P_SCE3, prm+P_SHE3, u1, prm+P_U0);

    // ---- f-path (MFMA f16) ----
    k_mfma_fw1T<<<dim3(8,512),256,0,stream>>>(fW1h, V3xT,
                                              (const f16*)(prm+P_SCE3H), (const f16*)(prm+P_SHE3H),
                                              u1, prm+P_U0, P1, prm+P_FTOT, out6T, pF);
    k_finalize_f<<<4,256,0,stream>>>(pF, fg1, fb1, prm+P_SCF1, prm+P_SHF1,
                                     (f16*)(prm+P_SCF1H), (f16*)(prm+P_SHF1H));
    // fw2 fused with d1: writes d1pre (BIG1, V3xT dead) + pD1; out7 never materialized
    k_mfma_fw2T<<<dim3(4,512),256,0,stream>>>(fW2h, out6T,
                                              (const f16*)(prm+P_SCF1H), (const f16*)(prm+P_SHF1H),
                                              fbias2, dW1h, d1p, pD1);

    // ---- d-path ----
    k_finalize_d1<<<1,256,0,stream>>>(pD1, dg1, db1, prm+P_SCD1, prm+P_SHD1);
    k_gemm_d2<<<dim3(8,512),128,0,stream>>>(dW2, d1p, prm+P_SCD1, prm+P_SHD1, d2p, pD2);
    k_finalize_d2<<<1,256,0,stream>>>(pD2, dg2, db2, prm+P_SCD2, prm+P_SHD2);
    k_d3<<<1024,256,0,stream>>>(d2p, dW3, prm+P_SCD2, prm+P_SHD2, dbias3, out);
}

// Round 10
// 924.346 us; speedup vs baseline: 1.0188x; 1.0188x over previous
//
#include <hip/hip_runtime.h>
#include <cstddef>

#define DEV __device__ __forceinline__
DEV float lrelu(float x){ return x >= 0.0f ? x : 0.2f*x; }
typedef _Float16 f16;
typedef _Float16 f16x8 __attribute__((ext_vector_type(8)));
typedef float f32x4 __attribute__((ext_vector_type(4)));

DEV f16x8 splat8(f16 s){ f16x8 v = {s,s,s,s,s,s,s,s}; return v; }
// packed BN + lrelu in f16: lrelu(v*sc+sh) with exact max/min formulation
DEV f16x8 bnl8(f16x8 v, f16x8 sc, f16x8 sh){
    f16x8 t = v*sc + sh;                       // v_pk_fma_f16
    f16x8 z = splat8((f16)0.0f);
    f16x8 mx = __builtin_elementwise_max(t, z);
    f16x8 mn = __builtin_elementwise_min(t, z);
    return mx + mn*splat8((f16)0.2f);
}

// async global->LDS, 16B per lane (raw staging, no VGPR roundtrip)
DEV void gload_lds16(const f16* src, f16* dst){
    __builtin_amdgcn_global_load_lds(
        (const __attribute__((address_space(1))) void*)src,
        (__attribute__((address_space(3))) void*)dst, 16, 0, 0);
}

// stage a 128x32 tile half-pair: slots t (rows 0..63) and 256+t (rows 64..127).
DEV void dma_pair(const f16* g0, const f16* g1, f16* ldsbase, int t){
    gload_lds16(g0, ldsbase + t*8);
    gload_lds16(g1, ldsbase + 2048 + t*8);
}
// reader-side swizzled f16 index for (row r, k-granule g)
DEV int swz_off(int r, int g){ return r*32 + ((g ^ ((r>>1)&3))<<3); }

#define SCHED0 __builtin_amdgcn_sched_barrier(0)
#define BARRIER __builtin_amdgcn_s_barrier()

// Problem dims: B=512, IN=512, CB=8, HD=256, CH=2048, CC=2560, EXP=128, FC1=1024, OUT=512
constexpr int NXPT = 512*512;     // dense support points (b,l<512)

// ---------------- workspace layout (float offsets) ----------------
constexpr size_t O_H1  = 0;                       // 512x1024 f32
constexpr size_t O_H2  = O_H1 + 512*1024;         // 512x1024 f32
constexpr size_t O_L   = O_H2 + 512*1024;         // 512x2048 f32 (c3 logits; dead after k_sel)
constexpr size_t O_SEL = O_L  + 512*2048;         // int32 512x256
constexpr size_t O_S   = O_SEL + 512*256;
constexpr size_t O_S2  = O_S + 512;
constexpr size_t O_VAL = O_S2 + 512;
constexpr size_t O_PRM = O_VAL + 512;
// params sub-offsets (within PRM)
constexpr size_t P_SC1=0, P_SH1=1024, P_SC2=2048, P_SH2=3072, P_SC3=4096, P_SH3=6144;
constexpr size_t P_A1=8192, P_C1=8224, P_EW2T=8256 /*2048*/;
constexpr size_t P_ACC2=18496 /*128*/, P_ACC3=18624 /*256*/;
constexpr size_t P_SCE2=18880, P_SHE2=18944, P_SCE3=19008, P_SHE3=19136;
constexpr size_t P_U0=19264 /*128*/, P_FTOT=19392 /*1024*/;
constexpr size_t P_SCF1=20416, P_SHF1=21440;
constexpr size_t P_SCD1=22464, P_SHD1=22528, P_SCD2=22592, P_SHD2=22624;
// f16 copies of BN affine params (for packed-f16 MFMA staging)
constexpr size_t P_SCE3H=22656, P_SHE3H=22720;    // 128 f16 each (64 floats)
constexpr size_t P_SCF1H=22784, P_SHF1H=23296;    // 1024 f16 each (512 floats)
constexpr size_t P_SCE2H=23808, P_SHE2H=23840;    // 64 f16 each (32 floats)
constexpr size_t PRM_SIZE = 32768;
// stats partial buffers (all alias dead regions)
constexpr size_t O_PF  = O_H1;                    // fw1 stats partials: 4096 x 256 f32 (H1+H2)
constexpr size_t O_PD1 = O_H2;                    // d1 stats partials: 2048 x 128 f32 (after pF dead)
constexpr size_t O_PD2 = O_H2 + 262144;           // d2 stats partials: 4096 x 64 f32
// weight copies + V2s ALIAS the dead L buffer (written after k_sel)
constexpr size_t O_FW1H = O_L;                    // f16 1024x512   (262144 floats)
constexpr size_t O_FW2H = O_L + 262144;           // f16 512x1024   (262144 floats)
constexpr size_t O_ACCF = O_L + 524288;           // f32 2048 (legacy zero region)
constexpr size_t O_DW1H = O_L + 528384;           // f16 64x128  (4096 floats)
constexpr size_t O_EW3H = O_L + 532480;           // f16 128x64  (4096 floats)
constexpr size_t O_V2SS = O_L + 536576;           // f32 513x64  (32832 floats)
constexpr size_t O_U1  = O_PRM + PRM_SIZE;        // 512x128 f32
constexpr size_t O_P1  = O_U1 + 512*128;          // 512x1024 f32; ALSO stats2d partials (before k_p1)
constexpr size_t O_FZT = O_P1 + 512*1024;         // 2048x1024 f32 (fW1 z-part T); pE3 aliases after k_p1
constexpr size_t O_V3S = O_FZT + (size_t)2048*1024;   // 513x128 f32
constexpr size_t O_BIG1= O_V3S + 513*128;             // f16 512*128*512  (V3xT, later out7)
constexpr size_t O_BIG2= O_BIG1 + (size_t)512*512*128/2; // f16 512*128*1024 (out6T); V2x + d1p alias
constexpr size_t O_D1  = O_BIG2;                      // f16 512*64*512 (aliases out6T, dead after fw2)
constexpr size_t O_D2  = O_BIG2 + (size_t)512*64*512; // f32 512*32*512
constexpr size_t O_END = O_BIG2 + (size_t)512*1024*128/2;   // ~211 MB

#define FMA44(av,bv) do{ \
  acc[0][0]=fmaf(av.x,bv.x,acc[0][0]); acc[0][1]=fmaf(av.x,bv.y,acc[0][1]); \
  acc[0][2]=fmaf(av.x,bv.z,acc[0][2]); acc[0][3]=fmaf(av.x,bv.w,acc[0][3]); \
  acc[1][0]=fmaf(av.y,bv.x,acc[1][0]); acc[1][1]=fmaf(av.y,bv.y,acc[1][1]); \
  acc[1][2]=fmaf(av.y,bv.z,acc[1][2]); acc[1][3]=fmaf(av.y,bv.w,acc[1][3]); \
  acc[2][0]=fmaf(av.z,bv.x,acc[2][0]); acc[2][1]=fmaf(av.z,bv.y,acc[2][1]); \
  acc[2][2]=fmaf(av.z,bv.z,acc[2][2]); acc[2][3]=fmaf(av.z,bv.w,acc[2][3]); \
  acc[3][0]=fmaf(av.w,bv.x,acc[3][0]); acc[3][1]=fmaf(av.w,bv.y,acc[3][1]); \
  acc[3][2]=fmaf(av.w,bv.z,acc[3][2]); acc[3][3]=fmaf(av.w,bv.w,acc[3][3]); \
}while(0)

__global__ void k_sentinel(float* out){ out[blockIdx.x*256 + threadIdx.x] = 1.0e6f; }

// prep: f16 weight copies, zero legacy accumulators. Runs AFTER k_sel (aliases L).
__global__ __launch_bounds__(256) void k_prep(
    const float* __restrict__ fW1, const float* __restrict__ fW2,
    const float* __restrict__ dW1, const float* __restrict__ eW3,
    f16* __restrict__ fW1h, f16* __restrict__ fW2h, f16* __restrict__ dW1h,
    f16* __restrict__ eW3h, float* __restrict__ accAll)
{
    const int i = blockIdx.x*256 + threadIdx.x;   // 524288 threads
    int f = i >> 9, l = i & 511;
    fW1h[i] = (f16)fW1[(size_t)f*2560 + l];       // x-part only (cols 0..511)
    fW2h[i] = (f16)fW2[i];
    if (i < 8192) { dW1h[i] = (f16)dW1[i]; eW3h[i] = (f16)eW3[i]; }
    if (i < 4096) accAll[i] = 0.f;
}

// ---------------- c-layers (NT, fp32: feeds argmax) ----------------
__global__ __launch_bounds__(256) void k_gemm_c(
    const float* __restrict__ A, const float* __restrict__ W, float* __restrict__ C,
    int N, int K, const float* __restrict__ sc, const float* __restrict__ sh)
{
    __shared__ __align__(16) float As[16][68];
    __shared__ __align__(16) float Ws[16][68];
    const int n0 = blockIdx.x * 64, m0 = blockIdx.y * 64;
    const int t = threadIdx.x;
    const int kk = t & 15, ri = t >> 4;
    const int tx = t & 15, ty = t >> 4;
    float acc[4][4] = {{0.f,0.f,0.f,0.f},{0.f,0.f,0.f,0.f},{0.f,0.f,0.f,0.f},{0.f,0.f,0.f,0.f}};
    for (int k0 = 0; k0 < K; k0 += 16) {
        float scv = 0.f, shv = 0.f;
        if (sc) { scv = sc[k0+kk]; shv = sh[k0+kk]; }
        #pragma unroll
        for (int mm = 0; mm < 4; ++mm) {
            float v = A[(size_t)(m0 + ri + mm*16) * K + k0 + kk];
            if (sc) v = lrelu(fmaf(v, scv, shv));
            As[kk][ri + mm*16] = v;
        }
        #pragma unroll
        for (int nn = 0; nn < 4; ++nn)
            Ws[kk][ri + nn*16] = W[(size_t)(n0 + ri + nn*16) * K + k0 + kk];
        __syncthreads();
        #pragma unroll
        for (int kq = 0; kq < 16; ++kq) {
            const float4 av = *reinterpret_cast<const float4*>(&As[kq][ty*4]);
            const float4 bv = *reinterpret_cast<const float4*>(&Ws[kq][tx*4]);
            FMA44(av, bv);
        }
        __syncthreads();
    }
    #pragma unroll
    for (int i = 0; i < 4; ++i)
        #pragma unroll
        for (int j = 0; j < 4; ++j)
            C[(size_t)(m0 + ty*4 + i) * N + n0 + tx*4 + j] = acc[i][j];
}

// coalesced column-stats partials for f32 buf[512][C]
__global__ __launch_bounds__(256) void k_stats2d_p(
    const float* __restrict__ buf, int C, float* __restrict__ part)
{
    const int t = threadIdx.x;
    const int r0 = blockIdx.x*16;
    const int c0 = blockIdx.y*1024;
    float s[4]={0.f,0.f,0.f,0.f}, s2[4]={0.f,0.f,0.f,0.f};
    for (int rr = 0; rr < 16; ++rr) {
        float4 v = *reinterpret_cast<const float4*>(buf + (size_t)(r0+rr)*C + c0 + t*4);
        s[0]+=v.x; s[1]+=v.y; s[2]+=v.z; s[3]+=v.w;
        s2[0]+=v.x*v.x; s2[1]+=v.y*v.y; s2[2]+=v.z*v.z; s2[3]+=v.w*v.w;
    }
    float* d0 = part + (size_t)blockIdx.x*2*C + c0 + t*4;
    *reinterpret_cast<float4*>(d0)     = (float4){s[0],s[1],s[2],s[3]};
    *reinterpret_cast<float4*>(d0 + C) = (float4){s2[0],s2[1],s2[2],s2[3]};
}

__global__ __launch_bounds__(256) void k_sel(
    const float* __restrict__ Lpre, const float* __restrict__ gumbel,
    const float* __restrict__ sc, const float* __restrict__ sh, int* __restrict__ sel)
{
    const int b = blockIdx.x, hd = threadIdx.x;
    float best = -3.0e38f; int bi = 0;
    #pragma unroll
    for (int cb = 0; cb < 8; ++cb) {
        int c = cb*256 + hd;
        float v = lrelu(fmaf(Lpre[(size_t)b*2048 + c], sc[c], sh[c])) + gumbel[(size_t)b*2048 + c];
        if (v > best) { best = v; bi = cb; }
    }
    sel[b*256 + hd] = bi;
}

__global__ __launch_bounds__(256) void k_val(const float* __restrict__ x,
    float* __restrict__ S, float* __restrict__ S2, float* __restrict__ val)
{
    const int b = blockIdx.x, t = threadIdx.x;
    float v0 = x[b*512 + t], v1 = x[b*512 + t + 256];
    __shared__ float ls[256], ls2[256];
    ls[t] = v0 + v1; ls2[t] = v0*v0 + v1*v1;
    __syncthreads();
    for (int off = 128; off; off >>= 1) { if (t < off) { ls[t]+=ls[t+off]; ls2[t]+=ls2[t+off]; } __syncthreads(); }
    if (t == 0) { float s = ls[0], s2 = ls2[0]; S[b]=s; S2[b]=s2; val[b]=0.5f*(s*s - s2); }
}

__global__ __launch_bounds__(256) void k_e1params(
    const float* __restrict__ S, const float* __restrict__ S2, const float* __restrict__ val,
    const float* __restrict__ eW1, const float* __restrict__ eg1, const float* __restrict__ eb1,
    float* __restrict__ A1, float* __restrict__ C1, float* __restrict__ accs /*384*/)
{
    const int t = threadIdx.x;
    accs[t] = 0.f; if (t < 128) accs[256 + t] = 0.f;
    __shared__ float ls[256], ls2[256];
    float s = 0.f, s2 = 0.f;
    for (int b = t; b < 512; b += 256) {
        float vb = val[b];
        s  += S[b]  + 256.f*vb;
        s2 += S2[b] + 256.f*vb*vb;
    }
    ls[t] = s; ls2[t] = s2; __syncthreads();
    for (int off = 128; off; off >>= 1) { if (t < off) { ls[t]+=ls[t+off]; ls2[t]+=ls2[t+off]; } __syncthreads(); }
    if (t < 32) {
        const float invn = 1.0f/1310720.f;
        float mu = ls[0]*invn;
        float var = fmaxf(ls2[0]*invn - mu*mu, 0.f);
        float w = eW1[t];
        float rs = 1.0f / sqrtf(w*w*var + 1e-5f);
        float a = w * eg1[t] * rs;
        A1[t] = a; C1[t] = eb1[t] - mu*a;
    }
}

// transpose eW2 (64x32)->(32x64)
__global__ void k_wtrans2(const float* __restrict__ eW2, float* __restrict__ eW2T)
{
    const int t = threadIdx.x;
    for (int i = t; i < 2048; i += 256) { int p = i >> 5, o = i & 31; eW2T[o*64 + p] = eW2[i]; }
}

__global__ __launch_bounds__(256) void k_transpose_fz(const float* __restrict__ fW1, float* __restrict__ fzT)
{
    __shared__ float tile[64][65];
    const int z0 = blockIdx.x*64, f0 = blockIdx.y*64;
    const int j = threadIdx.x & 63, i0 = threadIdx.x >> 6;
    #pragma unroll
    for (int ii = 0; ii < 16; ++ii) {
        int fi = i0*16 + ii;
        tile[fi][j] = fW1[(size_t)(f0+fi)*2560 + 512 + z0 + j];
    }
    __syncthreads();
    #pragma unroll
    for (int ii = 0; ii < 16; ++ii) {
        int zi = i0*16 + ii;
        fzT[(size_t)(z0+zi)*1024 + f0 + j] = tile[j][zi];
    }
}

__global__ __launch_bounds__(256) void k_ftot(const float* __restrict__ fzT, float* __restrict__ Ftot)
{
    const int f = blockIdx.x*256 + threadIdx.x;
    float s = 0.f;
    for (int z = 0; z < 2048; ++z) s += fzT[(size_t)z*1024 + f];
    Ftot[f] = s;
}

__global__ __launch_bounds__(256) void k_p1(const float* __restrict__ fzT, const int* __restrict__ sel,
                                            float* __restrict__ P1)
{
    const int b = blockIdx.x, t = threadIdx.x;
    float a0=0.f, a1=0.f, a2=0.f, a3=0.f;
    for (int hd = 0; hd < 256; ++hd) {
        int col = sel[b*256 + hd]*256 + hd;
        const float* r = fzT + (size_t)col*1024;
        a0 += r[t]; a1 += r[t+256]; a2 += r[t+512]; a3 += r[t+768];
    }
    P1[b*1024 + t] = a0; P1[b*1024 + t + 256] = a1; P1[b*1024 + t + 512] = a2; P1[b*1024 + t + 768] = a3;
}

// e2 main points: v2 = eW2 * lrelu(A1*x+C1); write V2x[pt][d] f16. NO stats.
__global__ __launch_bounds__(256) void k_epass2(
    const float* __restrict__ x,
    const float* __restrict__ A1, const float* __restrict__ C1,
    const float* __restrict__ eW2T, f16* __restrict__ V2x)
{
    __shared__ float sW[2048], sA[32], sC[32];
    const int t = threadIdx.x;
    #pragma unroll
    for (int i = 0; i < 8; ++i) sW[t + 256*i] = eW2T[t + 256*i];
    if (t < 32) { sA[t] = A1[t]; sC[t] = C1[t]; }
    __syncthreads();
    const int pt = blockIdx.x*256 + t;
    float phi = x[pt];
    float v2[64];
    #pragma unroll
    for (int p = 0; p < 64; ++p) v2[p] = 0.f;
    for (int o = 0; o < 32; ++o) {
        float t1 = lrelu(fmaf(sA[o], phi, sC[o]));
        #pragma unroll
        for (int p = 0; p < 64; ++p) v2[p] = fmaf(sW[o*64 + p], t1, v2[p]);
    }
    f16* dst = V2x + (size_t)pt*64;
    #pragma unroll
    for (int dd = 0; dd < 64; dd += 8) {
        f16x8 o;
        #pragma unroll
        for (int e = 0; e < 8; ++e) o[e] = (f16)v2[dd+e];
        *reinterpret_cast<f16x8*>(dst + dd) = o;
    }
}

// e2 support points
__global__ __launch_bounds__(64) void k_esupport2(
    const float* __restrict__ val,
    const float* __restrict__ A1, const float* __restrict__ C1,
    const float* __restrict__ eW2T, float* __restrict__ V2s)
{
    const int idx = blockIdx.x, d = threadIdx.x;
    float phi = (idx < 512) ? val[idx] : 0.f;
    __shared__ float t1s[32];
    if (d < 32) t1s[d] = lrelu(fmaf(A1[d], phi, C1[d]));
    __syncthreads();
    float s = 0.f;
    #pragma unroll
    for (int o = 0; o < 32; ++o) s = fmaf(eW2T[o*64 + d], t1s[o], s);
    V2s[idx*64 + d] = s;
}

// weighted column stats over V[513][C]: grid C blocks x 64 threads; 2 atomics/block
__global__ __launch_bounds__(64) void k_wstats(
    const float* __restrict__ V, int C, float* __restrict__ acc)
{
    const int c = blockIdx.x, lane = threadIdx.x;
    float s = 0.f, s2 = 0.f;
    for (int i = lane; i < 513; i += 64) {
        float w = (i < 512) ? 256.f : 917504.f;
        float v = V[(size_t)i*C + c];
        s += w*v; s2 += w*v*v;
    }
    #pragma unroll
    for (int off = 32; off; off >>= 1) { s += __shfl_xor(s, off); s2 += __shfl_xor(s2, off); }
    if (lane == 0) { atomicAdd(&acc[c], s); atomicAdd(&acc[C + c], s2); }
}

// e2 stats scan over V2x (262144 pts x 64 ch, f16). 64 blocks; 128 atomics/block.
__global__ __launch_bounds__(256) void k_stats_v2scan(const f16* __restrict__ V2x, float* __restrict__ acc2)
{
    const int t = threadIdx.x;
    const int wave = t >> 6, lane = t & 63;
    const int g = t & 7;
    const int slot = blockIdx.x*32 + (t >> 3);
    float s[8] = {0,0,0,0,0,0,0,0}, s2[8] = {0,0,0,0,0,0,0,0};
    for (int p = slot; p < NXPT; p += 2048) {
        f16x8 v = *reinterpret_cast<const f16x8*>(V2x + (size_t)p*64 + g*8);
        #pragma unroll
        for (int e = 0; e < 8; ++e) { float f = (float)v[e]; s[e] += f; s2[e] += f*f; }
    }
    #pragma unroll
    for (int off = 8; off <= 32; off <<= 1) {
        #pragma unroll
        for (int e = 0; e < 8; ++e) { s[e] += __shfl_xor(s[e], off); s2[e] += __shfl_xor(s2[e], off); }
    }
    __shared__ float red[4*128];
    if (lane < 8) {
        #pragma unroll
        for (int e = 0; e < 8; ++e) {
            red[wave*128 + lane*16 + e]     = s[e];
            red[wave*128 + lane*16 + 8 + e] = s2[e];
        }
    }
    __syncthreads();
    if (t < 128) {
        float v = red[t] + red[128 + t] + red[256 + t] + red[384 + t];
        int gg = t >> 4, k = t & 15;
        if (k < 8) atomicAdd(&acc2[gg*8 + k], v);
        else       atomicAdd(&acc2[64 + gg*8 + (k - 8)], v);
    }
}

__global__ void k_finalize(const float* __restrict__ acc, int C, float invn,
                           const float* __restrict__ g, const float* __restrict__ bb,
                           float* __restrict__ sc, float* __restrict__ sh,
                           f16* __restrict__ sch, f16* __restrict__ shh)
{
    const int idx = blockIdx.x*blockDim.x + threadIdx.x;
    if (idx < C) {
        float m = acc[idx] * invn;
        float var = fmaxf(acc[C + idx] * invn - m*m, 0.f);
        float r = 1.0f / sqrtf(var + 1e-5f);
        float s = g[idx] * r;
        float h = bb[idx] - m*s;
        sc[idx] = s; sh[idx] = h;
        if (sch) { sch[idx] = (f16)s; shh[idx] = (f16)h; }
    }
}

// finalize from contention-free partials: P = [nPart][2C] rows
__global__ void k_finalize_p(const float* __restrict__ P, int C, int nPart, float invn,
                             const float* __restrict__ g, const float* __restrict__ bb,
                             float* __restrict__ sc, float* __restrict__ sh,
                             f16* __restrict__ sch, f16* __restrict__ shh)
{
    const int idx = blockIdx.x*blockDim.x + threadIdx.x;
    if (idx < C) {
        float s = 0.f, s2 = 0.f;
        for (int p = 0; p < nPart; ++p) {
            s  += P[(size_t)p*2*C + idx];
            s2 += P[(size_t)p*2*C + C + idx];
        }
        float m = s * invn;
        float var = fmaxf(s2 * invn - m*m, 0.f);
        float r = 1.0f / sqrtf(var + 1e-5f);
        float sv = g[idx] * r;
        float h = bb[idx] - m*sv;
        sc[idx] = sv; sh[idx] = h;
        if (sch) { sch[idx] = (f16)sv; shh[idx] = (f16)h; }
    }
}

// finalize e3 BN: sum pE3 [2048][256] partials + wstats row accw[256]
__global__ __launch_bounds__(256) void k_finalize_e3(
    const float* __restrict__ P, const float* __restrict__ accw,
    const float* __restrict__ g, const float* __restrict__ bb,
    float* __restrict__ sc, float* __restrict__ sh,
    f16* __restrict__ sch, f16* __restrict__ shh)
{
    const int t = threadIdx.x, q = t & 127, h = t >> 7;
    float s = 0.f, s2 = 0.f;
    for (int p = h*1024; p < h*1024 + 1024; ++p) {
        s  += P[(size_t)p*256 + q];
        s2 += P[(size_t)p*256 + 128 + q];
    }
    __shared__ float red[2][2][128];
    red[h][0][q] = s; red[h][1][q] = s2;
    __syncthreads();
    if (t < 128) {
        float ss  = red[0][0][q] + red[1][0][q] + accw[q];
        float ss2 = red[0][1][q] + red[1][1][q] + accw[128 + q];
        const float invn = 1.0f/1310720.f;
        float m = ss * invn;
        float var = fmaxf(ss2 * invn - m*m, 0.f);
        float r = 1.0f / sqrtf(var + 1e-5f);
        float sv = g[q] * r, hh = bb[q] - m*sv;
        sc[q] = sv; sh[q] = hh; sch[q] = (f16)sv; shh[q] = (f16)hh;
    }
}

// finalize f-BN from pF [8 fblk][512 b][256]
__global__ __launch_bounds__(256) void k_finalize_f(
    const float* __restrict__ P,
    const float* __restrict__ g, const float* __restrict__ bb,
    float* __restrict__ sc, float* __restrict__ sh,
    f16* __restrict__ sch, f16* __restrict__ shh)
{
    const int f = blockIdx.x*256 + threadIdx.x;
    const int fb = f >> 7, c = f & 127;
    const float* base = P + (size_t)fb*512*256 + c;
    float s = 0.f, s2 = 0.f;
    for (int b = 0; b < 512; ++b) {
        s  += base[(size_t)b*256];
        s2 += base[(size_t)b*256 + 128];
    }
    float m = s*(1.0f/65536.f);
    float var = fmaxf(s2*(1.0f/65536.f) - m*m, 0.f);
    float r = 1.0f/sqrtf(var + 1e-5f);
    float sv = g[f]*r, h = bb[f] - m*sv;
    sc[f] = sv; sh[f] = h; sch[f] = (f16)sv; shh[f] = (f16)h;
}

// finalize d1-BN from pD1 [2048][128]
__global__ __launch_bounds__(256) void k_finalize_d1(
    const float* __restrict__ P,
    const float* __restrict__ g, const float* __restrict__ bb,
    float* __restrict__ sc, float* __restrict__ sh)
{
    const int t = threadIdx.x, d = t & 63, gr = t >> 6;  // 4 groups x 512 rows
    float s = 0.f, s2 = 0.f;
    for (int p = gr*512; p < gr*512 + 512; ++p) {
        s  += P[(size_t)p*128 + d];
        s2 += P[(size_t)p*128 + 64 + d];
    }
    __shared__ float red[4][2][64];
    red[gr][0][d] = s; red[gr][1][d] = s2;
    __syncthreads();
    if (t < 64) {
        float ss  = red[0][0][t]+red[1][0][t]+red[2][0][t]+red[3][0][t];
        float ss2 = red[0][1][t]+red[1][1][t]+red[2][1][t]+red[3][1][t];
        float m = ss*(1.0f/262144.f);
        float var = fmaxf(ss2*(1.0f/262144.f) - m*m, 0.f);
        float r = 1.0f/sqrtf(var + 1e-5f);
        float sv = g[t]*r;
        sc[t] = sv; sh[t] = bb[t] - m*sv;
    }
}

// finalize d2-BN from pD2 [4096][64] rows ([32 sums][32 sumsq])
__global__ __launch_bounds__(256) void k_finalize_d2(
    const float* __restrict__ P,
    const float* __restrict__ g, const float* __restrict__ bb,
    float* __restrict__ sc, float* __restrict__ sh)
{
    const int t = threadIdx.x, e = t & 31, gr = t >> 5;  // 8 groups x 512 rows
    float s = 0.f, s2 = 0.f;
    for (int p = gr*512; p < gr*512 + 512; ++p) {
        s  += P[(size_t)p*64 + e];
        s2 += P[(size_t)p*64 + 32 + e];
    }
    __shared__ float red[8][2][32];
    red[gr][0][e] = s; red[gr][1][e] = s2;
    __syncthreads();
    if (t < 32) {
        float ss = 0.f, ss2 = 0.f;
        #pragma unroll
        for (int k2 = 0; k2 < 8; ++k2) { ss += red[k2][0][t]; ss2 += red[k2][1][t]; }
        float m = ss*(1.0f/262144.f);
        float var = fmaxf(ss2*(1.0f/262144.f) - m*m, 0.f);
        float r = 1.0f/sqrtf(var + 1e-5f);
        float sv = g[t]*r;
        sc[t] = sv; sh[t] = bb[t] - m*sv;
    }
}

// MFMA e3 + fused V3xT stats partials; packed-f16 BN on V2x (sc2h/sh2h f16)
__global__ __launch_bounds__(256) void k_mfma_e3(
    const f16* __restrict__ eW3h, const f16* __restrict__ V2x,
    const f16* __restrict__ sc2h, const f16* __restrict__ sh2h,
    f16* __restrict__ V3xT, float* __restrict__ pE3)
{
    __shared__ __align__(16) f16 As[128][76];   // eW3 rows q, cols d
    __shared__ __align__(16) f16 Bs[128][76];   // t2 rows point, cols d
    __shared__ float rede[256];
    const int b = blockIdx.y, l0 = blockIdx.x * 128;
    const int t = threadIdx.x;
    const int wave = t >> 6, lane = t & 63;
    const int quad = lane >> 4, l16 = lane & 15;
    const int row = t >> 1, half = t & 1;
    #pragma unroll
    for (int c = 0; c < 4; ++c)
        *reinterpret_cast<f16x8*>(&As[row][half*32 + c*8]) =
            *reinterpret_cast<const f16x8*>(eW3h + row*64 + half*32 + c*8);
    const f16* src = V2x + ((size_t)(b*512 + l0 + row))*64 + half*32;
    #pragma unroll
    for (int c = 0; c < 4; ++c) {
        f16x8 v = *reinterpret_cast<const f16x8*>(src + c*8);
        const f16x8 csc = *reinterpret_cast<const f16x8*>(sc2h + half*32 + c*8);
        const f16x8 csh = *reinterpret_cast<const f16x8*>(sh2h + half*32 + c*8);
        *reinterpret_cast<f16x8*>(&Bs[row][half*32 + c*8]) = bnl8(v, csc, csh);
    }
    __syncthreads();
    f32x4 acc[2][8];
    #pragma unroll
    for (int i = 0; i < 2; ++i)
        #pragma unroll
        for (int j = 0; j < 8; ++j) acc[i][j] = (f32x4){0.f,0.f,0.f,0.f};
    f16x8 a0  = *reinterpret_cast<const f16x8*>(&As[32*wave + l16][quad*8]);
    f16x8 a0b = *reinterpret_cast<const f16x8*>(&As[32*wave + l16][32 + quad*8]);
    f16x8 a1  = *reinterpret_cast<const f16x8*>(&As[32*wave + 16 + l16][quad*8]);
    f16x8 a1b = *reinterpret_cast<const f16x8*>(&As[32*wave + 16 + l16][32 + quad*8]);
    #pragma unroll
    for (int j = 0; j < 8; ++j) {
        f16x8 bj  = *reinterpret_cast<const f16x8*>(&Bs[16*j + l16][quad*8]);
        f16x8 bjb = *reinterpret_cast<const f16x8*>(&Bs[16*j + l16][32 + quad*8]);
        acc[0][j] = __builtin_amdgcn_mfma_f32_16x16x32_f16(a0,  bj,  acc[0][j], 0, 0, 0);
        acc[0][j] = __builtin_amdgcn_mfma_f32_16x16x32_f16(a0b, bjb, acc[0][j], 0, 0, 0);
        acc[1][j] = __builtin_amdgcn_mfma_f32_16x16x32_f16(a1,  bj,  acc[1][j], 0, 0, 0);
        acc[1][j] = __builtin_amdgcn_mfma_f32_16x16x32_f16(a1b, bjb, acc[1][j], 0, 0, 0);
    }
    float se[8] = {0,0,0,0,0,0,0,0}, s2e[8] = {0,0,0,0,0,0,0,0};
    #pragma unroll
    for (int i = 0; i < 2; ++i) {
        #pragma unroll
        for (int r = 0; r < 4; ++r) {
            int q = 32*wave + 16*i + quad*4 + r;
            #pragma unroll
            for (int j = 0; j < 8; ++j) {
                float v = acc[i][j][r];
                V3xT[((size_t)b*128 + q)*512 + l0 + 16*j + l16] = (f16)v;
                se[i*4+r] += v; s2e[i*4+r] += v*v;
            }
        }
    }
    #pragma unroll
    for (int k = 0; k < 8; ++k) {
        se[k]  += __shfl_xor(se[k],1);  se[k]  += __shfl_xor(se[k],2);
        se[k]  += __shfl_xor(se[k],4);  se[k]  += __shfl_xor(se[k],8);
        s2e[k] += __shfl_xor(s2e[k],1); s2e[k] += __shfl_xor(s2e[k],2);
        s2e[k] += __shfl_xor(s2e[k],4); s2e[k] += __shfl_xor(s2e[k],8);
    }
    if (l16 == 0) {
        #pragma unroll
        for (int i = 0; i < 2; ++i)
            #pragma unroll
            for (int r = 0; r < 4; ++r) {
                int qq = 32*wave + 16*i + quad*4 + r;
                rede[qq] = se[i*4+r];
            }
    }
    __syncthreads();
    if (t < 128) pE3[((size_t)(blockIdx.x*512 + b))*256 + t] = rede[t];
    __syncthreads();
    if (l16 == 0) {
        #pragma unroll
        for (int i = 0; i < 2; ++i)
            #pragma unroll
            for (int r = 0; r < 4; ++r) {
                int qq = 32*wave + 16*i + quad*4 + r;
                rede[qq] = s2e[i*4+r];
            }
    }
    __syncthreads();
    if (t < 128) pE3[((size_t)(blockIdx.x*512 + b))*256 + 128 + t] = rede[t];
}

// e3 support points
__global__ __launch_bounds__(128) void k_esupport3(
    const float* __restrict__ V2s, const float* __restrict__ sc2, const float* __restrict__ sh2,
    const float* __restrict__ eW3, float* __restrict__ V3s)
{
    const int idx = blockIdx.x, q = threadIdx.x;
    __shared__ float t2s[64];
    if (q < 64) t2s[q] = lrelu(fmaf(sc2[q], V2s[idx*64 + q], sh2[q]));
    __syncthreads();
    float s = 0.f;
    #pragma unroll
    for (int d = 0; d < 64; ++d) s = fmaf(eW3[q*64 + d], t2s[d], s);
    V3s[idx*128 + q] = s;
}

__global__ void k_u(const float* __restrict__ V3s, const float* __restrict__ sc3, const float* __restrict__ sh3,
                    float* __restrict__ u1, float* __restrict__ u0)
{
    const int idx = blockIdx.x*256 + threadIdx.x;
    if (idx < 513*128) {
        int i = idx >> 7, q = idx & 127;
        float tv = lrelu(fmaf(sc3[q], V3s[idx], sh3[q]));
        if (i < 512) u1[idx] = tv; else u0[q] = tv;
    }
}

// ---------------- MFMA fw1 (pipeline + fused out6T stats; hoisted epilogue loads) ----------------
__global__ __launch_bounds__(256) void k_mfma_fw1T(
    const f16* __restrict__ fW1h, const f16* __restrict__ V3xT,
    const f16* __restrict__ sceh, const f16* __restrict__ sheh,
    const float* __restrict__ u1, const float* __restrict__ u0,
    const float* __restrict__ P1, const float* __restrict__ Ftot,
    f16* __restrict__ out6T, float* __restrict__ pF)
{
    __shared__ __align__(16) f16 lds[24576];    // 3 sets x (A 4096 + B 4096) f16
    __shared__ float redf[1024];
    const int t = threadIdx.x;
    const int wave = t >> 6, lane = t & 63;
    const int quad = lane >> 4, l16 = lane & 15;
    const int n = blockIdx.x + (blockIdx.y << 3);
    const int b = (n & 7)*64 + (n >> 6);
    const int fblk = (n >> 3) & 7;
    const int f0 = fblk * 128;
    const f16* Aa = V3xT + (size_t)b*65536;
    const f16* Bb = fW1h + (size_t)f0*512;
    const int sg = (t & 3) ^ ((t >> 3) & 3);
    const size_t go0 = (size_t)(t >> 2)*512 + sg*8;
    const size_t go1 = go0 + (size_t)64*512;
    const int rA0 = 32*wave + l16, rA1 = rA0 + 16;
    const f16x8 scA0 = splat8(sceh[rA0]), shA0 = splat8(sheh[rA0]);
    const f16x8 scA1 = splat8(sceh[rA1]), shA1 = splat8(sheh[rA1]);
    const int offA0 = swz_off(rA0, quad);
    const int offA1 = swz_off(rA1, quad);
    int offB[8];
    #pragma unroll
    for (int j = 0; j < 8; ++j) offB[j] = swz_off(16*j + l16, quad);
    // hoisted epilogue operands: latency hides under the whole k-loop
    float p1j[8], p0j[8], u1q[8], u0q[8];
    #pragma unroll
    for (int j = 0; j < 8; ++j) {
        int f = f0 + 16*j + l16;
        p1j[j] = P1[b*1024 + f];
        p0j[j] = Ftot[f] - p1j[j];
    }
    #pragma unroll
    for (int i = 0; i < 2; ++i)
        #pragma unroll
        for (int r = 0; r < 4; ++r) {
            int q = 32*wave + 16*i + quad*4 + r;
            u1q[i*4+r] = u1[b*128 + q];
            u0q[i*4+r] = u0[q];
        }
    f32x4 acc[2][8];
    #pragma unroll
    for (int i = 0; i < 2; ++i)
        #pragma unroll
        for (int j = 0; j < 8; ++j) acc[i][j] = (f32x4){0.f,0.f,0.f,0.f};
    dma_pair(Aa + go0,      Aa + go1,      lds,               t);
    dma_pair(Bb + go0,      Bb + go1,      lds + 4096,        t);
    dma_pair(Aa + 32 + go0, Aa + 32 + go1, lds + 8192,        t);
    dma_pair(Bb + 32 + go0, Bb + 32 + go1, lds + 8192 + 4096, t);
    int m = 0;
    for (int kt = 0; kt < 16; ++kt) {
        SCHED0; BARRIER; SCHED0;
        if (kt <= 13) {
            const int mp = (m >= 1) ? m - 1 : m + 2;
            const int k0 = (kt + 2) * 32;
            dma_pair(Aa + k0 + go0, Aa + k0 + go1, lds + mp*8192,        t);
            dma_pair(Bb + k0 + go0, Bb + k0 + go1, lds + mp*8192 + 4096, t);
            asm volatile("s_waitcnt vmcnt(8)" ::: "memory");
        } else if (kt == 14) {
            asm volatile("s_waitcnt vmcnt(4)" ::: "memory");
        } else {
            asm volatile("s_waitcnt vmcnt(0)" ::: "memory");
        }
        SCHED0; BARRIER; SCHED0;
        const f16* As = lds + m*8192;
        const f16* Bs = As + 4096;
        f16x8 a0 = bnl8(*reinterpret_cast<const f16x8*>(As + offA0), scA0, shA0);
        f16x8 a1 = bnl8(*reinterpret_cast<const f16x8*>(As + offA1), scA1, shA1);
        #pragma unroll
        for (int j = 0; j < 8; ++j) {
            f16x8 bj = *reinterpret_cast<const f16x8*>(Bs + offB[j]);
            acc[0][j] = __builtin_amdgcn_mfma_f32_16x16x32_f16(a0, bj, acc[0][j], 0, 0, 0);
            acc[1][j] = __builtin_amdgcn_mfma_f32_16x16x32_f16(a1, bj, acc[1][j], 0, 0, 0);
        }
        m = (m == 2) ? 0 : m + 1;
    }
    float sj[8], s2j[8];
    #pragma unroll
    for (int j = 0; j < 8; ++j) { sj[j] = 0.f; s2j[j] = 0.f; }
    #pragma unroll
    for (int i = 0; i < 2; ++i) {
        #pragma unroll
        for (int r = 0; r < 4; ++r) {
            int q = 32*wave + 16*i + quad*4 + r;
            #pragma unroll
            for (int j = 0; j < 8; ++j) {
                int f = f0 + 16*j + l16;
                float v = acc[i][j][r] + u1q[i*4+r]*p1j[j] + u0q[i*4+r]*p0j[j];
                out6T[((size_t)b*128 + q)*1024 + f] = (f16)v;
                sj[j] += v; s2j[j] += v*v;
            }
        }
    }
    #pragma unroll
    for (int j = 0; j < 8; ++j) {
        sj[j]  += __shfl_xor(sj[j],16);  sj[j]  += __shfl_xor(sj[j],32);
        s2j[j] += __shfl_xor(s2j[j],16); s2j[j] += __shfl_xor(s2j[j],32);
    }
    if (quad == 0) {
        #pragma unroll
        for (int j = 0; j < 8; ++j) {
            redf[wave*256 + j*16 + l16]       = sj[j];
            redf[wave*256 + 128 + j*16 + l16] = s2j[j];
        }
    }
    __syncthreads();
    {
        float v = redf[t] + redf[256 + t] + redf[512 + t] + redf[768 + t];
        pF[((size_t)(fblk*512 + b))*256 + t] = v;
    }
}

// ---------------- MFMA fw2 (triple-buffered pipeline + in-place LDS BN) ----------------
__global__ __launch_bounds__(256) void k_mfma_fw2T(
    const f16* __restrict__ fW2h, const f16* __restrict__ out6T,
    const f16* __restrict__ scfh, const f16* __restrict__ shfh,
    const float* __restrict__ fbias2, f16* __restrict__ out7)
{
    __shared__ __align__(16) f16 lds[24576];
    __shared__ __align__(16) f16 scL[1024];
    __shared__ __align__(16) f16 shL[1024];
    const int t = threadIdx.x;
    const int wave = t >> 6, lane = t & 63;
    const int quad = lane >> 4, l16 = lane & 15;
    const int n = blockIdx.x + (blockIdx.y << 2);
    const int b = (n & 7)*64 + (n >> 5);
    const int o0 = ((n >> 3) & 3) * 128;
    const f16* Aa = fW2h + (size_t)o0*1024;
    const f16* Bb = out6T + (size_t)b*131072;
    const int sg = (t & 3) ^ ((t >> 3) & 3);
    const size_t go0 = (size_t)(t >> 2)*1024 + sg*8;
    const size_t go1 = go0 + (size_t)64*1024;
    const int bnO = sg*8;
    const int offA0 = swz_off(32*wave + l16, quad);
    const int offA1 = swz_off(32*wave + 16 + l16, quad);
    int offB[8];
    #pragma unroll
    for (int j = 0; j < 8; ++j) offB[j] = swz_off(16*j + l16, quad);
    // hoisted bias loads
    float biasv[8];
    #pragma unroll
    for (int i = 0; i < 2; ++i)
        #pragma unroll
        for (int r = 0; r < 4; ++r)
            biasv[i*4+r] = fbias2[o0 + 32*wave + 16*i + quad*4 + r];
    f32x4 acc[2][8];
    #pragma unroll
    for (int i = 0; i < 2; ++i)
        #pragma unroll
        for (int j = 0; j < 8; ++j) acc[i][j] = (f32x4){0.f,0.f,0.f,0.f};
    if (t < 128) *reinterpret_cast<f16x8*>(&scL[t*8]) =
        *reinterpret_cast<const f16x8*>(scfh + t*8);
    else         *reinterpret_cast<f16x8*>(&shL[(t-128)*8]) =
        *reinterpret_cast<const f16x8*>(shfh + (t-128)*8);
    __syncthreads();
    dma_pair(Aa + go0,      Aa + go1,      lds,               t);
    dma_pair(Bb + go0,      Bb + go1,      lds + 4096,        t);
    dma_pair(Aa + 32 + go0, Aa + 32 + go1, lds + 8192,        t);
    dma_pair(Bb + 32 + go0, Bb + 32 + go1, lds + 8192 + 4096, t);
    int m = 0;
    for (int kt = 0; kt < 32; ++kt) {
        SCHED0; BARRIER; SCHED0;
        if (kt <= 29) {
            const int mp = (m >= 1) ? m - 1 : m + 2;
            const int k0 = (kt + 2) * 32;
            dma_pair(Aa + k0 + go0, Aa + k0 + go1, lds + mp*8192,        t);
            dma_pair(Bb + k0 + go0, Bb + k0 + go1, lds + mp*8192 + 4096, t);
            asm volatile("s_waitcnt vmcnt(8)" ::: "memory");
        } else if (kt == 30) {
            asm volatile("s_waitcnt vmcnt(4)" ::: "memory");
        } else {
            asm volatile("s_waitcnt vmcnt(0)" ::: "memory");
        }
        SCHED0; BARRIER; SCHED0;
        {
            f16* Bm = lds + m*8192 + 4096;
            const f16x8 csc = *reinterpret_cast<const f16x8*>(&scL[kt*32 + bnO]);
            const f16x8 csh = *reinterpret_cast<const f16x8*>(&shL[kt*32 + bnO]);
            f16x8 v0 = *reinterpret_cast<const f16x8*>(Bm + t*8);
            f16x8 v1 = *reinterpret_cast<const f16x8*>(Bm + 2048 + t*8);
            *reinterpret_cast<f16x8*>(Bm + t*8)        = bnl8(v0, csc, csh);
            *reinterpret_cast<f16x8*>(Bm + 2048 + t*8) = bnl8(v1, csc, csh);
        }
        asm volatile("s_waitcnt lgkmcnt(0)" ::: "memory");
        SCHED0; BARRIER; SCHED0;
        const f16* As = lds + m*8192;
        const f16* Bs = As + 4096;
        f16x8 a0 = *reinterpret_cast<const f16x8*>(As + offA0);
        f16x8 a1 = *reinterpret_cast<const f16x8*>(As + offA1);
        #pragma unroll
        for (int j = 0; j < 8; ++j) {
            f16x8 bj = *reinterpret_cast<const f16x8*>(Bs + offB[j]);
            acc[0][j] = __builtin_amdgcn_mfma_f32_16x16x32_f16(a0, bj, acc[0][j], 0, 0, 0);
            acc[1][j] = __builtin_amdgcn_mfma_f32_16x16x32_f16(a1, bj, acc[1][j], 0, 0, 0);
        }
        m = (m == 2) ? 0 : m + 1;
    }
    #pragma unroll
    for (int i = 0; i < 2; ++i) {
        #pragma unroll
        for (int r = 0; r < 4; ++r) {
            int o = o0 + 32*wave + 16*i + quad*4 + r;
            #pragma unroll
            for (int j = 0; j < 8; ++j) {
                int q = 16*j + l16;
                out7[((size_t)b*512 + o)*128 + q] = (f16)(acc[i][j][r] + biasv[i*4+r]);
            }
        }
    }
}

// ---------------- MFMA d1 (f16 output + fused stats) ----------------
__global__ __launch_bounds__(256) void k_mfma_d1(
    const f16* __restrict__ dW1h, const f16* __restrict__ out7,
    f16* __restrict__ d1pre, float* __restrict__ pD1)
{
    __shared__ __align__(16) f16 As[64][44];
    __shared__ __align__(16) f16 Bs[128][44];
    __shared__ float redd[128];
    const int b = blockIdx.y, o0 = blockIdx.x * 128;
    const int t = threadIdx.x;
    const int wave = t >> 6, lane = t & 63;
    const int quad = lane >> 4, l16 = lane & 15;
    const int row0 = t >> 2, grp = t & 3;
    const f16* Bb = out7 + (size_t)b*65536;
    f32x4 acc[8];
    #pragma unroll
    for (int j = 0; j < 8; ++j) acc[j] = (f32x4){0.f,0.f,0.f,0.f};
    for (int k0 = 0; k0 < 128; k0 += 32) {
        *reinterpret_cast<f16x8*>(&As[row0][grp*8]) =
            *reinterpret_cast<const f16x8*>(dW1h + row0*128 + k0 + grp*8);
        #pragma unroll
        for (int p = 0; p < 2; ++p) {
            const int row = row0 + 64*p;
            *reinterpret_cast<f16x8*>(&Bs[row][grp*8]) =
                *reinterpret_cast<const f16x8*>(Bb + (size_t)(o0+row)*128 + k0 + grp*8);
        }
        __syncthreads();
        f16x8 a0 = *reinterpret_cast<const f16x8*>(&As[16*wave + l16][quad*8]);
        #pragma unroll
        for (int j = 0; j < 8; ++j) {
            f16x8 bj = *reinterpret_cast<const f16x8*>(&Bs[16*j + l16][quad*8]);
            acc[j] = __builtin_amdgcn_mfma_f32_16x16x32_f16(a0, bj, acc[j], 0, 0, 0);
        }
        __syncthreads();
    }
    float sd[4] = {0,0,0,0}, s2d[4] = {0,0,0,0};
    #pragma unroll
    for (int r = 0; r < 4; ++r) {
        int d = 16*wave + quad*4 + r;
        #pragma unroll
        for (int j = 0; j < 8; ++j) {
            int o = o0 + 16*j + l16;
            float v = acc[j][r];
            d1pre[(size_t)b*32768 + (size_t)d*512 + o] = (f16)v;
            sd[r] += v; s2d[r] += v*v;
        }
    }
    #pragma unroll
    for (int r = 0; r < 4; ++r) {
        sd[r]  += __shfl_xor(sd[r],1);  sd[r]  += __shfl_xor(sd[r],2);
        sd[r]  += __shfl_xor(sd[r],4);  sd[r]  += __shfl_xor(sd[r],8);
        s2d[r] += __shfl_xor(s2d[r],1); s2d[r] += __shfl_xor(s2d[r],2);
        s2d[r] += __shfl_xor(s2d[r],4); s2d[r] += __shfl_xor(s2d[r],8);
    }
    if (l16 == 0) {
        #pragma unroll
        for (int r = 0; r < 4; ++r) {
            int dd = 16*wave + quad*4 + r;
            redd[dd] = sd[r]; redd[64 + dd] = s2d[r];
        }
    }
    __syncthreads();
    if (t < 128) pD1[((size_t)(blockIdx.x*512 + b))*128 + t] = redd[t];
}

// d2: C[e,o] = sum_d dW2[e,d] * lrelu(sc*d1pre[b][d][o]+sh)  (d1pre f16) + fused stats
__global__ __launch_bounds__(128) void k_gemm_d2(
    const float* __restrict__ dW2, const f16* __restrict__ d1pre,
    const float* __restrict__ scd, const float* __restrict__ shd,
    float* __restrict__ d2pre, float* __restrict__ pD2)
{
    __shared__ __align__(16) float As[16][36];
    __shared__ __align__(16) float Bs[16][68];
    __shared__ float sred[64];
    const int n0 = blockIdx.x * 64, b = blockIdx.y;
    const int t = threadIdx.x;
    const int kk = t & 15, ri = t >> 4;
    const int qv = t & 63, kh = t >> 6;
    const int tx = t & 15, ty = t >> 4;
    float acc[4][4] = {{0.f,0.f,0.f,0.f},{0.f,0.f,0.f,0.f},{0.f,0.f,0.f,0.f},{0.f,0.f,0.f,0.f}};
    for (int k0 = 0; k0 < 64; k0 += 16) {
        #pragma unroll
        for (int mm = 0; mm < 4; ++mm)
            As[kk][ri + mm*8] = dW2[(ri + mm*8)*64 + k0 + kk];
        #pragma unroll
        for (int ki = 0; ki < 8; ++ki) {
            int d = k0 + kh + ki*2;
            float v = (float)d1pre[(size_t)b*32768 + (size_t)d*512 + n0 + qv];
            Bs[kh + ki*2][qv] = lrelu(fmaf(scd[d], v, shd[d]));
        }
        __syncthreads();
        #pragma unroll
        for (int kq = 0; kq < 16; ++kq) {
            const float4 av = *reinterpret_cast<const float4*>(&As[kq][ty*4]);
            const float4 bv = *reinterpret_cast<const float4*>(&Bs[kq][tx*4]);
            FMA44(av, bv);
        }
        __syncthreads();
    }
    #pragma unroll
    for (int i = 0; i < 4; ++i) {
        float s = 0.f, s2 = 0.f;
        #pragma unroll
        for (int j = 0; j < 4; ++j) {
            float v = acc[i][j];
            d2pre[(size_t)b*16384 + (size_t)(ty*4 + i)*512 + n0 + tx*4 + j] = v;
            s += v; s2 += v*v;
        }
        s  += __shfl_xor(s,1);  s  += __shfl_xor(s,2);
        s  += __shfl_xor(s,4);  s  += __shfl_xor(s,8);
        s2 += __shfl_xor(s2,1); s2 += __shfl_xor(s2,2);
        s2 += __shfl_xor(s2,4); s2 += __shfl_xor(s2,8);
        if (tx == 0) {
            int e = ty*4 + i;
            sred[e] = s; sred[32 + e] = s2;
        }
    }
    __syncthreads();
    if (t < 64) pD2[((size_t)(blockIdx.y*8 + blockIdx.x))*64 + t] = sred[t];
}

__global__ __launch_bounds__(256) void k_d3(
    const float* __restrict__ d2pre, const float* __restrict__ dW3,
    const float* __restrict__ sce, const float* __restrict__ she,
    const float* __restrict__ dbias3, float* __restrict__ out)
{
    const int idx = blockIdx.x*256 + threadIdx.x;
    const int b = idx >> 9, o = idx & 511;
    float s = dbias3[0];
    for (int e = 0; e < 32; ++e) {
        float v = d2pre[(size_t)b*16384 + e*512 + o];
        s = fmaf(dW3[e], lrelu(fmaf(v, sce[e], she[e])), s);
    }
    out[idx] = s;
}

extern "C" void kernel_launch(void* const* d_in, const int* in_sizes, int n_in,
                              void* d_out, int out_size, void* d_ws, size_t ws_size,
                              hipStream_t stream)
{
    (void)in_sizes; (void)n_in; (void)out_size;
    const float* x      = (const float*)d_in[0];
    const float* gumbel = (const float*)d_in[1];
    const float* cW1 = (const float*)d_in[2];
    const float* cg1 = (const float*)d_in[3];
    const float* cb1 = (const float*)d_in[4];
    const float* cW2 = (const float*)d_in[5];
    const float* cg2 = (const float*)d_in[6];
    const float* cb2 = (const float*)d_in[7];
    const float* cW3 = (const float*)d_in[8];
    const float* cg3 = (const float*)d_in[9];
    const float* cb3 = (const float*)d_in[10];
    const float* eW1 = (const float*)d_in[11];
    const float* eg1 = (const float*)d_in[12];
    const float* eb1 = (const float*)d_in[13];
    const float* eW2 = (const float*)d_in[14];
    const float* eg2 = (const float*)d_in[15];
    const float* eb2 = (const float*)d_in[16];
    const float* eW3 = (const float*)d_in[17];
    const float* eg3 = (const float*)d_in[18];
    const float* eb3 = (const float*)d_in[19];
    const float* fW1 = (const float*)d_in[20];
    const float* fg1 = (const float*)d_in[21];
    const float* fb1 = (const float*)d_in[22];
    const float* fW2 = (const float*)d_in[23];
    const float* fbias2 = (const float*)d_in[24];
    const float* dW1 = (const float*)d_in[25];
    const float* dg1 = (const float*)d_in[26];
    const float* db1 = (const float*)d_in[27];
    const float* dW2 = (const float*)d_in[28];
    const float* dg2 = (const float*)d_in[29];
    const float* db2 = (const float*)d_in[30];
    const float* dW3 = (const float*)d_in[31];
    const float* dbias3 = (const float*)d_in[32];
    float* out = (float*)d_out;
    float* ws  = (float*)d_ws;

    if (ws_size < O_END * sizeof(float)) {
        k_sentinel<<<1024,256,0,stream>>>(out);
        return;
    }

    float* H1  = ws + O_H1;
    float* H2  = ws + O_H2;
    float* L   = ws + O_L;
    int*   sel = (int*)(ws + O_SEL);
    float* S   = ws + O_S;
    float* S2  = ws + O_S2;
    float* val = ws + O_VAL;
    float* prm = ws + O_PRM;
    f16*   fW1h= (f16*)(ws + O_FW1H);
    f16*   fW2h= (f16*)(ws + O_FW2H);
    float* accF= ws + O_ACCF;
    f16*   dW1h= (f16*)(ws + O_DW1H);
    f16*   eW3h= (f16*)(ws + O_EW3H);
    float* V2s = ws + O_V2SS;
    float* u1  = ws + O_U1;
    float* P1  = ws + O_P1;
    float* fzT = ws + O_FZT;
    float* V3s = ws + O_V3S;
    float* pF  = ws + O_PF;             // fw1 stats partials (H1+H2)
    float* pD1 = ws + O_PD1;            // d1 stats partials (H2; pF dead by then)
    float* pD2 = ws + O_PD2;
    float* p2d = ws + O_P1;             // stats2d partials (P1 written later)
    float* pE3 = ws + O_FZT;            // e3 stats partials (fzT dead after k_p1)
    f16*   V3xT= (f16*)(ws + O_BIG1);
    f16*   out7= (f16*)(ws + O_BIG1);   // aliases V3xT (dead after fw1)
    f16*   out6T=(f16*)(ws + O_BIG2);
    f16*   V2x = (f16*)(ws + O_BIG2);   // aliases out6T
    f16*   d1p = (f16*)(ws + O_D1);     // f16; aliases out6T (dead after fw2)
    float* d2p = ws + O_D2;

    const float invN_e = 1.0f/1310720.f;

    // ---- c-path (deterministic fp32; feeds argmax) ----
    k_gemm_c<<<dim3(16,8),256,0,stream>>>(x,  cW1, H1, 1024, 512,  nullptr,     nullptr);
    k_stats2d_p<<<dim3(32,1),256,0,stream>>>(H1, 1024, p2d);
    k_finalize_p<<<4,256,0,stream>>>(p2d, 1024, 32, 1.0f/512.f, cg1, cb1,
                                     prm+P_SC1, prm+P_SH1, nullptr, nullptr);
    k_gemm_c<<<dim3(16,8),256,0,stream>>>(H1, cW2, H2, 1024, 1024, prm+P_SC1, prm+P_SH1);
    k_stats2d_p<<<dim3(32,1),256,0,stream>>>(H2, 1024, p2d);
    k_finalize_p<<<4,256,0,stream>>>(p2d, 1024, 32, 1.0f/512.f, cg2, cb2,
                                     prm+P_SC2, prm+P_SH2, nullptr, nullptr);
    k_gemm_c<<<dim3(32,8),256,0,stream>>>(H2, cW3, L,  2048, 1024, prm+P_SC2, prm+P_SH2);
    k_stats2d_p<<<dim3(32,2),256,0,stream>>>(L, 2048, p2d);
    k_finalize_p<<<8,256,0,stream>>>(p2d, 2048, 32, 1.0f/512.f, cg3, cb3,
                                     prm+P_SC3, prm+P_SH3, nullptr, nullptr);
    k_sel<<<512,256,0,stream>>>(L, gumbel, prm+P_SC3, prm+P_SH3, sel);

    // ---- weight prep (overwrites L region) + selection-derived helpers ----
    k_prep<<<2048,256,0,stream>>>(fW1, fW2, dW1, eW3, fW1h, fW2h, dW1h, eW3h, accF);
    k_val<<<512,256,0,stream>>>(x, S, S2, val);
    k_e1params<<<1,256,0,stream>>>(S, S2, val, eW1, eg1, eb1, prm+P_A1, prm+P_C1, prm+P_ACC2);
    k_transpose_fz<<<dim3(32,16),256,0,stream>>>(fW1, fzT);
    k_wtrans2<<<1,256,0,stream>>>(eW2, prm+P_EW2T);
    k_ftot<<<4,256,0,stream>>>(fzT, prm+P_FTOT);
    k_p1<<<512,256,0,stream>>>(fzT, sel, P1);

    // ---- e-path ----
    k_epass2<<<1024,256,0,stream>>>(x, prm+P_A1, prm+P_C1, prm+P_EW2T, V2x);
    k_esupport2<<<513,64,0,stream>>>(val, prm+P_A1, prm+P_C1, prm+P_EW2T, V2s);
    k_stats_v2scan<<<64,256,0,stream>>>(V2x, prm+P_ACC2);
    k_wstats<<<64,64,0,stream>>>(V2s, 64, prm+P_ACC2);
    k_finalize<<<1,256,0,stream>>>(prm+P_ACC2, 64, invN_e, eg2, eb2, prm+P_SCE2, prm+P_SHE2,
                                   (f16*)(prm+P_SCE2H), (f16*)(prm+P_SHE2H));
    k_mfma_e3<<<dim3(4,512),256,0,stream>>>(eW3h, V2x,
                                            (const f16*)(prm+P_SCE2H), (const f16*)(prm+P_SHE2H),
                                            V3xT, pE3);
    k_esupport3<<<513,128,0,stream>>>(V2s, prm+P_SCE2, prm+P_SHE2, eW3, V3s);
    k_wstats<<<128,64,0,stream>>>(V3s, 128, prm+P_ACC3);
    k_finalize_e3<<<1,256,0,stream>>>(pE3, prm+P_ACC3, eg3, eb3, prm+P_SCE3, prm+P_SHE3,
                                      (f16*)(prm+P_SCE3H), (f16*)(prm+P_SHE3H));
    k_u<<<257,256,0,stream>>>(V3s, prm+P_SCE3, prm+P_SHE3, u1, prm+P_U0);

    // ---- f-path (MFMA f16) ----
    k_mfma_fw1T<<<dim3(8,512),256,0,stream>>>(fW1h, V3xT,
                                              (const f16*)(prm+P_SCE3H), (const f16*)(prm+P_SHE3H),
                                              u1, prm+P_U0, P1, prm+P_FTOT, out6T, pF);
    k_finalize_f<<<4,256,0,stream>>>(pF, fg1, fb1, prm+P_SCF1, prm+P_SHF1,
                                     (f16*)(prm+P_SCF1H), (f16*)(prm+P_SHF1H));
    k_mfma_fw2T<<<dim3(4,512),256,0,stream>>>(fW2h, out6T,
                                              (const f16*)(prm+P_SCF1H), (const f16*)(prm+P_SHF1H),
                                              fbias2, out7);

    // ---- d-path ----
    k_mfma_d1<<<dim3(4,512),256,0,stream>>>(dW1h, out7, d1p, pD1);
    k_finalize_d1<<<1,256,0,stream>>>(pD1, dg1, db1, prm+P_SCD1, prm+P_SHD1);
    k_gemm_d2<<<dim3(8,512),128,0,stream>>>(dW2, d1p, prm+P_SCD1, prm+P_SHD1, d2p, pD2);
    k_finalize_d2<<<1,256,0,stream>>>(pD2, dg2, db2, prm+P_SCD2, prm+P_SHD2);
    k_d3<<<1024,256,0,stream>>>(d2p, dW3, prm+P_SCD2, prm+P_SHD2, dbias3, out);
}

// Round 11
// 881.018 us; speedup vs baseline: 1.0690x; 1.0492x over previous
//
#include <hip/hip_runtime.h>
#include <cstddef>

#define DEV __device__ __forceinline__
DEV float lrelu(float x){ return x >= 0.0f ? x : 0.2f*x; }
typedef _Float16 f16;
typedef _Float16 f16x8 __attribute__((ext_vector_type(8)));
typedef float f32x4 __attribute__((ext_vector_type(4)));

DEV f16x8 splat8(f16 s){ f16x8 v = {s,s,s,s,s,s,s,s}; return v; }
// packed BN + lrelu in f16: lrelu(v*sc+sh) with exact max/min formulation
DEV f16x8 bnl8(f16x8 v, f16x8 sc, f16x8 sh){
    f16x8 t = v*sc + sh;                       // v_pk_fma_f16
    f16x8 z = splat8((f16)0.0f);
    f16x8 mx = __builtin_elementwise_max(t, z);
    f16x8 mn = __builtin_elementwise_min(t, z);
    return mx + mn*splat8((f16)0.2f);
}

// async global->LDS, 16B per lane (raw staging, no VGPR roundtrip)
DEV void gload_lds16(const f16* src, f16* dst){
    __builtin_amdgcn_global_load_lds(
        (const __attribute__((address_space(1))) void*)src,
        (__attribute__((address_space(3))) void*)dst, 16, 0, 0);
}

// stage a 128x32 tile half-pair: slots t (rows 0..63) and 256+t (rows 64..127).
DEV void dma_pair(const f16* g0, const f16* g1, f16* ldsbase, int t){
    gload_lds16(g0, ldsbase + t*8);
    gload_lds16(g1, ldsbase + 2048 + t*8);
}
// reader-side swizzled f16 index for (row r, k-granule g)
DEV int swz_off(int r, int g){ return r*32 + ((g ^ ((r>>1)&3))<<3); }

#define SCHED0 __builtin_amdgcn_sched_barrier(0)
#define BARRIER __builtin_amdgcn_s_barrier()

// Problem dims: B=512, IN=512, CB=8, HD=256, CH=2048, CC=2560, EXP=128, FC1=1024, OUT=512
constexpr int NXPT = 512*512;     // dense support points (b,l<512)

// ---------------- workspace layout (float offsets) ----------------
constexpr size_t O_H1  = 0;                       // 512x1024 f32
constexpr size_t O_H2  = O_H1 + 512*1024;         // 512x1024 f32
constexpr size_t O_L   = O_H2 + 512*1024;         // 512x2048 f32 (c3 logits; dead after k_sel)
constexpr size_t O_SEL = O_L  + 512*2048;         // int32 512x256
constexpr size_t O_S   = O_SEL + 512*256;
constexpr size_t O_S2  = O_S + 512;
constexpr size_t O_VAL = O_S2 + 512;
constexpr size_t O_PRM = O_VAL + 512;
// params sub-offsets (within PRM)
constexpr size_t P_SC1=0, P_SH1=1024, P_SC2=2048, P_SH2=3072, P_SC3=4096, P_SH3=6144;
constexpr size_t P_A1=8192, P_C1=8224, P_EW2T=8256 /*2048*/;
constexpr size_t P_ACC2=18496 /*128*/, P_ACC3=18624 /*256*/;
constexpr size_t P_SCE2=18880, P_SHE2=18944, P_SCE3=19008, P_SHE3=19136;
constexpr size_t P_U0=19264 /*128*/, P_FTOT=19392 /*1024*/;
constexpr size_t P_SCF1=20416, P_SHF1=21440;
constexpr size_t P_SCD1=22464, P_SHD1=22528, P_SCD2=22592, P_SHD2=22624;
// f16 copies of BN affine params (for packed-f16 MFMA staging)
constexpr size_t P_SCE3H=22656, P_SHE3H=22720;    // 128 f16 each (64 floats)
constexpr size_t P_SCF1H=22784, P_SHF1H=23296;    // 1024 f16 each (512 floats)
constexpr size_t P_SCE2H=23808, P_SHE2H=23840;    // 64 f16 each (32 floats)
constexpr size_t PRM_SIZE = 32768;
// stats partial buffers (all alias dead regions)
constexpr size_t O_PF  = O_H1;                    // fw1 stats partials: 4096 x 256 f32 (H1+H2); ALSO ftot partials (earlier)
constexpr size_t O_PD1 = O_H2;                    // d1 stats partials: 2048 x 128 f32 (after pF dead)
constexpr size_t O_PD2 = O_H2 + 262144;           // d2 stats partials: 4096 x 64 f32
// weight copies + V2s ALIAS the dead L buffer (written after k_sel)
constexpr size_t O_FW1H = O_L;                    // f16 1024x512   (262144 floats)
constexpr size_t O_FW2H = O_L + 262144;           // f16 512x1024   (262144 floats)
constexpr size_t O_ACCF = O_L + 524288;           // f32 2048 (legacy zero region)
constexpr size_t O_DW1H = O_L + 528384;           // f16 64x128  (4096 floats)
constexpr size_t O_EW3H = O_L + 532480;           // f16 128x64  (4096 floats)
constexpr size_t O_V2SS = O_L + 536576;           // f32 513x64  (32832 floats)
constexpr size_t O_U1  = O_PRM + PRM_SIZE;        // 512x128 f32
constexpr size_t O_P1  = O_U1 + 512*128;          // 512x1024 f32; ALSO stats2d partials (before k_p1)
constexpr size_t O_FZT = O_P1 + 512*1024;         // 2048x1024 f32 (fW1 z-part T); pE3 aliases after k_p1
constexpr size_t O_V3S = O_FZT + (size_t)2048*1024;   // 513x128 f32
constexpr size_t O_BIG1= O_V3S + 513*128;             // f16 512*128*512  (V3xT, later out7)
constexpr size_t O_BIG2= O_BIG1 + (size_t)512*512*128/2; // f16 512*128*1024 (out6T); V2x + d1p alias
constexpr size_t O_D1  = O_BIG2;                      // f16 512*64*512 (aliases out6T, dead after fw2)
constexpr size_t O_D2  = O_BIG2 + (size_t)512*64*512; // f16 512*32*512 now
constexpr size_t O_END = O_BIG2 + (size_t)512*1024*128/2;   // ~211 MB

#define FMA44(av,bv) do{ \
  acc[0][0]=fmaf(av.x,bv.x,acc[0][0]); acc[0][1]=fmaf(av.x,bv.y,acc[0][1]); \
  acc[0][2]=fmaf(av.x,bv.z,acc[0][2]); acc[0][3]=fmaf(av.x,bv.w,acc[0][3]); \
  acc[1][0]=fmaf(av.y,bv.x,acc[1][0]); acc[1][1]=fmaf(av.y,bv.y,acc[1][1]); \
  acc[1][2]=fmaf(av.y,bv.z,acc[1][2]); acc[1][3]=fmaf(av.y,bv.w,acc[1][3]); \
  acc[2][0]=fmaf(av.z,bv.x,acc[2][0]); acc[2][1]=fmaf(av.z,bv.y,acc[2][1]); \
  acc[2][2]=fmaf(av.z,bv.z,acc[2][2]); acc[2][3]=fmaf(av.z,bv.w,acc[2][3]); \
  acc[3][0]=fmaf(av.w,bv.x,acc[3][0]); acc[3][1]=fmaf(av.w,bv.y,acc[3][1]); \
  acc[3][2]=fmaf(av.w,bv.z,acc[3][2]); acc[3][3]=fmaf(av.w,bv.w,acc[3][3]); \
}while(0)

__global__ void k_sentinel(float* out){ out[blockIdx.x*256 + threadIdx.x] = 1.0e6f; }

// prep: f16 weight copies, zero legacy accumulators. Runs AFTER k_sel (aliases L).
__global__ __launch_bounds__(256) void k_prep(
    const float* __restrict__ fW1, const float* __restrict__ fW2,
    const float* __restrict__ dW1, const float* __restrict__ eW3,
    f16* __restrict__ fW1h, f16* __restrict__ fW2h, f16* __restrict__ dW1h,
    f16* __restrict__ eW3h, float* __restrict__ accAll)
{
    const int i = blockIdx.x*256 + threadIdx.x;   // 524288 threads
    int f = i >> 9, l = i & 511;
    fW1h[i] = (f16)fW1[(size_t)f*2560 + l];       // x-part only (cols 0..511)
    fW2h[i] = (f16)fW2[i];
    if (i < 8192) { dW1h[i] = (f16)dW1[i]; eW3h[i] = (f16)eW3[i]; }
    if (i < 4096) accAll[i] = 0.f;
}

// ---------------- c-layers (NT, fp32: feeds argmax) ----------------
__global__ __launch_bounds__(256) void k_gemm_c(
    const float* __restrict__ A, const float* __restrict__ W, float* __restrict__ C,
    int N, int K, const float* __restrict__ sc, const float* __restrict__ sh)
{
    __shared__ __align__(16) float As[16][68];
    __shared__ __align__(16) float Ws[16][68];
    const int n0 = blockIdx.x * 64, m0 = blockIdx.y * 64;
    const int t = threadIdx.x;
    const int kk = t & 15, ri = t >> 4;
    const int tx = t & 15, ty = t >> 4;
    float acc[4][4] = {{0.f,0.f,0.f,0.f},{0.f,0.f,0.f,0.f},{0.f,0.f,0.f,0.f},{0.f,0.f,0.f,0.f}};
    for (int k0 = 0; k0 < K; k0 += 16) {
        float scv = 0.f, shv = 0.f;
        if (sc) { scv = sc[k0+kk]; shv = sh[k0+kk]; }
        #pragma unroll
        for (int mm = 0; mm < 4; ++mm) {
            float v = A[(size_t)(m0 + ri + mm*16) * K + k0 + kk];
            if (sc) v = lrelu(fmaf(v, scv, shv));
            As[kk][ri + mm*16] = v;
        }
        #pragma unroll
        for (int nn = 0; nn < 4; ++nn)
            Ws[kk][ri + nn*16] = W[(size_t)(n0 + ri + nn*16) * K + k0 + kk];
        __syncthreads();
        #pragma unroll
        for (int kq = 0; kq < 16; ++kq) {
            const float4 av = *reinterpret_cast<const float4*>(&As[kq][ty*4]);
            const float4 bv = *reinterpret_cast<const float4*>(&Ws[kq][tx*4]);
            FMA44(av, bv);
        }
        __syncthreads();
    }
    #pragma unroll
    for (int i = 0; i < 4; ++i)
        #pragma unroll
        for (int j = 0; j < 4; ++j)
            C[(size_t)(m0 + ty*4 + i) * N + n0 + tx*4 + j] = acc[i][j];
}

// coalesced column-stats partials for f32 buf[512][C]
__global__ __launch_bounds__(256) void k_stats2d_p(
    const float* __restrict__ buf, int C, float* __restrict__ part)
{
    const int t = threadIdx.x;
    const int r0 = blockIdx.x*16;
    const int c0 = blockIdx.y*1024;
    float s[4]={0.f,0.f,0.f,0.f}, s2[4]={0.f,0.f,0.f,0.f};
    for (int rr = 0; rr < 16; ++rr) {
        float4 v = *reinterpret_cast<const float4*>(buf + (size_t)(r0+rr)*C + c0 + t*4);
        s[0]+=v.x; s[1]+=v.y; s[2]+=v.z; s[3]+=v.w;
        s2[0]+=v.x*v.x; s2[1]+=v.y*v.y; s2[2]+=v.z*v.z; s2[3]+=v.w*v.w;
    }
    float* d0 = part + (size_t)blockIdx.x*2*C + c0 + t*4;
    *reinterpret_cast<float4*>(d0)     = (float4){s[0],s[1],s[2],s[3]};
    *reinterpret_cast<float4*>(d0 + C) = (float4){s2[0],s2[1],s2[2],s2[3]};
}

__global__ __launch_bounds__(256) void k_sel(
    const float* __restrict__ Lpre, const float* __restrict__ gumbel,
    const float* __restrict__ sc, const float* __restrict__ sh, int* __restrict__ sel)
{
    const int b = blockIdx.x, hd = threadIdx.x;
    float best = -3.0e38f; int bi = 0;
    #pragma unroll
    for (int cb = 0; cb < 8; ++cb) {
        int c = cb*256 + hd;
        float v = lrelu(fmaf(Lpre[(size_t)b*2048 + c], sc[c], sh[c])) + gumbel[(size_t)b*2048 + c];
        if (v > best) { best = v; bi = cb; }
    }
    sel[b*256 + hd] = bi;
}

__global__ __launch_bounds__(256) void k_val(const float* __restrict__ x,
    float* __restrict__ S, float* __restrict__ S2, float* __restrict__ val)
{
    const int b = blockIdx.x, t = threadIdx.x;
    float v0 = x[b*512 + t], v1 = x[b*512 + t + 256];
    __shared__ float ls[256], ls2[256];
    ls[t] = v0 + v1; ls2[t] = v0*v0 + v1*v1;
    __syncthreads();
    for (int off = 128; off; off >>= 1) { if (t < off) { ls[t]+=ls[t+off]; ls2[t]+=ls2[t+off]; } __syncthreads(); }
    if (t == 0) { float s = ls[0], s2 = ls2[0]; S[b]=s; S2[b]=s2; val[b]=0.5f*(s*s - s2); }
}

__global__ __launch_bounds__(256) void k_e1params(
    const float* __restrict__ S, const float* __restrict__ S2, const float* __restrict__ val,
    const float* __restrict__ eW1, const float* __restrict__ eg1, const float* __restrict__ eb1,
    float* __restrict__ A1, float* __restrict__ C1, float* __restrict__ accs /*384*/)
{
    const int t = threadIdx.x;
    accs[t] = 0.f; if (t < 128) accs[256 + t] = 0.f;
    __shared__ float ls[256], ls2[256];
    float s = 0.f, s2 = 0.f;
    for (int b = t; b < 512; b += 256) {
        float vb = val[b];
        s  += S[b]  + 256.f*vb;
        s2 += S2[b] + 256.f*vb*vb;
    }
    ls[t] = s; ls2[t] = s2; __syncthreads();
    for (int off = 128; off; off >>= 1) { if (t < off) { ls[t]+=ls[t+off]; ls2[t]+=ls2[t+off]; } __syncthreads(); }
    if (t < 32) {
        const float invn = 1.0f/1310720.f;
        float mu = ls[0]*invn;
        float var = fmaxf(ls2[0]*invn - mu*mu, 0.f);
        float w = eW1[t];
        float rs = 1.0f / sqrtf(w*w*var + 1e-5f);
        float a = w * eg1[t] * rs;
        A1[t] = a; C1[t] = eb1[t] - mu*a;
    }
}

// transpose eW2 (64x32)->(32x64)
__global__ void k_wtrans2(const float* __restrict__ eW2, float* __restrict__ eW2T)
{
    const int t = threadIdx.x;
    for (int i = t; i < 2048; i += 256) { int p = i >> 5, o = i & 31; eW2T[o*64 + p] = eW2[i]; }
}

__global__ __launch_bounds__(256) void k_transpose_fz(const float* __restrict__ fW1, float* __restrict__ fzT)
{
    __shared__ float tile[64][65];
    const int z0 = blockIdx.x*64, f0 = blockIdx.y*64;
    const int j = threadIdx.x & 63, i0 = threadIdx.x >> 6;
    #pragma unroll
    for (int ii = 0; ii < 16; ++ii) {
        int fi = i0*16 + ii;
        tile[fi][j] = fW1[(size_t)(f0+fi)*2560 + 512 + z0 + j];
    }
    __syncthreads();
    #pragma unroll
    for (int ii = 0; ii < 16; ++ii) {
        int zi = i0*16 + ii;
        fzT[(size_t)(z0+zi)*1024 + f0 + j] = tile[j][zi];
    }
}

// parallel ftot: grid (4,16); block sums 128 z-rows over 256 f-cols -> part[zc][1024]
__global__ __launch_bounds__(256) void k_ftot_p(const float* __restrict__ fzT, float* __restrict__ part)
{
    const int f = blockIdx.x*256 + threadIdx.x;
    const int z0 = blockIdx.y*128;
    float s = 0.f;
    for (int z = z0; z < z0 + 128; ++z) s += fzT[(size_t)z*1024 + f];
    part[(size_t)blockIdx.y*1024 + f] = s;
}
__global__ __launch_bounds__(256) void k_ftot_s(const float* __restrict__ part, float* __restrict__ Ftot)
{
    const int f = blockIdx.x*256 + threadIdx.x;
    float s = 0.f;
    #pragma unroll
    for (int zc = 0; zc < 16; ++zc) s += part[(size_t)zc*1024 + f];
    Ftot[f] = s;
}

__global__ __launch_bounds__(256) void k_p1(const float* __restrict__ fzT, const int* __restrict__ sel,
                                            float* __restrict__ P1)
{
    const int b = blockIdx.x, t = threadIdx.x;
    float a0=0.f, a1=0.f, a2=0.f, a3=0.f;
    for (int hd = 0; hd < 256; ++hd) {
        int col = sel[b*256 + hd]*256 + hd;
        const float* r = fzT + (size_t)col*1024;
        a0 += r[t]; a1 += r[t+256]; a2 += r[t+512]; a3 += r[t+768];
    }
    P1[b*1024 + t] = a0; P1[b*1024 + t + 256] = a1; P1[b*1024 + t + 512] = a2; P1[b*1024 + t + 768] = a3;
}

// e2 main points: v2 = eW2 * lrelu(A1*x+C1); write V2x[pt][d] f16. NO stats.
__global__ __launch_bounds__(256) void k_epass2(
    const float* __restrict__ x,
    const float* __restrict__ A1, const float* __restrict__ C1,
    const float* __restrict__ eW2T, f16* __restrict__ V2x)
{
    __shared__ float sW[2048], sA[32], sC[32];
    const int t = threadIdx.x;
    #pragma unroll
    for (int i = 0; i < 8; ++i) sW[t + 256*i] = eW2T[t + 256*i];
    if (t < 32) { sA[t] = A1[t]; sC[t] = C1[t]; }
    __syncthreads();
    const int pt = blockIdx.x*256 + t;
    float phi = x[pt];
    float v2[64];
    #pragma unroll
    for (int p = 0; p < 64; ++p) v2[p] = 0.f;
    for (int o = 0; o < 32; ++o) {
        float t1 = lrelu(fmaf(sA[o], phi, sC[o]));
        #pragma unroll
        for (int p = 0; p < 64; ++p) v2[p] = fmaf(sW[o*64 + p], t1, v2[p]);
    }
    f16* dst = V2x + (size_t)pt*64;
    #pragma unroll
    for (int dd = 0; dd < 64; dd += 8) {
        f16x8 o;
        #pragma unroll
        for (int e = 0; e < 8; ++e) o[e] = (f16)v2[dd+e];
        *reinterpret_cast<f16x8*>(dst + dd) = o;
    }
}

// e2 support points
__global__ __launch_bounds__(64) void k_esupport2(
    const float* __restrict__ val,
    const float* __restrict__ A1, const float* __restrict__ C1,
    const float* __restrict__ eW2T, float* __restrict__ V2s)
{
    const int idx = blockIdx.x, d = threadIdx.x;
    float phi = (idx < 512) ? val[idx] : 0.f;
    __shared__ float t1s[32];
    if (d < 32) t1s[d] = lrelu(fmaf(A1[d], phi, C1[d]));
    __syncthreads();
    float s = 0.f;
    #pragma unroll
    for (int o = 0; o < 32; ++o) s = fmaf(eW2T[o*64 + d], t1s[o], s);
    V2s[idx*64 + d] = s;
}

// weighted column stats over V[513][C]: grid C blocks x 64 threads; 2 atomics/block
__global__ __launch_bounds__(64) void k_wstats(
    const float* __restrict__ V, int C, float* __restrict__ acc)
{
    const int c = blockIdx.x, lane = threadIdx.x;
    float s = 0.f, s2 = 0.f;
    for (int i = lane; i < 513; i += 64) {
        float w = (i < 512) ? 256.f : 917504.f;
        float v = V[(size_t)i*C + c];
        s += w*v; s2 += w*v*v;
    }
    #pragma unroll
    for (int off = 32; off; off >>= 1) { s += __shfl_xor(s, off); s2 += __shfl_xor(s2, off); }
    if (lane == 0) { atomicAdd(&acc[c], s); atomicAdd(&acc[C + c], s2); }
}

// e2 stats scan over V2x (262144 pts x 64 ch, f16). 64 blocks; 128 atomics/block.
__global__ __launch_bounds__(256) void k_stats_v2scan(const f16* __restrict__ V2x, float* __restrict__ acc2)
{
    const int t = threadIdx.x;
    const int wave = t >> 6, lane = t & 63;
    const int g = t & 7;
    const int slot = blockIdx.x*32 + (t >> 3);
    float s[8] = {0,0,0,0,0,0,0,0}, s2[8] = {0,0,0,0,0,0,0,0};
    for (int p = slot; p < NXPT; p += 2048) {
        f16x8 v = *reinterpret_cast<const f16x8*>(V2x + (size_t)p*64 + g*8);
        #pragma unroll
        for (int e = 0; e < 8; ++e) { float f = (float)v[e]; s[e] += f; s2[e] += f*f; }
    }
    #pragma unroll
    for (int off = 8; off <= 32; off <<= 1) {
        #pragma unroll
        for (int e = 0; e < 8; ++e) { s[e] += __shfl_xor(s[e], off); s2[e] += __shfl_xor(s2[e], off); }
    }
    __shared__ float red[4*128];
    if (lane < 8) {
        #pragma unroll
        for (int e = 0; e < 8; ++e) {
            red[wave*128 + lane*16 + e]     = s[e];
            red[wave*128 + lane*16 + 8 + e] = s2[e];
        }
    }
    __syncthreads();
    if (t < 128) {
        float v = red[t] + red[128 + t] + red[256 + t] + red[384 + t];
        int gg = t >> 4, k = t & 15;
        if (k < 8) atomicAdd(&acc2[gg*8 + k], v);
        else       atomicAdd(&acc2[64 + gg*8 + (k - 8)], v);
    }
}

__global__ void k_finalize(const float* __restrict__ acc, int C, float invn,
                           const float* __restrict__ g, const float* __restrict__ bb,
                           float* __restrict__ sc, float* __restrict__ sh,
                           f16* __restrict__ sch, f16* __restrict__ shh)
{
    const int idx = blockIdx.x*blockDim.x + threadIdx.x;
    if (idx < C) {
        float m = acc[idx] * invn;
        float var = fmaxf(acc[C + idx] * invn - m*m, 0.f);
        float r = 1.0f / sqrtf(var + 1e-5f);
        float s = g[idx] * r;
        float h = bb[idx] - m*s;
        sc[idx] = s; sh[idx] = h;
        if (sch) { sch[idx] = (f16)s; shh[idx] = (f16)h; }
    }
}

// finalize from contention-free partials: P = [nPart][2C] rows
__global__ void k_finalize_p(const float* __restrict__ P, int C, int nPart, float invn,
                             const float* __restrict__ g, const float* __restrict__ bb,
                             float* __restrict__ sc, float* __restrict__ sh,
                             f16* __restrict__ sch, f16* __restrict__ shh)
{
    const int idx = blockIdx.x*blockDim.x + threadIdx.x;
    if (idx < C) {
        float s = 0.f, s2 = 0.f;
        for (int p = 0; p < nPart; ++p) {
            s  += P[(size_t)p*2*C + idx];
            s2 += P[(size_t)p*2*C + C + idx];
        }
        float m = s * invn;
        float var = fmaxf(s2 * invn - m*m, 0.f);
        float r = 1.0f / sqrtf(var + 1e-5f);
        float sv = g[idx] * r;
        float h = bb[idx] - m*sv;
        sc[idx] = sv; sh[idx] = h;
        if (sch) { sch[idx] = (f16)sv; shh[idx] = (f16)h; }
    }
}

// finalize e3 BN: sum pE3 [2048][256] partials + wstats row accw[256]
__global__ __launch_bounds__(256) void k_finalize_e3(
    const float* __restrict__ P, const float* __restrict__ accw,
    const float* __restrict__ g, const float* __restrict__ bb,
    float* __restrict__ sc, float* __restrict__ sh,
    f16* __restrict__ sch, f16* __restrict__ shh)
{
    const int t = threadIdx.x, q = t & 127, h = t >> 7;
    float s = 0.f, s2 = 0.f;
    for (int p = h*1024; p < h*1024 + 1024; ++p) {
        s  += P[(size_t)p*256 + q];
        s2 += P[(size_t)p*256 + 128 + q];
    }
    __shared__ float red[2][2][128];
    red[h][0][q] = s; red[h][1][q] = s2;
    __syncthreads();
    if (t < 128) {
        float ss  = red[0][0][q] + red[1][0][q] + accw[q];
        float ss2 = red[0][1][q] + red[1][1][q] + accw[128 + q];
        const float invn = 1.0f/1310720.f;
        float m = ss * invn;
        float var = fmaxf(ss2 * invn - m*m, 0.f);
        float r = 1.0f / sqrtf(var + 1e-5f);
        float sv = g[q] * r, hh = bb[q] - m*sv;
        sc[q] = sv; sh[q] = hh; sch[q] = (f16)sv; shh[q] = (f16)hh;
    }
}

// finalize f-BN from pF [8 fblk][512 b][256]
__global__ __launch_bounds__(256) void k_finalize_f(
    const float* __restrict__ P,
    const float* __restrict__ g, const float* __restrict__ bb,
    float* __restrict__ sc, float* __restrict__ sh,
    f16* __restrict__ sch, f16* __restrict__ shh)
{
    const int f = blockIdx.x*256 + threadIdx.x;
    const int fb = f >> 7, c = f & 127;
    const float* base = P + (size_t)fb*512*256 + c;
    float s = 0.f, s2 = 0.f;
    for (int b = 0; b < 512; ++b) {
        s  += base[(size_t)b*256];
        s2 += base[(size_t)b*256 + 128];
    }
    float m = s*(1.0f/65536.f);
    float var = fmaxf(s2*(1.0f/65536.f) - m*m, 0.f);
    float r = 1.0f/sqrtf(var + 1e-5f);
    float sv = g[f]*r, h = bb[f] - m*sv;
    sc[f] = sv; sh[f] = h; sch[f] = (f16)sv; shh[f] = (f16)h;
}

// finalize d1-BN from pD1 [2048][128]
__global__ __launch_bounds__(256) void k_finalize_d1(
    const float* __restrict__ P,
    const float* __restrict__ g, const float* __restrict__ bb,
    float* __restrict__ sc, float* __restrict__ sh)
{
    const int t = threadIdx.x, d = t & 63, gr = t >> 6;  // 4 groups x 512 rows
    float s = 0.f, s2 = 0.f;
    for (int p = gr*512; p < gr*512 + 512; ++p) {
        s  += P[(size_t)p*128 + d];
        s2 += P[(size_t)p*128 + 64 + d];
    }
    __shared__ float red[4][2][64];
    red[gr][0][d] = s; red[gr][1][d] = s2;
    __syncthreads();
    if (t < 64) {
        float ss  = red[0][0][t]+red[1][0][t]+red[2][0][t]+red[3][0][t];
        float ss2 = red[0][1][t]+red[1][1][t]+red[2][1][t]+red[3][1][t];
        float m = ss*(1.0f/262144.f);
        float var = fmaxf(ss2*(1.0f/262144.f) - m*m, 0.f);
        float r = 1.0f/sqrtf(var + 1e-5f);
        float sv = g[t]*r;
        sc[t] = sv; sh[t] = bb[t] - m*sv;
    }
}

// finalize d2-BN from pD2 [4096][64] rows ([32 sums][32 sumsq])
__global__ __launch_bounds__(256) void k_finalize_d2(
    const float* __restrict__ P,
    const float* __restrict__ g, const float* __restrict__ bb,
    float* __restrict__ sc, float* __restrict__ sh)
{
    const int t = threadIdx.x, e = t & 31, gr = t >> 5;  // 8 groups x 512 rows
    float s = 0.f, s2 = 0.f;
    for (int p = gr*512; p < gr*512 + 512; ++p) {
        s  += P[(size_t)p*64 + e];
        s2 += P[(size_t)p*64 + 32 + e];
    }
    __shared__ float red[8][2][32];
    red[gr][0][e] = s; red[gr][1][e] = s2;
    __syncthreads();
    if (t < 32) {
        float ss = 0.f, ss2 = 0.f;
        #pragma unroll
        for (int k2 = 0; k2 < 8; ++k2) { ss += red[k2][0][t]; ss2 += red[k2][1][t]; }
        float m = ss*(1.0f/262144.f);
        float var = fmaxf(ss2*(1.0f/262144.f) - m*m, 0.f);
        float r = 1.0f/sqrtf(var + 1e-5f);
        float sv = g[t]*r;
        sc[t] = sv; sh[t] = bb[t] - m*sv;
    }
}

// MFMA e3 + fused V3xT stats partials; packed-f16 BN on V2x (sc2h/sh2h f16)
__global__ __launch_bounds__(256) void k_mfma_e3(
    const f16* __restrict__ eW3h, const f16* __restrict__ V2x,
    const f16* __restrict__ sc2h, const f16* __restrict__ sh2h,
    f16* __restrict__ V3xT, float* __restrict__ pE3)
{
    __shared__ __align__(16) f16 As[128][76];   // eW3 rows q, cols d
    __shared__ __align__(16) f16 Bs[128][76];   // t2 rows point, cols d
    __shared__ float rede[256];
    const int b = blockIdx.y, l0 = blockIdx.x * 128;
    const int t = threadIdx.x;
    const int wave = t >> 6, lane = t & 63;
    const int quad = lane >> 4, l16 = lane & 15;
    const int row = t >> 1, half = t & 1;
    #pragma unroll
    for (int c = 0; c < 4; ++c)
        *reinterpret_cast<f16x8*>(&As[row][half*32 + c*8]) =
            *reinterpret_cast<const f16x8*>(eW3h + row*64 + half*32 + c*8);
    const f16* src = V2x + ((size_t)(b*512 + l0 + row))*64 + half*32;
    #pragma unroll
    for (int c = 0; c < 4; ++c) {
        f16x8 v = *reinterpret_cast<const f16x8*>(src + c*8);
        const f16x8 csc = *reinterpret_cast<const f16x8*>(sc2h + half*32 + c*8);
        const f16x8 csh = *reinterpret_cast<const f16x8*>(sh2h + half*32 + c*8);
        *reinterpret_cast<f16x8*>(&Bs[row][half*32 + c*8]) = bnl8(v, csc, csh);
    }
    __syncthreads();
    f32x4 acc[2][8];
    #pragma unroll
    for (int i = 0; i < 2; ++i)
        #pragma unroll
        for (int j = 0; j < 8; ++j) acc[i][j] = (f32x4){0.f,0.f,0.f,0.f};
    f16x8 a0  = *reinterpret_cast<const f16x8*>(&As[32*wave + l16][quad*8]);
    f16x8 a0b = *reinterpret_cast<const f16x8*>(&As[32*wave + l16][32 + quad*8]);
    f16x8 a1  = *reinterpret_cast<const f16x8*>(&As[32*wave + 16 + l16][quad*8]);
    f16x8 a1b = *reinterpret_cast<const f16x8*>(&As[32*wave + 16 + l16][32 + quad*8]);
    #pragma unroll
    for (int j = 0; j < 8; ++j) {
        f16x8 bj  = *reinterpret_cast<const f16x8*>(&Bs[16*j + l16][quad*8]);
        f16x8 bjb = *reinterpret_cast<const f16x8*>(&Bs[16*j + l16][32 + quad*8]);
        acc[0][j] = __builtin_amdgcn_mfma_f32_16x16x32_f16(a0,  bj,  acc[0][j], 0, 0, 0);
        acc[0][j] = __builtin_amdgcn_mfma_f32_16x16x32_f16(a0b, bjb, acc[0][j], 0, 0, 0);
        acc[1][j] = __builtin_amdgcn_mfma_f32_16x16x32_f16(a1,  bj,  acc[1][j], 0, 0, 0);
        acc[1][j] = __builtin_amdgcn_mfma_f32_16x16x32_f16(a1b, bjb, acc[1][j], 0, 0, 0);
    }
    float se[8] = {0,0,0,0,0,0,0,0}, s2e[8] = {0,0,0,0,0,0,0,0};
    #pragma unroll
    for (int i = 0; i < 2; ++i) {
        #pragma unroll
        for (int r = 0; r < 4; ++r) {
            int q = 32*wave + 16*i + quad*4 + r;
            #pragma unroll
            for (int j = 0; j < 8; ++j) {
                float v = acc[i][j][r];
                V3xT[((size_t)b*128 + q)*512 + l0 + 16*j + l16] = (f16)v;
                se[i*4+r] += v; s2e[i*4+r] += v*v;
            }
        }
    }
    #pragma unroll
    for (int k = 0; k < 8; ++k) {
        se[k]  += __shfl_xor(se[k],1);  se[k]  += __shfl_xor(se[k],2);
        se[k]  += __shfl_xor(se[k],4);  se[k]  += __shfl_xor(se[k],8);
        s2e[k] += __shfl_xor(s2e[k],1); s2e[k] += __shfl_xor(s2e[k],2);
        s2e[k] += __shfl_xor(s2e[k],4); s2e[k] += __shfl_xor(s2e[k],8);
    }
    if (l16 == 0) {
        #pragma unroll
        for (int i = 0; i < 2; ++i)
            #pragma unroll
            for (int r = 0; r < 4; ++r) {
                int qq = 32*wave + 16*i + quad*4 + r;
                rede[qq]       = se[i*4+r];
                rede[128 + qq] = s2e[i*4+r];
            }
    }
    __syncthreads();
    pE3[((size_t)(blockIdx.x*512 + b))*256 + t] = rede[t];
}

// e3 support points
__global__ __launch_bounds__(128) void k_esupport3(
    const float* __restrict__ V2s, const float* __restrict__ sc2, const float* __restrict__ sh2,
    const float* __restrict__ eW3, float* __restrict__ V3s)
{
    const int idx = blockIdx.x, q = threadIdx.x;
    __shared__ float t2s[64];
    if (q < 64) t2s[q] = lrelu(fmaf(sc2[q], V2s[idx*64 + q], sh2[q]));
    __syncthreads();
    float s = 0.f;
    #pragma unroll
    for (int d = 0; d < 64; ++d) s = fmaf(eW3[q*64 + d], t2s[d], s);
    V3s[idx*128 + q] = s;
}

__global__ void k_u(const float* __restrict__ V3s, const float* __restrict__ sc3, const float* __restrict__ sh3,
                    float* __restrict__ u1, float* __restrict__ u0)
{
    const int idx = blockIdx.x*256 + threadIdx.x;
    if (idx < 513*128) {
        int i = idx >> 7, q = idx & 127;
        float tv = lrelu(fmaf(sc3[q], V3s[idx], sh3[q]));
        if (i < 512) u1[idx] = tv; else u0[q] = tv;
    }
}

// ---------------- MFMA fw1 (pipeline + fused out6T stats; hoisted epilogue loads) ----------------
__global__ __launch_bounds__(256) void k_mfma_fw1T(
    const f16* __restrict__ fW1h, const f16* __restrict__ V3xT,
    const f16* __restrict__ sceh, const f16* __restrict__ sheh,
    const float* __restrict__ u1, const float* __restrict__ u0,
    const float* __restrict__ P1, const float* __restrict__ Ftot,
    f16* __restrict__ out6T, float* __restrict__ pF)
{
    __shared__ __align__(16) f16 lds[24576];    // 3 sets x (A 4096 + B 4096) f16
    __shared__ float redf[1024];
    const int t = threadIdx.x;
    const int wave = t >> 6, lane = t & 63;
    const int quad = lane >> 4, l16 = lane & 15;
    const int n = blockIdx.x + (blockIdx.y << 3);
    const int b = (n & 7)*64 + (n >> 6);
    const int fblk = (n >> 3) & 7;
    const int f0 = fblk * 128;
    const f16* Aa = V3xT + (size_t)b*65536;
    const f16* Bb = fW1h + (size_t)f0*512;
    const int sg = (t & 3) ^ ((t >> 3) & 3);
    const size_t go0 = (size_t)(t >> 2)*512 + sg*8;
    const size_t go1 = go0 + (size_t)64*512;
    const int rA0 = 32*wave + l16, rA1 = rA0 + 16;
    const f16x8 scA0 = splat8(sceh[rA0]), shA0 = splat8(sheh[rA0]);
    const f16x8 scA1 = splat8(sceh[rA1]), shA1 = splat8(sheh[rA1]);
    const int offA0 = swz_off(rA0, quad);
    const int offA1 = swz_off(rA1, quad);
    int offB[8];
    #pragma unroll
    for (int j = 0; j < 8; ++j) offB[j] = swz_off(16*j + l16, quad);
    // hoisted epilogue operands: latency hides under the whole k-loop
    float p1j[8], p0j[8], u1q[8], u0q[8];
    #pragma unroll
    for (int j = 0; j < 8; ++j) {
        int f = f0 + 16*j + l16;
        p1j[j] = P1[b*1024 + f];
        p0j[j] = Ftot[f] - p1j[j];
    }
    #pragma unroll
    for (int i = 0; i < 2; ++i)
        #pragma unroll
        for (int r = 0; r < 4; ++r) {
            int q = 32*wave + 16*i + quad*4 + r;
            u1q[i*4+r] = u1[b*128 + q];
            u0q[i*4+r] = u0[q];
        }
    f32x4 acc[2][8];
    #pragma unroll
    for (int i = 0; i < 2; ++i)
        #pragma unroll
        for (int j = 0; j < 8; ++j) acc[i][j] = (f32x4){0.f,0.f,0.f,0.f};
    dma_pair(Aa + go0,      Aa + go1,      lds,               t);
    dma_pair(Bb + go0,      Bb + go1,      lds + 4096,        t);
    dma_pair(Aa + 32 + go0, Aa + 32 + go1, lds + 8192,        t);
    dma_pair(Bb + 32 + go0, Bb + 32 + go1, lds + 8192 + 4096, t);
    int m = 0;
    for (int kt = 0; kt < 16; ++kt) {
        SCHED0; BARRIER; SCHED0;
        if (kt <= 13) {
            const int mp = (m >= 1) ? m - 1 : m + 2;
            const int k0 = (kt + 2) * 32;
            dma_pair(Aa + k0 + go0, Aa + k0 + go1, lds + mp*8192,        t);
            dma_pair(Bb + k0 + go0, Bb + k0 + go1, lds + mp*8192 + 4096, t);
            asm volatile("s_waitcnt vmcnt(8)" ::: "memory");
        } else if (kt == 14) {
            asm volatile("s_waitcnt vmcnt(4)" ::: "memory");
        } else {
            asm volatile("s_waitcnt vmcnt(0)" ::: "memory");
        }
        SCHED0; BARRIER; SCHED0;
        const f16* As = lds + m*8192;
        const f16* Bs = As + 4096;
        f16x8 a0 = bnl8(*reinterpret_cast<const f16x8*>(As + offA0), scA0, shA0);
        f16x8 a1 = bnl8(*reinterpret_cast<const f16x8*>(As + offA1), scA1, shA1);
        #pragma unroll
        for (int j = 0; j < 8; ++j) {
            f16x8 bj = *reinterpret_cast<const f16x8*>(Bs + offB[j]);
            acc[0][j] = __builtin_amdgcn_mfma_f32_16x16x32_f16(a0, bj, acc[0][j], 0, 0, 0);
            acc[1][j] = __builtin_amdgcn_mfma_f32_16x16x32_f16(a1, bj, acc[1][j], 0, 0, 0);
        }
        m = (m == 2) ? 0 : m + 1;
    }
    float sj[8], s2j[8];
    #pragma unroll
    for (int j = 0; j < 8; ++j) { sj[j] = 0.f; s2j[j] = 0.f; }
    #pragma unroll
    for (int i = 0; i < 2; ++i) {
        #pragma unroll
        for (int r = 0; r < 4; ++r) {
            int q = 32*wave + 16*i + quad*4 + r;
            #pragma unroll
            for (int j = 0; j < 8; ++j) {
                int f = f0 + 16*j + l16;
                float v = acc[i][j][r] + u1q[i*4+r]*p1j[j] + u0q[i*4+r]*p0j[j];
                out6T[((size_t)b*128 + q)*1024 + f] = (f16)v;
                sj[j] += v; s2j[j] += v*v;
            }
        }
    }
    #pragma unroll
    for (int j = 0; j < 8; ++j) {
        sj[j]  += __shfl_xor(sj[j],16);  sj[j]  += __shfl_xor(sj[j],32);
        s2j[j] += __shfl_xor(s2j[j],16); s2j[j] += __shfl_xor(s2j[j],32);
    }
    if (quad == 0) {
        #pragma unroll
        for (int j = 0; j < 8; ++j) {
            redf[wave*256 + j*16 + l16]       = sj[j];
            redf[wave*256 + 128 + j*16 + l16] = s2j[j];
        }
    }
    __syncthreads();
    {
        float v = redf[t] + redf[256 + t] + redf[512 + t] + redf[768 + t];
        pF[((size_t)(fblk*512 + b))*256 + t] = v;
    }
}

// ---------------- MFMA fw2 (triple-buffered pipeline + in-place LDS BN) ----------------
__global__ __launch_bounds__(256) void k_mfma_fw2T(
    const f16* __restrict__ fW2h, const f16* __restrict__ out6T,
    const f16* __restrict__ scfh, const f16* __restrict__ shfh,
    const float* __restrict__ fbias2, f16* __restrict__ out7)
{
    __shared__ __align__(16) f16 lds[24576];
    __shared__ __align__(16) f16 scL[1024];
    __shared__ __align__(16) f16 shL[1024];
    const int t = threadIdx.x;
    const int wave = t >> 6, lane = t & 63;
    const int quad = lane >> 4, l16 = lane & 15;
    const int n = blockIdx.x + (blockIdx.y << 2);
    const int b = (n & 7)*64 + (n >> 5);
    const int o0 = ((n >> 3) & 3) * 128;
    const f16* Aa = fW2h + (size_t)o0*1024;
    const f16* Bb = out6T + (size_t)b*131072;
    const int sg = (t & 3) ^ ((t >> 3) & 3);
    const size_t go0 = (size_t)(t >> 2)*1024 + sg*8;
    const size_t go1 = go0 + (size_t)64*1024;
    const int bnO = sg*8;
    const int offA0 = swz_off(32*wave + l16, quad);
    const int offA1 = swz_off(32*wave + 16 + l16, quad);
    int offB[8];
    #pragma unroll
    for (int j = 0; j < 8; ++j) offB[j] = swz_off(16*j + l16, quad);
    // hoisted bias loads
    float biasv[8];
    #pragma unroll
    for (int i = 0; i < 2; ++i)
        #pragma unroll
        for (int r = 0; r < 4; ++r)
            biasv[i*4+r] = fbias2[o0 + 32*wave + 16*i + quad*4 + r];
    f32x4 acc[2][8];
    #pragma unroll
    for (int i = 0; i < 2; ++i)
        #pragma unroll
        for (int j = 0; j < 8; ++j) acc[i][j] = (f32x4){0.f,0.f,0.f,0.f};
    if (t < 128) *reinterpret_cast<f16x8*>(&scL[t*8]) =
        *reinterpret_cast<const f16x8*>(scfh + t*8);
    else         *reinterpret_cast<f16x8*>(&shL[(t-128)*8]) =
        *reinterpret_cast<const f16x8*>(shfh + (t-128)*8);
    __syncthreads();
    dma_pair(Aa + go0,      Aa + go1,      lds,               t);
    dma_pair(Bb + go0,      Bb + go1,      lds + 4096,        t);
    dma_pair(Aa + 32 + go0, Aa + 32 + go1, lds + 8192,        t);
    dma_pair(Bb + 32 + go0, Bb + 32 + go1, lds + 8192 + 4096, t);
    int m = 0;
    for (int kt = 0; kt < 32; ++kt) {
        SCHED0; BARRIER; SCHED0;
        if (kt <= 29) {
            const int mp = (m >= 1) ? m - 1 : m + 2;
            const int k0 = (kt + 2) * 32;
            dma_pair(Aa + k0 + go0, Aa + k0 + go1, lds + mp*8192,        t);
            dma_pair(Bb + k0 + go0, Bb + k0 + go1, lds + mp*8192 + 4096, t);
            asm volatile("s_waitcnt vmcnt(8)" ::: "memory");
        } else if (kt == 30) {
            asm volatile("s_waitcnt vmcnt(4)" ::: "memory");
        } else {
            asm volatile("s_waitcnt vmcnt(0)" ::: "memory");
        }
        SCHED0; BARRIER; SCHED0;
        {
            f16* Bm = lds + m*8192 + 4096;
            const f16x8 csc = *reinterpret_cast<const f16x8*>(&scL[kt*32 + bnO]);
            const f16x8 csh = *reinterpret_cast<const f16x8*>(&shL[kt*32 + bnO]);
            f16x8 v0 = *reinterpret_cast<const f16x8*>(Bm + t*8);
            f16x8 v1 = *reinterpret_cast<const f16x8*>(Bm + 2048 + t*8);
            *reinterpret_cast<f16x8*>(Bm + t*8)        = bnl8(v0, csc, csh);
            *reinterpret_cast<f16x8*>(Bm + 2048 + t*8) = bnl8(v1, csc, csh);
        }
        asm volatile("s_waitcnt lgkmcnt(0)" ::: "memory");
        SCHED0; BARRIER; SCHED0;
        const f16* As = lds + m*8192;
        const f16* Bs = As + 4096;
        f16x8 a0 = *reinterpret_cast<const f16x8*>(As + offA0);
        f16x8 a1 = *reinterpret_cast<const f16x8*>(As + offA1);
        #pragma unroll
        for (int j = 0; j < 8; ++j) {
            f16x8 bj = *reinterpret_cast<const f16x8*>(Bs + offB[j]);
            acc[0][j] = __builtin_amdgcn_mfma_f32_16x16x32_f16(a0, bj, acc[0][j], 0, 0, 0);
            acc[1][j] = __builtin_amdgcn_mfma_f32_16x16x32_f16(a1, bj, acc[1][j], 0, 0, 0);
        }
        m = (m == 2) ? 0 : m + 1;
    }
    #pragma unroll
    for (int i = 0; i < 2; ++i) {
        #pragma unroll
        for (int r = 0; r < 4; ++r) {
            int o = o0 + 32*wave + 16*i + quad*4 + r;
            #pragma unroll
            for (int j = 0; j < 8; ++j) {
                int q = 16*j + l16;
                out7[((size_t)b*512 + o)*128 + q] = (f16)(acc[i][j][r] + biasv[i*4+r]);
            }
        }
    }
}

// ---------------- MFMA d1 (f16 output + fused stats) ----------------
__global__ __launch_bounds__(256) void k_mfma_d1(
    const f16* __restrict__ dW1h, const f16* __restrict__ out7,
    f16* __restrict__ d1pre, float* __restrict__ pD1)
{
    __shared__ __align__(16) f16 As[64][44];
    __shared__ __align__(16) f16 Bs[128][44];
    __shared__ float redd[128];
    const int b = blockIdx.y, o0 = blockIdx.x * 128;
    const int t = threadIdx.x;
    const int wave = t >> 6, lane = t & 63;
    const int quad = lane >> 4, l16 = lane & 15;
    const int row0 = t >> 2, grp = t & 3;
    const f16* Bb = out7 + (size_t)b*65536;
    f32x4 acc[8];
    #pragma unroll
    for (int j = 0; j < 8; ++j) acc[j] = (f32x4){0.f,0.f,0.f,0.f};
    for (int k0 = 0; k0 < 128; k0 += 32) {
        *reinterpret_cast<f16x8*>(&As[row0][grp*8]) =
            *reinterpret_cast<const f16x8*>(dW1h + row0*128 + k0 + grp*8);
        #pragma unroll
        for (int p = 0; p < 2; ++p) {
            const int row = row0 + 64*p;
            *reinterpret_cast<f16x8*>(&Bs[row][grp*8]) =
                *reinterpret_cast<const f16x8*>(Bb + (size_t)(o0+row)*128 + k0 + grp*8);
        }
        __syncthreads();
        f16x8 a0 = *reinterpret_cast<const f16x8*>(&As[16*wave + l16][quad*8]);
        #pragma unroll
        for (int j = 0; j < 8; ++j) {
            f16x8 bj = *reinterpret_cast<const f16x8*>(&Bs[16*j + l16][quad*8]);
            acc[j] = __builtin_amdgcn_mfma_f32_16x16x32_f16(a0, bj, acc[j], 0, 0, 0);
        }
        __syncthreads();
    }
    float sd[4] = {0,0,0,0}, s2d[4] = {0,0,0,0};
    #pragma unroll
    for (int r = 0; r < 4; ++r) {
        int d = 16*wave + quad*4 + r;
        #pragma unroll
        for (int j = 0; j < 8; ++j) {
            int o = o0 + 16*j + l16;
            float v = acc[j][r];
            d1pre[(size_t)b*32768 + (size_t)d*512 + o] = (f16)v;
            sd[r] += v; s2d[r] += v*v;
        }
    }
    #pragma unroll
    for (int r = 0; r < 4; ++r) {
        sd[r]  += __shfl_xor(sd[r],1);  sd[r]  += __shfl_xor(sd[r],2);
        sd[r]  += __shfl_xor(sd[r],4);  sd[r]  += __shfl_xor(sd[r],8);
        s2d[r] += __shfl_xor(s2d[r],1); s2d[r] += __shfl_xor(s2d[r],2);
        s2d[r] += __shfl_xor(s2d[r],4); s2d[r] += __shfl_xor(s2d[r],8);
    }
    if (l16 == 0) {
        #pragma unroll
        for (int r = 0; r < 4; ++r) {
            int dd = 16*wave + quad*4 + r;
            redd[dd] = sd[r]; redd[64 + dd] = s2d[r];
        }
    }
    __syncthreads();
    if (t < 128) pD1[((size_t)(blockIdx.x*512 + b))*128 + t] = redd[t];
}

// d2: C[e,o] = sum_d dW2[e,d] * lrelu(sc*d1pre[b][d][o]+sh)  (d1pre f16) + fused stats
// d2pre stored as f16 now (stats computed pre-rounding)
__global__ __launch_bounds__(128) void k_gemm_d2(
    const float* __restrict__ dW2, const f16* __restrict__ d1pre,
    const float* __restrict__ scd, const float* __restrict__ shd,
    f16* __restrict__ d2pre, float* __restrict__ pD2)
{
    __shared__ __align__(16) float As[16][36];
    __shared__ __align__(16) float Bs[16][68];
    __shared__ float sred[64];
    const int n0 = blockIdx.x * 64, b = blockIdx.y;
    const int t = threadIdx.x;
    const int kk = t & 15, ri = t >> 4;
    const int qv = t & 63, kh = t >> 6;
    const int tx = t & 15, ty = t >> 4;
    float acc[4][4] = {{0.f,0.f,0.f,0.f},{0.f,0.f,0.f,0.f},{0.f,0.f,0.f,0.f},{0.f,0.f,0.f,0.f}};
    for (int k0 = 0; k0 < 64; k0 += 16) {
        #pragma unroll
        for (int mm = 0; mm < 4; ++mm)
            As[kk][ri + mm*8] = dW2[(ri + mm*8)*64 + k0 + kk];
        #pragma unroll
        for (int ki = 0; ki < 8; ++ki) {
            int d = k0 + kh + ki*2;
            float v = (float)d1pre[(size_t)b*32768 + (size_t)d*512 + n0 + qv];
            Bs[kh + ki*2][qv] = lrelu(fmaf(scd[d], v, shd[d]));
        }
        __syncthreads();
        #pragma unroll
        for (int kq = 0; kq < 16; ++kq) {
            const float4 av = *reinterpret_cast<const float4*>(&As[kq][ty*4]);
            const float4 bv = *reinterpret_cast<const float4*>(&Bs[kq][tx*4]);
            FMA44(av, bv);
        }
        __syncthreads();
    }
    #pragma unroll
    for (int i = 0; i < 4; ++i) {
        float s = 0.f, s2 = 0.f;
        #pragma unroll
        for (int j = 0; j < 4; ++j) {
            float v = acc[i][j];
            d2pre[(size_t)b*16384 + (size_t)(ty*4 + i)*512 + n0 + tx*4 + j] = (f16)v;
            s += v; s2 += v*v;
        }
        s  += __shfl_xor(s,1);  s  += __shfl_xor(s,2);
        s  += __shfl_xor(s,4);  s  += __shfl_xor(s,8);
        s2 += __shfl_xor(s2,1); s2 += __shfl_xor(s2,2);
        s2 += __shfl_xor(s2,4); s2 += __shfl_xor(s2,8);
        if (tx == 0) {
            int e = ty*4 + i;
            sred[e] = s; sred[32 + e] = s2;
        }
    }
    __syncthreads();
    if (t < 64) pD2[((size_t)(blockIdx.y*8 + blockIdx.x))*64 + t] = sred[t];
}

__global__ __launch_bounds__(256) void k_d3(
    const f16* __restrict__ d2pre, const float* __restrict__ dW3,
    const float* __restrict__ sce, const float* __restrict__ she,
    const float* __restrict__ dbias3, float* __restrict__ out)
{
    const int idx = blockIdx.x*256 + threadIdx.x;
    const int b = idx >> 9, o = idx & 511;
    float s = dbias3[0];
    for (int e = 0; e < 32; ++e) {
        float v = (float)d2pre[(size_t)b*16384 + e*512 + o];
        s = fmaf(dW3[e], lrelu(fmaf(v, sce[e], she[e])), s);
    }
    out[idx] = s;
}

extern "C" void kernel_launch(void* const* d_in, const int* in_sizes, int n_in,
                              void* d_out, int out_size, void* d_ws, size_t ws_size,
                              hipStream_t stream)
{
    (void)in_sizes; (void)n_in; (void)out_size;
    const float* x      = (const float*)d_in[0];
    const float* gumbel = (const float*)d_in[1];
    const float* cW1 = (const float*)d_in[2];
    const float* cg1 = (const float*)d_in[3];
    const float* cb1 = (const float*)d_in[4];
    const float* cW2 = (const float*)d_in[5];
    const float* cg2 = (const float*)d_in[6];
    const float* cb2 = (const float*)d_in[7];
    const float* cW3 = (const float*)d_in[8];
    const float* cg3 = (const float*)d_in[9];
    const float* cb3 = (const float*)d_in[10];
    const float* eW1 = (const float*)d_in[11];
    const float* eg1 = (const float*)d_in[12];
    const float* eb1 = (const float*)d_in[13];
    const float* eW2 = (const float*)d_in[14];
    const float* eg2 = (const float*)d_in[15];
    const float* eb2 = (const float*)d_in[16];
    const float* eW3 = (const float*)d_in[17];
    const float* eg3 = (const float*)d_in[18];
    const float* eb3 = (const float*)d_in[19];
    const float* fW1 = (const float*)d_in[20];
    const float* fg1 = (const float*)d_in[21];
    const float* fb1 = (const float*)d_in[22];
    const float* fW2 = (const float*)d_in[23];
    const float* fbias2 = (const float*)d_in[24];
    const float* dW1 = (const float*)d_in[25];
    const float* dg1 = (const float*)d_in[26];
    const float* db1 = (const float*)d_in[27];
    const float* dW2 = (const float*)d_in[28];
    const float* dg2 = (const float*)d_in[29];
    const float* db2 = (const float*)d_in[30];
    const float* dW3 = (const float*)d_in[31];
    const float* dbias3 = (const float*)d_in[32];
    float* out = (float*)d_out;
    float* ws  = (float*)d_ws;

    if (ws_size < O_END * sizeof(float)) {
        k_sentinel<<<1024,256,0,stream>>>(out);
        return;
    }

    float* H1  = ws + O_H1;
    float* H2  = ws + O_H2;
    float* L   = ws + O_L;
    int*   sel = (int*)(ws + O_SEL);
    float* S   = ws + O_S;
    float* S2  = ws + O_S2;
    float* val = ws + O_VAL;
    float* prm = ws + O_PRM;
    f16*   fW1h= (f16*)(ws + O_FW1H);
    f16*   fW2h= (f16*)(ws + O_FW2H);
    float* accF= ws + O_ACCF;
    f16*   dW1h= (f16*)(ws + O_DW1H);
    f16*   eW3h= (f16*)(ws + O_EW3H);
    float* V2s = ws + O_V2SS;
    float* u1  = ws + O_U1;
    float* P1  = ws + O_P1;
    float* fzT = ws + O_FZT;
    float* V3s = ws + O_V3S;
    float* pF  = ws + O_PF;             // fw1 stats partials (H1+H2); ftot partials earlier
    float* pFT = ws + O_H1;             // ftot partials: 16 x 1024 f32 (H1, free post c-path)
    float* pD1 = ws + O_PD1;            // d1 stats partials (H2; pF dead by then)
    float* pD2 = ws + O_PD2;
    float* p2d = ws + O_P1;             // stats2d partials (P1 written later)
    float* pE3 = ws + O_FZT;            // e3 stats partials (fzT dead after k_p1)
    f16*   V3xT= (f16*)(ws + O_BIG1);
    f16*   out7= (f16*)(ws + O_BIG1);   // aliases V3xT (dead after fw1)
    f16*   out6T=(f16*)(ws + O_BIG2);
    f16*   V2x = (f16*)(ws + O_BIG2);   // aliases out6T
    f16*   d1p = (f16*)(ws + O_D1);     // f16; aliases out6T (dead after fw2)
    f16*   d2p = (f16*)(ws + O_D2);     // f16 now

    const float invN_e = 1.0f/1310720.f;

    // ---- c-path (deterministic fp32; feeds argmax) ----
    k_gemm_c<<<dim3(16,8),256,0,stream>>>(x,  cW1, H1, 1024, 512,  nullptr,     nullptr);
    k_stats2d_p<<<dim3(32,1),256,0,stream>>>(H1, 1024, p2d);
    k_finalize_p<<<4,256,0,stream>>>(p2d, 1024, 32, 1.0f/512.f, cg1, cb1,
                                     prm+P_SC1, prm+P_SH1, nullptr, nullptr);
    k_gemm_c<<<dim3(16,8),256,0,stream>>>(H1, cW2, H2, 1024, 1024, prm+P_SC1, prm+P_SH1);
    k_stats2d_p<<<dim3(32,1),256,0,stream>>>(H2, 1024, p2d);
    k_finalize_p<<<4,256,0,stream>>>(p2d, 1024, 32, 1.0f/512.f, cg2, cb2,
                                     prm+P_SC2, prm+P_SH2, nullptr, nullptr);
    k_gemm_c<<<dim3(32,8),256,0,stream>>>(H2, cW3, L,  2048, 1024, prm+P_SC2, prm+P_SH2);
    k_stats2d_p<<<dim3(32,2),256,0,stream>>>(L, 2048, p2d);
    k_finalize_p<<<8,256,0,stream>>>(p2d, 2048, 32, 1.0f/512.f, cg3, cb3,
                                     prm+P_SC3, prm+P_SH3, nullptr, nullptr);
    k_sel<<<512,256,0,stream>>>(L, gumbel, prm+P_SC3, prm+P_SH3, sel);

    // ---- weight prep (overwrites L region) + selection-derived helpers ----
    k_prep<<<2048,256,0,stream>>>(fW1, fW2, dW1, eW3, fW1h, fW2h, dW1h, eW3h, accF);
    k_val<<<512,256,0,stream>>>(x, S, S2, val);
    k_e1params<<<1,256,0,stream>>>(S, S2, val, eW1, eg1, eb1, prm+P_A1, prm+P_C1, prm+P_ACC2);
    k_transpose_fz<<<dim3(32,16),256,0,stream>>>(fW1, fzT);
    k_wtrans2<<<1,256,0,stream>>>(eW2, prm+P_EW2T);
    k_ftot_p<<<dim3(4,16),256,0,stream>>>(fzT, pFT);
    k_ftot_s<<<4,256,0,stream>>>(pFT, prm+P_FTOT);
    k_p1<<<512,256,0,stream>>>(fzT, sel, P1);

    // ---- e-path ----
    k_epass2<<<1024,256,0,stream>>>(x, prm+P_A1, prm+P_C1, prm+P_EW2T, V2x);
    k_esupport2<<<513,64,0,stream>>>(val, prm+P_A1, prm+P_C1, prm+P_EW2T, V2s);
    k_stats_v2scan<<<64,256,0,stream>>>(V2x, prm+P_ACC2);
    k_wstats<<<64,64,0,stream>>>(V2s, 64, prm+P_ACC2);
    k_finalize<<<1,256,0,stream>>>(prm+P_ACC2, 64, invN_e, eg2, eb2, prm+P_SCE2, prm+P_SHE2,
                                   (f16*)(prm+P_SCE2H), (f16*)(prm+P_SHE2H));
    k_mfma_e3<<<dim3(4,512),256,0,stream>>>(eW3h, V2x,
                                            (const f16*)(prm+P_SCE2H), (const f16*)(prm+P_SHE2H),
                                            V3xT, pE3);
    k_esupport3<<<513,128,0,stream>>>(V2s, prm+P_SCE2, prm+P_SHE2, eW3, V3s);
    k_wstats<<<128,64,0,stream>>>(V3s, 128, prm+P_ACC3);
    k_finalize_e3<<<1,256,0,stream>>>(pE3, prm+P_ACC3, eg3, eb3, prm+P_SCE3, prm+P_SHE3,
                                      (f16*)(prm+P_SCE3H), (f16*)(prm+P_SHE3H));
    k_u<<<257,256,0,stream>>>(V3s, prm+P_SCE3, prm+P_SHE3, u1, prm+P_U0);

    // ---- f-path (MFMA f16) ----
    k_mfma_fw1T<<<dim3(8,512),256,0,stream>>>(fW1h, V3xT,
                                              (const f16*)(prm+P_SCE3H), (const f16*)(prm+P_SHE3H),
                                              u1, prm+P_U0, P1, prm+P_FTOT, out6T, pF);
    k_finalize_f<<<4,256,0,stream>>>(pF, fg1, fb1, prm+P_SCF1, prm+P_SHF1,
                                     (f16*)(prm+P_SCF1H), (f16*)(prm+P_SHF1H));
    k_mfma_fw2T<<<dim3(4,512),256,0,stream>>>(fW2h, out6T,
                                              (const f16*)(prm+P_SCF1H), (const f16*)(prm+P_SHF1H),
                                              fbias2, out7);

    // ---- d-path ----
    k_mfma_d1<<<dim3(4,512),256,0,stream>>>(dW1h, out7, d1p, pD1);
    k_finalize_d1<<<1,256,0,stream>>>(pD1, dg1, db1, prm+P_SCD1, prm+P_SHD1);
    k_gemm_d2<<<dim3(8,512),128,0,stream>>>(dW2, d1p, prm+P_SCD1, prm+P_SHD1, d2p, pD2);
    k_finalize_d2<<<1,256,0,stream>>>(pD2, dg2, db2, prm+P_SCD2, prm+P_SHD2);
    k_d3<<<1024,256,0,stream>>>(d2p, dW3, prm+P_SCD2, prm+P_SHD2, dbias3, out);
}

// Round 12
// 824.006 us; speedup vs baseline: 1.1429x; 1.0692x over previous
//
#include <hip/hip_runtime.h>
#include <cstddef>

#define DEV __device__ __forceinline__
DEV float lrelu(float x){ return x >= 0.0f ? x : 0.2f*x; }
typedef _Float16 f16;
typedef _Float16 f16x8 __attribute__((ext_vector_type(8)));
typedef float f32x4 __attribute__((ext_vector_type(4)));

DEV f16x8 splat8(f16 s){ f16x8 v = {s,s,s,s,s,s,s,s}; return v; }
// packed BN + lrelu in f16: lrelu(v*sc+sh) with exact max/min formulation
DEV f16x8 bnl8(f16x8 v, f16x8 sc, f16x8 sh){
    f16x8 t = v*sc + sh;                       // v_pk_fma_f16
    f16x8 z = splat8((f16)0.0f);
    f16x8 mx = __builtin_elementwise_max(t, z);
    f16x8 mn = __builtin_elementwise_min(t, z);
    return mx + mn*splat8((f16)0.2f);
}

// async global->LDS, 16B per lane (raw staging, no VGPR roundtrip)
DEV void gload_lds16(const f16* src, f16* dst){
    __builtin_amdgcn_global_load_lds(
        (const __attribute__((address_space(1))) void*)src,
        (__attribute__((address_space(3))) void*)dst, 16, 0, 0);
}

// stage a 128x32 tile half-pair: slots t (rows 0..63) and 256+t (rows 64..127).
DEV void dma_pair(const f16* g0, const f16* g1, f16* ldsbase, int t){
    gload_lds16(g0, ldsbase + t*8);
    gload_lds16(g1, ldsbase + 2048 + t*8);
}
// reader-side swizzled f16 index for (row r, k-granule g)
DEV int swz_off(int r, int g){ return r*32 + ((g ^ ((r>>1)&3))<<3); }

#define SCHED0 __builtin_amdgcn_sched_barrier(0)
#define BARRIER __builtin_amdgcn_s_barrier()

// Problem dims: B=512, IN=512, CB=8, HD=256, CH=2048, CC=2560, EXP=128, FC1=1024, OUT=512
constexpr int NXPT = 512*512;     // dense support points (b,l<512)

// ---------------- workspace layout (float offsets) ----------------
constexpr size_t O_H1  = 0;                       // 512x1024 f32
constexpr size_t O_H2  = O_H1 + 512*1024;         // 512x1024 f32
constexpr size_t O_L   = O_H2 + 512*1024;         // 512x2048 f32 (c3 logits; dead after k_sel)
constexpr size_t O_SEL = O_L  + 512*2048;         // int32 512x256
constexpr size_t O_S   = O_SEL + 512*256;
constexpr size_t O_S2  = O_S + 512;
constexpr size_t O_VAL = O_S2 + 512;
constexpr size_t O_PRM = O_VAL + 512;
// params sub-offsets (within PRM)
constexpr size_t P_SC1=0, P_SH1=1024, P_SC2=2048, P_SH2=3072, P_SC3=4096, P_SH3=6144;
constexpr size_t P_A1=8192, P_C1=8224, P_EW2T=8256 /*2048*/;
constexpr size_t P_ACC2=18496 /*128*/, P_ACC3=18624 /*256*/;
constexpr size_t P_SCE2=18880, P_SHE2=18944, P_SCE3=19008, P_SHE3=19136;
constexpr size_t P_U0=19264 /*128*/, P_FTOT=19392 /*1024*/;
constexpr size_t P_SCF1=20416, P_SHF1=21440;
constexpr size_t P_SCD1=22464, P_SHD1=22528, P_SCD2=22592, P_SHD2=22624;
// f16 copies of BN affine params (for packed-f16 MFMA staging)
constexpr size_t P_SCE3H=22656, P_SHE3H=22720;    // 128 f16 each (64 floats)
constexpr size_t P_SCF1H=22784, P_SHF1H=23296;    // 1024 f16 each (512 floats)
constexpr size_t P_SCE2H=23808, P_SHE2H=23840;    // 64 f16 each (32 floats)
constexpr size_t PRM_SIZE = 32768;
// stats partial buffers (all alias dead regions)
constexpr size_t O_PF  = O_H1;                    // fw1 stats partials: 4096 x 256 f32 (H1+H2); ftot partials earlier
constexpr size_t O_PD1 = O_H2;                    // d1 stats partials: 2048 x 128 f32 (after pF dead)
constexpr size_t O_PD2 = O_H2 + 262144;           // d2 stats partials: 4096 x 64 f32
// weight copies + V2s ALIAS the dead L buffer (written after k_sel)
constexpr size_t O_FW1H = O_L;                    // f16 1024x512   (262144 floats)
constexpr size_t O_FW2H = O_L + 262144;           // f16 512x1024   (262144 floats)
constexpr size_t O_ACCF = O_L + 524288;           // f32 2048 (legacy zero region)
constexpr size_t O_DW1H = O_L + 528384;           // f16 64x128  (4096 floats)
constexpr size_t O_EW3H = O_L + 532480;           // f16 128x64  (4096 floats)
constexpr size_t O_V2SS = O_L + 536576;           // f32 513x64  (32832 floats)
constexpr size_t O_U1  = O_PRM + PRM_SIZE;        // 512x128 f32
constexpr size_t O_P1  = O_U1 + 512*128;          // 512x1024 f32; ALSO c-stats partials (before k_p1)
constexpr size_t O_FZT = O_P1 + 512*1024;         // f16 2048x1024 (fW1 z-part T); pE3 aliases after k_p1
constexpr size_t O_V3S = O_FZT + (size_t)2048*1024;   // 513x128 f32
constexpr size_t O_BIG1= O_V3S + 513*128;             // f16 512*128*512  (V3xT, later out7)
constexpr size_t O_BIG2= O_BIG1 + (size_t)512*512*128/2; // f16 512*128*1024 (out6T); V2x + d1p alias
constexpr size_t O_D1  = O_BIG2;                      // f16 512*64*512 (aliases out6T, dead after fw2)
constexpr size_t O_D2  = O_BIG2 + (size_t)512*64*512; // f16 512*32*512
constexpr size_t O_END = O_BIG2 + (size_t)512*1024*128/2;   // ~211 MB

#define FMA44(av,bv) do{ \
  acc[0][0]=fmaf(av.x,bv.x,acc[0][0]); acc[0][1]=fmaf(av.x,bv.y,acc[0][1]); \
  acc[0][2]=fmaf(av.x,bv.z,acc[0][2]); acc[0][3]=fmaf(av.x,bv.w,acc[0][3]); \
  acc[1][0]=fmaf(av.y,bv.x,acc[1][0]); acc[1][1]=fmaf(av.y,bv.y,acc[1][1]); \
  acc[1][2]=fmaf(av.y,bv.z,acc[1][2]); acc[1][3]=fmaf(av.y,bv.w,acc[1][3]); \
  acc[2][0]=fmaf(av.z,bv.x,acc[2][0]); acc[2][1]=fmaf(av.z,bv.y,acc[2][1]); \
  acc[2][2]=fmaf(av.z,bv.z,acc[2][2]); acc[2][3]=fmaf(av.z,bv.w,acc[2][3]); \
  acc[3][0]=fmaf(av.w,bv.x,acc[3][0]); acc[3][1]=fmaf(av.w,bv.y,acc[3][1]); \
  acc[3][2]=fmaf(av.w,bv.z,acc[3][2]); acc[3][3]=fmaf(av.w,bv.w,acc[3][3]); \
}while(0)

__global__ void k_sentinel(float* out){ out[blockIdx.x*256 + threadIdx.x] = 1.0e6f; }

// prep: f16 weight copies, zero legacy accumulators. Runs AFTER k_sel (aliases L).
__global__ __launch_bounds__(256) void k_prep(
    const float* __restrict__ fW1, const float* __restrict__ fW2,
    const float* __restrict__ dW1, const float* __restrict__ eW3,
    f16* __restrict__ fW1h, f16* __restrict__ fW2h, f16* __restrict__ dW1h,
    f16* __restrict__ eW3h, float* __restrict__ accAll)
{
    const int i = blockIdx.x*256 + threadIdx.x;   // 524288 threads
    int f = i >> 9, l = i & 511;
    fW1h[i] = (f16)fW1[(size_t)f*2560 + l];       // x-part only (cols 0..511)
    fW2h[i] = (f16)fW2[i];
    if (i < 8192) { dW1h[i] = (f16)dW1[i]; eW3h[i] = (f16)eW3[i]; }
    if (i < 4096) accAll[i] = 0.f;
}

// ---------------- c-layers (NT, fp32: feeds argmax) + FUSED column stats ----------------
__global__ __launch_bounds__(256) void k_gemm_c(
    const float* __restrict__ A, const float* __restrict__ W, float* __restrict__ C,
    int N, int K, const float* __restrict__ sc, const float* __restrict__ sh,
    float* __restrict__ part)
{
    __shared__ __align__(16) float As[16][68];
    __shared__ __align__(16) float Ws[16][68];
    __shared__ float redc[512];
    const int n0 = blockIdx.x * 64, m0 = blockIdx.y * 64;
    const int t = threadIdx.x;
    const int kk = t & 15, ri = t >> 4;
    const int tx = t & 15, ty = t >> 4;
    float acc[4][4] = {{0.f,0.f,0.f,0.f},{0.f,0.f,0.f,0.f},{0.f,0.f,0.f,0.f},{0.f,0.f,0.f,0.f}};
    for (int k0 = 0; k0 < K; k0 += 16) {
        float scv = 0.f, shv = 0.f;
        if (sc) { scv = sc[k0+kk]; shv = sh[k0+kk]; }
        #pragma unroll
        for (int mm = 0; mm < 4; ++mm) {
            float v = A[(size_t)(m0 + ri + mm*16) * K + k0 + kk];
            if (sc) v = lrelu(fmaf(v, scv, shv));
            As[kk][ri + mm*16] = v;
        }
        #pragma unroll
        for (int nn = 0; nn < 4; ++nn)
            Ws[kk][ri + nn*16] = W[(size_t)(n0 + ri + nn*16) * K + k0 + kk];
        __syncthreads();
        #pragma unroll
        for (int kq = 0; kq < 16; ++kq) {
            const float4 av = *reinterpret_cast<const float4*>(&As[kq][ty*4]);
            const float4 bv = *reinterpret_cast<const float4*>(&Ws[kq][tx*4]);
            FMA44(av, bv);
        }
        __syncthreads();
    }
    float sj[4], s2j[4];
    #pragma unroll
    for (int j = 0; j < 4; ++j) { sj[j] = 0.f; s2j[j] = 0.f; }
    #pragma unroll
    for (int i = 0; i < 4; ++i)
        #pragma unroll
        for (int j = 0; j < 4; ++j) {
            float v = acc[i][j];
            C[(size_t)(m0 + ty*4 + i) * N + n0 + tx*4 + j] = v;
            sj[j] += v; s2j[j] += v*v;
        }
    // reduce over ty within wave (ty spans 4 values per wave: t = ty*16+tx)
    #pragma unroll
    for (int j = 0; j < 4; ++j) {
        sj[j]  += __shfl_xor(sj[j],16);  sj[j]  += __shfl_xor(sj[j],32);
        s2j[j] += __shfl_xor(s2j[j],16); s2j[j] += __shfl_xor(s2j[j],32);
    }
    const int wave = t >> 6;
    if ((t & 63) < 16) {
        #pragma unroll
        for (int j = 0; j < 4; ++j) {
            redc[wave*128 + tx*4 + j]      = sj[j];
            redc[wave*128 + 64 + tx*4 + j] = s2j[j];
        }
    }
    __syncthreads();
    if (t < 128) {
        float v = redc[t] + redc[128 + t] + redc[256 + t] + redc[384 + t];
        if (t < 64) part[(size_t)blockIdx.y*2*N + n0 + t]            = v;
        else        part[(size_t)blockIdx.y*2*N + N + n0 + (t - 64)] = v;
    }
}

__global__ __launch_bounds__(256) void k_sel(
    const float* __restrict__ Lpre, const float* __restrict__ gumbel,
    const float* __restrict__ sc, const float* __restrict__ sh, int* __restrict__ sel)
{
    const int b = blockIdx.x, hd = threadIdx.x;
    float best = -3.0e38f; int bi = 0;
    #pragma unroll
    for (int cb = 0; cb < 8; ++cb) {
        int c = cb*256 + hd;
        float v = lrelu(fmaf(Lpre[(size_t)b*2048 + c], sc[c], sh[c])) + gumbel[(size_t)b*2048 + c];
        if (v > best) { best = v; bi = cb; }
    }
    sel[b*256 + hd] = bi;
}

__global__ __launch_bounds__(256) void k_val(const float* __restrict__ x,
    float* __restrict__ S, float* __restrict__ S2, float* __restrict__ val)
{
    const int b = blockIdx.x, t = threadIdx.x;
    float v0 = x[b*512 + t], v1 = x[b*512 + t + 256];
    __shared__ float ls[256], ls2[256];
    ls[t] = v0 + v1; ls2[t] = v0*v0 + v1*v1;
    __syncthreads();
    for (int off = 128; off; off >>= 1) { if (t < off) { ls[t]+=ls[t+off]; ls2[t]+=ls2[t+off]; } __syncthreads(); }
    if (t == 0) { float s = ls[0], s2 = ls2[0]; S[b]=s; S2[b]=s2; val[b]=0.5f*(s*s - s2); }
}

__global__ __launch_bounds__(256) void k_e1params(
    const float* __restrict__ S, const float* __restrict__ S2, const float* __restrict__ val,
    const float* __restrict__ eW1, const float* __restrict__ eg1, const float* __restrict__ eb1,
    float* __restrict__ A1, float* __restrict__ C1, float* __restrict__ accs /*384*/)
{
    const int t = threadIdx.x;
    accs[t] = 0.f; if (t < 128) accs[256 + t] = 0.f;
    __shared__ float ls[256], ls2[256];
    float s = 0.f, s2 = 0.f;
    for (int b = t; b < 512; b += 256) {
        float vb = val[b];
        s  += S[b]  + 256.f*vb;
        s2 += S2[b] + 256.f*vb*vb;
    }
    ls[t] = s; ls2[t] = s2; __syncthreads();
    for (int off = 128; off; off >>= 1) { if (t < off) { ls[t]+=ls[t+off]; ls2[t]+=ls2[t+off]; } __syncthreads(); }
    if (t < 32) {
        const float invn = 1.0f/1310720.f;
        float mu = ls[0]*invn;
        float var = fmaxf(ls2[0]*invn - mu*mu, 0.f);
        float w = eW1[t];
        float rs = 1.0f / sqrtf(w*w*var + 1e-5f);
        float a = w * eg1[t] * rs;
        A1[t] = a; C1[t] = eb1[t] - mu*a;
    }
}

// transpose eW2 (64x32)->(32x64)
__global__ void k_wtrans2(const float* __restrict__ eW2, float* __restrict__ eW2T)
{
    const int t = threadIdx.x;
    for (int i = t; i < 2048; i += 256) { int p = i >> 5, o = i & 31; eW2T[o*64 + p] = eW2[i]; }
}

// fW1 z-part transpose -> f16 (feeds only P1/Ftot additive terms; |w|~0.02)
__global__ __launch_bounds__(256) void k_transpose_fz(const float* __restrict__ fW1, f16* __restrict__ fzT)
{
    __shared__ float tile[64][65];
    const int z0 = blockIdx.x*64, f0 = blockIdx.y*64;
    const int j = threadIdx.x & 63, i0 = threadIdx.x >> 6;
    #pragma unroll
    for (int ii = 0; ii < 16; ++ii) {
        int fi = i0*16 + ii;
        tile[fi][j] = fW1[(size_t)(f0+fi)*2560 + 512 + z0 + j];
    }
    __syncthreads();
    #pragma unroll
    for (int ii = 0; ii < 16; ++ii) {
        int zi = i0*16 + ii;
        fzT[(size_t)(z0+zi)*1024 + f0 + j] = (f16)tile[j][zi];
    }
}

// parallel ftot over f16 fzT: grid (4,16); part[zc][1024] f32
__global__ __launch_bounds__(256) void k_ftot_p(const f16* __restrict__ fzT, float* __restrict__ part)
{
    const int f = blockIdx.x*256 + threadIdx.x;
    const int z0 = blockIdx.y*128;
    float s = 0.f;
    for (int z = z0; z < z0 + 128; ++z) s += (float)fzT[(size_t)z*1024 + f];
    part[(size_t)blockIdx.y*1024 + f] = s;
}
__global__ __launch_bounds__(256) void k_ftot_s(const float* __restrict__ part, float* __restrict__ Ftot)
{
    const int f = blockIdx.x*256 + threadIdx.x;
    float s = 0.f;
    #pragma unroll
    for (int zc = 0; zc < 16; ++zc) s += part[(size_t)zc*1024 + f];
    Ftot[f] = s;
}

__global__ __launch_bounds__(256) void k_p1(const f16* __restrict__ fzT, const int* __restrict__ sel,
                                            float* __restrict__ P1)
{
    const int b = blockIdx.x, t = threadIdx.x;
    float a0=0.f, a1=0.f, a2=0.f, a3=0.f;
    for (int hd = 0; hd < 256; ++hd) {
        int col = sel[b*256 + hd]*256 + hd;
        const f16* r = fzT + (size_t)col*1024;
        a0 += (float)r[t]; a1 += (float)r[t+256]; a2 += (float)r[t+512]; a3 += (float)r[t+768];
    }
    P1[b*1024 + t] = a0; P1[b*1024 + t + 256] = a1; P1[b*1024 + t + 512] = a2; P1[b*1024 + t + 768] = a3;
}

// e2 main points: v2 = eW2 * lrelu(A1*x+C1); write V2x[pt][d] f16. NO stats.
__global__ __launch_bounds__(256) void k_epass2(
    const float* __restrict__ x,
    const float* __restrict__ A1, const float* __restrict__ C1,
    const float* __restrict__ eW2T, f16* __restrict__ V2x)
{
    __shared__ float sW[2048], sA[32], sC[32];
    const int t = threadIdx.x;
    #pragma unroll
    for (int i = 0; i < 8; ++i) sW[t + 256*i] = eW2T[t + 256*i];
    if (t < 32) { sA[t] = A1[t]; sC[t] = C1[t]; }
    __syncthreads();
    const int pt = blockIdx.x*256 + t;
    float phi = x[pt];
    float v2[64];
    #pragma unroll
    for (int p = 0; p < 64; ++p) v2[p] = 0.f;
    for (int o = 0; o < 32; ++o) {
        float t1 = lrelu(fmaf(sA[o], phi, sC[o]));
        #pragma unroll
        for (int p = 0; p < 64; ++p) v2[p] = fmaf(sW[o*64 + p], t1, v2[p]);
    }
    f16* dst = V2x + (size_t)pt*64;
    #pragma unroll
    for (int dd = 0; dd < 64; dd += 8) {
        f16x8 o;
        #pragma unroll
        for (int e = 0; e < 8; ++e) o[e] = (f16)v2[dd+e];
        *reinterpret_cast<f16x8*>(dst + dd) = o;
    }
}

// e2 support points
__global__ __launch_bounds__(64) void k_esupport2(
    const float* __restrict__ val,
    const float* __restrict__ A1, const float* __restrict__ C1,
    const float* __restrict__ eW2T, float* __restrict__ V2s)
{
    const int idx = blockIdx.x, d = threadIdx.x;
    float phi = (idx < 512) ? val[idx] : 0.f;
    __shared__ float t1s[32];
    if (d < 32) t1s[d] = lrelu(fmaf(A1[d], phi, C1[d]));
    __syncthreads();
    float s = 0.f;
    #pragma unroll
    for (int o = 0; o < 32; ++o) s = fmaf(eW2T[o*64 + d], t1s[o], s);
    V2s[idx*64 + d] = s;
}

// weighted column stats over V[513][C]: grid C blocks x 64 threads; 2 atomics/block
__global__ __launch_bounds__(64) void k_wstats(
    const float* __restrict__ V, int C, float* __restrict__ acc)
{
    const int c = blockIdx.x, lane = threadIdx.x;
    float s = 0.f, s2 = 0.f;
    for (int i = lane; i < 513; i += 64) {
        float w = (i < 512) ? 256.f : 917504.f;
        float v = V[(size_t)i*C + c];
        s += w*v; s2 += w*v*v;
    }
    #pragma unroll
    for (int off = 32; off; off >>= 1) { s += __shfl_xor(s, off); s2 += __shfl_xor(s2, off); }
    if (lane == 0) { atomicAdd(&acc[c], s); atomicAdd(&acc[C + c], s2); }
}

// e2 stats scan over V2x (262144 pts x 64 ch, f16). 64 blocks; 128 atomics/block.
__global__ __launch_bounds__(256) void k_stats_v2scan(const f16* __restrict__ V2x, float* __restrict__ acc2)
{
    const int t = threadIdx.x;
    const int wave = t >> 6, lane = t & 63;
    const int g = t & 7;
    const int slot = blockIdx.x*32 + (t >> 3);
    float s[8] = {0,0,0,0,0,0,0,0}, s2[8] = {0,0,0,0,0,0,0,0};
    for (int p = slot; p < NXPT; p += 2048) {
        f16x8 v = *reinterpret_cast<const f16x8*>(V2x + (size_t)p*64 + g*8);
        #pragma unroll
        for (int e = 0; e < 8; ++e) { float f = (float)v[e]; s[e] += f; s2[e] += f*f; }
    }
    #pragma unroll
    for (int off = 8; off <= 32; off <<= 1) {
        #pragma unroll
        for (int e = 0; e < 8; ++e) { s[e] += __shfl_xor(s[e], off); s2[e] += __shfl_xor(s2[e], off); }
    }
    __shared__ float red[4*128];
    if (lane < 8) {
        #pragma unroll
        for (int e = 0; e < 8; ++e) {
            red[wave*128 + lane*16 + e]     = s[e];
            red[wave*128 + lane*16 + 8 + e] = s2[e];
        }
    }
    __syncthreads();
    if (t < 128) {
        float v = red[t] + red[128 + t] + red[256 + t] + red[384 + t];
        int gg = t >> 4, k = t & 15;
        if (k < 8) atomicAdd(&acc2[gg*8 + k], v);
        else       atomicAdd(&acc2[64 + gg*8 + (k - 8)], v);
    }
}

__global__ void k_finalize(const float* __restrict__ acc, int C, float invn,
                           const float* __restrict__ g, const float* __restrict__ bb,
                           float* __restrict__ sc, float* __restrict__ sh,
                           f16* __restrict__ sch, f16* __restrict__ shh)
{
    const int idx = blockIdx.x*blockDim.x + threadIdx.x;
    if (idx < C) {
        float m = acc[idx] * invn;
        float var = fmaxf(acc[C + idx] * invn - m*m, 0.f);
        float r = 1.0f / sqrtf(var + 1e-5f);
        float s = g[idx] * r;
        float h = bb[idx] - m*s;
        sc[idx] = s; sh[idx] = h;
        if (sch) { sch[idx] = (f16)s; shh[idx] = (f16)h; }
    }
}

// finalize from contention-free partials: P = [nPart][2C] rows
__global__ void k_finalize_p(const float* __restrict__ P, int C, int nPart, float invn,
                             const float* __restrict__ g, const float* __restrict__ bb,
                             float* __restrict__ sc, float* __restrict__ sh,
                             f16* __restrict__ sch, f16* __restrict__ shh)
{
    const int idx = blockIdx.x*blockDim.x + threadIdx.x;
    if (idx < C) {
        float s = 0.f, s2 = 0.f;
        for (int p = 0; p < nPart; ++p) {
            s  += P[(size_t)p*2*C + idx];
            s2 += P[(size_t)p*2*C + C + idx];
        }
        float m = s * invn;
        float var = fmaxf(s2 * invn - m*m, 0.f);
        float r = 1.0f / sqrtf(var + 1e-5f);
        float sv = g[idx] * r;
        float h = bb[idx] - m*sv;
        sc[idx] = sv; sh[idx] = h;
        if (sch) { sch[idx] = (f16)sv; shh[idx] = (f16)h; }
    }
}

// finalize e3 BN: sum pE3 [2048][256] partials + wstats row accw[256]
__global__ __launch_bounds__(256) void k_finalize_e3(
    const float* __restrict__ P, const float* __restrict__ accw,
    const float* __restrict__ g, const float* __restrict__ bb,
    float* __restrict__ sc, float* __restrict__ sh,
    f16* __restrict__ sch, f16* __restrict__ shh)
{
    const int t = threadIdx.x, q = t & 127, h = t >> 7;
    float s = 0.f, s2 = 0.f;
    for (int p = h*1024; p < h*1024 + 1024; ++p) {
        s  += P[(size_t)p*256 + q];
        s2 += P[(size_t)p*256 + 128 + q];
    }
    __shared__ float red[2][2][128];
    red[h][0][q] = s; red[h][1][q] = s2;
    __syncthreads();
    if (t < 128) {
        float ss  = red[0][0][q] + red[1][0][q] + accw[q];
        float ss2 = red[0][1][q] + red[1][1][q] + accw[128 + q];
        const float invn = 1.0f/1310720.f;
        float m = ss * invn;
        float var = fmaxf(ss2 * invn - m*m, 0.f);
        float r = 1.0f / sqrtf(var + 1e-5f);
        float sv = g[q] * r, hh = bb[q] - m*sv;
        sc[q] = sv; sh[q] = hh; sch[q] = (f16)sv; shh[q] = (f16)hh;
    }
}

// finalize f-BN from pF [8 fblk][512 b][256]
__global__ __launch_bounds__(256) void k_finalize_f(
    const float* __restrict__ P,
    const float* __restrict__ g, const float* __restrict__ bb,
    float* __restrict__ sc, float* __restrict__ sh,
    f16* __restrict__ sch, f16* __restrict__ shh)
{
    const int f = blockIdx.x*256 + threadIdx.x;
    const int fb = f >> 7, c = f & 127;
    const float* base = P + (size_t)fb*512*256 + c;
    float s = 0.f, s2 = 0.f;
    for (int b = 0; b < 512; ++b) {
        s  += base[(size_t)b*256];
        s2 += base[(size_t)b*256 + 128];
    }
    float m = s*(1.0f/65536.f);
    float var = fmaxf(s2*(1.0f/65536.f) - m*m, 0.f);
    float r = 1.0f/sqrtf(var + 1e-5f);
    float sv = g[f]*r, h = bb[f] - m*sv;
    sc[f] = sv; sh[f] = h; sch[f] = (f16)sv; shh[f] = (f16)h;
}

// finalize d1-BN from pD1 [2048][128]
__global__ __launch_bounds__(256) void k_finalize_d1(
    const float* __restrict__ P,
    const float* __restrict__ g, const float* __restrict__ bb,
    float* __restrict__ sc, float* __restrict__ sh)
{
    const int t = threadIdx.x, d = t & 63, gr = t >> 6;  // 4 groups x 512 rows
    float s = 0.f, s2 = 0.f;
    for (int p = gr*512; p < gr*512 + 512; ++p) {
        s  += P[(size_t)p*128 + d];
        s2 += P[(size_t)p*128 + 64 + d];
    }
    __shared__ float red[4][2][64];
    red[gr][0][d] = s; red[gr][1][d] = s2;
    __syncthreads();
    if (t < 64) {
        float ss  = red[0][0][t]+red[1][0][t]+red[2][0][t]+red[3][0][t];
        float ss2 = red[0][1][t]+red[1][1][t]+red[2][1][t]+red[3][1][t];
        float m = ss*(1.0f/262144.f);
        float var = fmaxf(ss2*(1.0f/262144.f) - m*m, 0.f);
        float r = 1.0f/sqrtf(var + 1e-5f);
        float sv = g[t]*r;
        sc[t] = sv; sh[t] = bb[t] - m*sv;
    }
}

// finalize d2-BN from pD2 [4096][64] rows ([32 sums][32 sumsq])
__global__ __launch_bounds__(256) void k_finalize_d2(
    const float* __restrict__ P,
    const float* __restrict__ g, const float* __restrict__ bb,
    float* __restrict__ sc, float* __restrict__ sh)
{
    const int t = threadIdx.x, e = t & 31, gr = t >> 5;  // 8 groups x 512 rows
    float s = 0.f, s2 = 0.f;
    for (int p = gr*512; p < gr*512 + 512; ++p) {
        s  += P[(size_t)p*64 + e];
        s2 += P[(size_t)p*64 + 32 + e];
    }
    __shared__ float red[8][2][32];
    red[gr][0][e] = s; red[gr][1][e] = s2;
    __syncthreads();
    if (t < 32) {
        float ss = 0.f, ss2 = 0.f;
        #pragma unroll
        for (int k2 = 0; k2 < 8; ++k2) { ss += red[k2][0][t]; ss2 += red[k2][1][t]; }
        float m = ss*(1.0f/262144.f);
        float var = fmaxf(ss2*(1.0f/262144.f) - m*m, 0.f);
        float r = 1.0f/sqrtf(var + 1e-5f);
        float sv = g[t]*r;
        sc[t] = sv; sh[t] = bb[t] - m*sv;
    }
}

// MFMA e3 + fused V3xT stats partials; packed-f16 BN on V2x (sc2h/sh2h f16)
__global__ __launch_bounds__(256) void k_mfma_e3(
    const f16* __restrict__ eW3h, const f16* __restrict__ V2x,
    const f16* __restrict__ sc2h, const f16* __restrict__ sh2h,
    f16* __restrict__ V3xT, float* __restrict__ pE3)
{
    __shared__ __align__(16) f16 As[128][76];   // eW3 rows q, cols d
    __shared__ __align__(16) f16 Bs[128][76];   // t2 rows point, cols d
    __shared__ float rede[256];
    const int b = blockIdx.y, l0 = blockIdx.x * 128;
    const int t = threadIdx.x;
    const int wave = t >> 6, lane = t & 63;
    const int quad = lane >> 4, l16 = lane & 15;
    const int row = t >> 1, half = t & 1;
    #pragma unroll
    for (int c = 0; c < 4; ++c)
        *reinterpret_cast<f16x8*>(&As[row][half*32 + c*8]) =
            *reinterpret_cast<const f16x8*>(eW3h + row*64 + half*32 + c*8);
    const f16* src = V2x + ((size_t)(b*512 + l0 + row))*64 + half*32;
    #pragma unroll
    for (int c = 0; c < 4; ++c) {
        f16x8 v = *reinterpret_cast<const f16x8*>(src + c*8);
        const f16x8 csc = *reinterpret_cast<const f16x8*>(sc2h + half*32 + c*8);
        const f16x8 csh = *reinterpret_cast<const f16x8*>(sh2h + half*32 + c*8);
        *reinterpret_cast<f16x8*>(&Bs[row][half*32 + c*8]) = bnl8(v, csc, csh);
    }
    __syncthreads();
    f32x4 acc[2][8];
    #pragma unroll
    for (int i = 0; i < 2; ++i)
        #pragma unroll
        for (int j = 0; j < 8; ++j) acc[i][j] = (f32x4){0.f,0.f,0.f,0.f};
    f16x8 a0  = *reinterpret_cast<const f16x8*>(&As[32*wave + l16][quad*8]);
    f16x8 a0b = *reinterpret_cast<const f16x8*>(&As[32*wave + l16][32 + quad*8]);
    f16x8 a1  = *reinterpret_cast<const f16x8*>(&As[32*wave + 16 + l16][quad*8]);
    f16x8 a1b = *reinterpret_cast<const f16x8*>(&As[32*wave + 16 + l16][32 + quad*8]);
    #pragma unroll
    for (int j = 0; j < 8; ++j) {
        f16x8 bj  = *reinterpret_cast<const f16x8*>(&Bs[16*j + l16][quad*8]);
        f16x8 bjb = *reinterpret_cast<const f16x8*>(&Bs[16*j + l16][32 + quad*8]);
        acc[0][j] = __builtin_amdgcn_mfma_f32_16x16x32_f16(a0,  bj,  acc[0][j], 0, 0, 0);
        acc[0][j] = __builtin_amdgcn_mfma_f32_16x16x32_f16(a0b, bjb, acc[0][j], 0, 0, 0);
        acc[1][j] = __builtin_amdgcn_mfma_f32_16x16x32_f16(a1,  bj,  acc[1][j], 0, 0, 0);
        acc[1][j] = __builtin_amdgcn_mfma_f32_16x16x32_f16(a1b, bjb, acc[1][j], 0, 0, 0);
    }
    float se[8] = {0,0,0,0,0,0,0,0}, s2e[8] = {0,0,0,0,0,0,0,0};
    #pragma unroll
    for (int i = 0; i < 2; ++i) {
        #pragma unroll
        for (int r = 0; r < 4; ++r) {
            int q = 32*wave + 16*i + quad*4 + r;
            #pragma unroll
            for (int j = 0; j < 8; ++j) {
                float v = acc[i][j][r];
                V3xT[((size_t)b*128 + q)*512 + l0 + 16*j + l16] = (f16)v;
                se[i*4+r] += v; s2e[i*4+r] += v*v;
            }
        }
    }
    #pragma unroll
    for (int k = 0; k < 8; ++k) {
        se[k]  += __shfl_xor(se[k],1);  se[k]  += __shfl_xor(se[k],2);
        se[k]  += __shfl_xor(se[k],4);  se[k]  += __shfl_xor(se[k],8);
        s2e[k] += __shfl_xor(s2e[k],1); s2e[k] += __shfl_xor(s2e[k],2);
        s2e[k] += __shfl_xor(s2e[k],4); s2e[k] += __shfl_xor(s2e[k],8);
    }
    if (l16 == 0) {
        #pragma unroll
        for (int i = 0; i < 2; ++i)
            #pragma unroll
            for (int r = 0; r < 4; ++r) {
                int qq = 32*wave + 16*i + quad*4 + r;
                rede[qq]       = se[i*4+r];
                rede[128 + qq] = s2e[i*4+r];
            }
    }
    __syncthreads();
    pE3[((size_t)(blockIdx.x*512 + b))*256 + t] = rede[t];
}

// e3 support points
__global__ __launch_bounds__(128) void k_esupport3(
    const float* __restrict__ V2s, const float* __restrict__ sc2, const float* __restrict__ sh2,
    const float* __restrict__ eW3, float* __restrict__ V3s)
{
    const int idx = blockIdx.x, q = threadIdx.x;
    __shared__ float t2s[64];
    if (q < 64) t2s[q] = lrelu(fmaf(sc2[q], V2s[idx*64 + q], sh2[q]));
    __syncthreads();
    float s = 0.f;
    #pragma unroll
    for (int d = 0; d < 64; ++d) s = fmaf(eW3[q*64 + d], t2s[d], s);
    V3s[idx*128 + q] = s;
}

__global__ void k_u(const float* __restrict__ V3s, const float* __restrict__ sc3, const float* __restrict__ sh3,
                    float* __restrict__ u1, float* __restrict__ u0)
{
    const int idx = blockIdx.x*256 + threadIdx.x;
    if (idx < 513*128) {
        int i = idx >> 7, q = idx & 127;
        float tv = lrelu(fmaf(sc3[q], V3s[idx], sh3[q]));
        if (i < 512) u1[idx] = tv; else u0[q] = tv;
    }
}

// ---------------- MFMA fw1 (pipeline + fused out6T stats; hoisted epilogue loads) ----------------
__global__ __launch_bounds__(256) void k_mfma_fw1T(
    const f16* __restrict__ fW1h, const f16* __restrict__ V3xT,
    const f16* __restrict__ sceh, const f16* __restrict__ sheh,
    const float* __restrict__ u1, const float* __restrict__ u0,
    const float* __restrict__ P1, const float* __restrict__ Ftot,
    f16* __restrict__ out6T, float* __restrict__ pF)
{
    __shared__ __align__(16) f16 lds[24576];    // 3 sets x (A 4096 + B 4096) f16
    __shared__ float redf[1024];
    const int t = threadIdx.x;
    const int wave = t >> 6, lane = t & 63;
    const int quad = lane >> 4, l16 = lane & 15;
    const int n = blockIdx.x + (blockIdx.y << 3);
    const int b = (n & 7)*64 + (n >> 6);
    const int fblk = (n >> 3) & 7;
    const int f0 = fblk * 128;
    const f16* Aa = V3xT + (size_t)b*65536;
    const f16* Bb = fW1h + (size_t)f0*512;
    const int sg = (t & 3) ^ ((t >> 3) & 3);
    const size_t go0 = (size_t)(t >> 2)*512 + sg*8;
    const size_t go1 = go0 + (size_t)64*512;
    const int rA0 = 32*wave + l16, rA1 = rA0 + 16;
    const f16x8 scA0 = splat8(sceh[rA0]), shA0 = splat8(sheh[rA0]);
    const f16x8 scA1 = splat8(sceh[rA1]), shA1 = splat8(sheh[rA1]);
    const int offA0 = swz_off(rA0, quad);
    const int offA1 = swz_off(rA1, quad);
    int offB[8];
    #pragma unroll
    for (int j = 0; j < 8; ++j) offB[j] = swz_off(16*j + l16, quad);
    // hoisted epilogue operands: latency hides under the whole k-loop
    float p1j[8], p0j[8], u1q[8], u0q[8];
    #pragma unroll
    for (int j = 0; j < 8; ++j) {
        int f = f0 + 16*j + l16;
        p1j[j] = P1[b*1024 + f];
        p0j[j] = Ftot[f] - p1j[j];
    }
    #pragma unroll
    for (int i = 0; i < 2; ++i)
        #pragma unroll
        for (int r = 0; r < 4; ++r) {
            int q = 32*wave + 16*i + quad*4 + r;
            u1q[i*4+r] = u1[b*128 + q];
            u0q[i*4+r] = u0[q];
        }
    f32x4 acc[2][8];
    #pragma unroll
    for (int i = 0; i < 2; ++i)
        #pragma unroll
        for (int j = 0; j < 8; ++j) acc[i][j] = (f32x4){0.f,0.f,0.f,0.f};
    dma_pair(Aa + go0,      Aa + go1,      lds,               t);
    dma_pair(Bb + go0,      Bb + go1,      lds + 4096,        t);
    dma_pair(Aa + 32 + go0, Aa + 32 + go1, lds + 8192,        t);
    dma_pair(Bb + 32 + go0, Bb + 32 + go1, lds + 8192 + 4096, t);
    int m = 0;
    for (int kt = 0; kt < 16; ++kt) {
        SCHED0; BARRIER; SCHED0;
        if (kt <= 13) {
            const int mp = (m >= 1) ? m - 1 : m + 2;
            const int k0 = (kt + 2) * 32;
            dma_pair(Aa + k0 + go0, Aa + k0 + go1, lds + mp*8192,        t);
            dma_pair(Bb + k0 + go0, Bb + k0 + go1, lds + mp*8192 + 4096, t);
            asm volatile("s_waitcnt vmcnt(8)" ::: "memory");
        } else if (kt == 14) {
            asm volatile("s_waitcnt vmcnt(4)" ::: "memory");
        } else {
            asm volatile("s_waitcnt vmcnt(0)" ::: "memory");
        }
        SCHED0; BARRIER; SCHED0;
        const f16* As = lds + m*8192;
        const f16* Bs = As + 4096;
        f16x8 a0 = bnl8(*reinterpret_cast<const f16x8*>(As + offA0), scA0, shA0);
        f16x8 a1 = bnl8(*reinterpret_cast<const f16x8*>(As + offA1), scA1, shA1);
        #pragma unroll
        for (int j = 0; j < 8; ++j) {
            f16x8 bj = *reinterpret_cast<const f16x8*>(Bs + offB[j]);
            acc[0][j] = __builtin_amdgcn_mfma_f32_16x16x32_f16(a0, bj, acc[0][j], 0, 0, 0);
            acc[1][j] = __builtin_amdgcn_mfma_f32_16x16x32_f16(a1, bj, acc[1][j], 0, 0, 0);
        }
        m = (m == 2) ? 0 : m + 1;
    }
    float sj[8], s2j[8];
    #pragma unroll
    for (int j = 0; j < 8; ++j) { sj[j] = 0.f; s2j[j] = 0.f; }
    #pragma unroll
    for (int i = 0; i < 2; ++i) {
        #pragma unroll
        for (int r = 0; r < 4; ++r) {
            int q = 32*wave + 16*i + quad*4 + r;
            #pragma unroll
            for (int j = 0; j < 8; ++j) {
                int f = f0 + 16*j + l16;
                float v = acc[i][j][r] + u1q[i*4+r]*p1j[j] + u0q[i*4+r]*p0j[j];
                out6T[((size_t)b*128 + q)*1024 + f] = (f16)v;
                sj[j] += v; s2j[j] += v*v;
            }
        }
    }
    #pragma unroll
    for (int j = 0; j < 8; ++j) {
        sj[j]  += __shfl_xor(sj[j],16);  sj[j]  += __shfl_xor(sj[j],32);
        s2j[j] += __shfl_xor(s2j[j],16); s2j[j] += __shfl_xor(s2j[j],32);
    }
    if (quad == 0) {
        #pragma unroll
        for (int j = 0; j < 8; ++j) {
            redf[wave*256 + j*16 + l16]       = sj[j];
            redf[wave*256 + 128 + j*16 + l16] = s2j[j];
        }
    }
    __syncthreads();
    {
        float v = redf[t] + redf[256 + t] + redf[512 + t] + redf[768 + t];
        pF[((size_t)(fblk*512 + b))*256 + t] = v;
    }
}

// ---------------- MFMA fw2 (triple-buffered pipeline + in-place LDS BN) ----------------
__global__ __launch_bounds__(256) void k_mfma_fw2T(
    const f16* __restrict__ fW2h, const f16* __restrict__ out6T,
    const f16* __restrict__ scfh, const f16* __restrict__ shfh,
    const float* __restrict__ fbias2, f16* __restrict__ out7)
{
    __shared__ __align__(16) f16 lds[24576];
    __shared__ __align__(16) f16 scL[1024];
    __shared__ __align__(16) f16 shL[1024];
    const int t = threadIdx.x;
    const int wave = t >> 6, lane = t & 63;
    const int quad = lane >> 4, l16 = lane & 15;
    const int n = blockIdx.x + (blockIdx.y << 2);
    const int b = (n & 7)*64 + (n >> 5);
    const int o0 = ((n >> 3) & 3) * 128;
    const f16* Aa = fW2h + (size_t)o0*1024;
    const f16* Bb = out6T + (size_t)b*131072;
    const int sg = (t & 3) ^ ((t >> 3) & 3);
    const size_t go0 = (size_t)(t >> 2)*1024 + sg*8;
    const size_t go1 = go0 + (size_t)64*1024;
    const int bnO = sg*8;
    const int offA0 = swz_off(32*wave + l16, quad);
    const int offA1 = swz_off(32*wave + 16 + l16, quad);
    int offB[8];
    #pragma unroll
    for (int j = 0; j < 8; ++j) offB[j] = swz_off(16*j + l16, quad);
    // hoisted bias loads
    float biasv[8];
    #pragma unroll
    for (int i = 0; i < 2; ++i)
        #pragma unroll
        for (int r = 0; r < 4; ++r)
            biasv[i*4+r] = fbias2[o0 + 32*wave + 16*i + quad*4 + r];
    f32x4 acc[2][8];
    #pragma unroll
    for (int i = 0; i < 2; ++i)
        #pragma unroll
        for (int j = 0; j < 8; ++j) acc[i][j] = (f32x4){0.f,0.f,0.f,0.f};
    if (t < 128) *reinterpret_cast<f16x8*>(&scL[t*8]) =
        *reinterpret_cast<const f16x8*>(scfh + t*8);
    else         *reinterpret_cast<f16x8*>(&shL[(t-128)*8]) =
        *reinterpret_cast<const f16x8*>(shfh + (t-128)*8);
    __syncthreads();
    dma_pair(Aa + go0,      Aa + go1,      lds,               t);
    dma_pair(Bb + go0,      Bb + go1,      lds + 4096,        t);
    dma_pair(Aa + 32 + go0, Aa + 32 + go1, lds + 8192,        t);
    dma_pair(Bb + 32 + go0, Bb + 32 + go1, lds + 8192 + 4096, t);
    int m = 0;
    for (int kt = 0; kt < 32; ++kt) {
        SCHED0; BARRIER; SCHED0;
        if (kt <= 29) {
            const int mp = (m >= 1) ? m - 1 : m + 2;
            const int k0 = (kt + 2) * 32;
            dma_pair(Aa + k0 + go0, Aa + k0 + go1, lds + mp*8192,        t);
            dma_pair(Bb + k0 + go0, Bb + k0 + go1, lds + mp*8192 + 4096, t);
            asm volatile("s_waitcnt vmcnt(8)" ::: "memory");
        } else if (kt == 30) {
            asm volatile("s_waitcnt vmcnt(4)" ::: "memory");
        } else {
            asm volatile("s_waitcnt vmcnt(0)" ::: "memory");
        }
        SCHED0; BARRIER; SCHED0;
        {
            f16* Bm = lds + m*8192 + 4096;
            const f16x8 csc = *reinterpret_cast<const f16x8*>(&scL[kt*32 + bnO]);
            const f16x8 csh = *reinterpret_cast<const f16x8*>(&shL[kt*32 + bnO]);
            f16x8 v0 = *reinterpret_cast<const f16x8*>(Bm + t*8);
            f16x8 v1 = *reinterpret_cast<const f16x8*>(Bm + 2048 + t*8);
            *reinterpret_cast<f16x8*>(Bm + t*8)        = bnl8(v0, csc, csh);
            *reinterpret_cast<f16x8*>(Bm + 2048 + t*8) = bnl8(v1, csc, csh);
        }
        asm volatile("s_waitcnt lgkmcnt(0)" ::: "memory");
        SCHED0; BARRIER; SCHED0;
        const f16* As = lds + m*8192;
        const f16* Bs = As + 4096;
        f16x8 a0 = *reinterpret_cast<const f16x8*>(As + offA0);
        f16x8 a1 = *reinterpret_cast<const f16x8*>(As + offA1);
        #pragma unroll
        for (int j = 0; j < 8; ++j) {
            f16x8 bj = *reinterpret_cast<const f16x8*>(Bs + offB[j]);
            acc[0][j] = __builtin_amdgcn_mfma_f32_16x16x32_f16(a0, bj, acc[0][j], 0, 0, 0);
            acc[1][j] = __builtin_amdgcn_mfma_f32_16x16x32_f16(a1, bj, acc[1][j], 0, 0, 0);
        }
        m = (m == 2) ? 0 : m + 1;
    }
    #pragma unroll
    for (int i = 0; i < 2; ++i) {
        #pragma unroll
        for (int r = 0; r < 4; ++r) {
            int o = o0 + 32*wave + 16*i + quad*4 + r;
            #pragma unroll
            for (int j = 0; j < 8; ++j) {
                int q = 16*j + l16;
                out7[((size_t)b*512 + o)*128 + q] = (f16)(acc[i][j][r] + biasv[i*4+r]);
            }
        }
    }
}

// ---------------- MFMA d1 (f16 output + fused stats) ----------------
__global__ __launch_bounds__(256) void k_mfma_d1(
    const f16* __restrict__ dW1h, const f16* __restrict__ out7,
    f16* __restrict__ d1pre, float* __restrict__ pD1)
{
    __shared__ __align__(16) f16 As[64][44];
    __shared__ __align__(16) f16 Bs[128][44];
    __shared__ float redd[128];
    const int b = blockIdx.y, o0 = blockIdx.x * 128;
    const int t = threadIdx.x;
    const int wave = t >> 6, lane = t & 63;
    const int quad = lane >> 4, l16 = lane & 15;
    const int row0 = t >> 2, grp = t & 3;
    const f16* Bb = out7 + (size_t)b*65536;
    f32x4 acc[8];
    #pragma unroll
    for (int j = 0; j < 8; ++j) acc[j] = (f32x4){0.f,0.f,0.f,0.f};
    for (int k0 = 0; k0 < 128; k0 += 32) {
        *reinterpret_cast<f16x8*>(&As[row0][grp*8]) =
            *reinterpret_cast<const f16x8*>(dW1h + row0*128 + k0 + grp*8);
        #pragma unroll
        for (int p = 0; p < 2; ++p) {
            const int row = row0 + 64*p;
            *reinterpret_cast<f16x8*>(&Bs[row][grp*8]) =
                *reinterpret_cast<const f16x8*>(Bb + (size_t)(o0+row)*128 + k0 + grp*8);
        }
        __syncthreads();
        f16x8 a0 = *reinterpret_cast<const f16x8*>(&As[16*wave + l16][quad*8]);
        #pragma unroll
        for (int j = 0; j < 8; ++j) {
            f16x8 bj = *reinterpret_cast<const f16x8*>(&Bs[16*j + l16][quad*8]);
            acc[j] = __builtin_amdgcn_mfma_f32_16x16x32_f16(a0, bj, acc[j], 0, 0, 0);
        }
        __syncthreads();
    }
    float sd[4] = {0,0,0,0}, s2d[4] = {0,0,0,0};
    #pragma unroll
    for (int r = 0; r < 4; ++r) {
        int d = 16*wave + quad*4 + r;
        #pragma unroll
        for (int j = 0; j < 8; ++j) {
            int o = o0 + 16*j + l16;
            float v = acc[j][r];
            d1pre[(size_t)b*32768 + (size_t)d*512 + o] = (f16)v;
            sd[r] += v; s2d[r] += v*v;
        }
    }
    #pragma unroll
    for (int r = 0; r < 4; ++r) {
        sd[r]  += __shfl_xor(sd[r],1);  sd[r]  += __shfl_xor(sd[r],2);
        sd[r]  += __shfl_xor(sd[r],4);  sd[r]  += __shfl_xor(sd[r],8);
        s2d[r] += __shfl_xor(s2d[r],1); s2d[r] += __shfl_xor(s2d[r],2);
        s2d[r] += __shfl_xor(s2d[r],4); s2d[r] += __shfl_xor(s2d[r],8);
    }
    if (l16 == 0) {
        #pragma unroll
        for (int r = 0; r < 4; ++r) {
            int dd = 16*wave + quad*4 + r;
            redd[dd] = sd[r]; redd[64 + dd] = s2d[r];
        }
    }
    __syncthreads();
    if (t < 128) pD1[((size_t)(blockIdx.x*512 + b))*128 + t] = redd[t];
}

// d2: C[e,o] = sum_d dW2[e,d] * lrelu(sc*d1pre[b][d][o]+sh)  (d1pre f16) + fused stats
// d2pre stored as f16 (stats computed pre-rounding)
__global__ __launch_bounds__(128) void k_gemm_d2(
    const float* __restrict__ dW2, const f16* __restrict__ d1pre,
    const float* __restrict__ scd, const float* __restrict__ shd,
    f16* __restrict__ d2pre, float* __restrict__ pD2)
{
    __shared__ __align__(16) float As[16][36];
    __shared__ __align__(16) float Bs[16][68];
    __shared__ float sred[64];
    const int n0 = blockIdx.x * 64, b = blockIdx.y;
    const int t = threadIdx.x;
    const int kk = t & 15, ri = t >> 4;
    const int qv = t & 63, kh = t >> 6;
    const int tx = t & 15, ty = t >> 4;
    float acc[4][4] = {{0.f,0.f,0.f,0.f},{0.f,0.f,0.f,0.f},{0.f,0.f,0.f,0.f},{0.f,0.f,0.f,0.f}};
    for (int k0 = 0; k0 < 64; k0 += 16) {
        #pragma unroll
        for (int mm = 0; mm < 4; ++mm)
            As[kk][ri + mm*8] = dW2[(ri + mm*8)*64 + k0 + kk];
        #pragma unroll
        for (int ki = 0; ki < 8; ++ki) {
            int d = k0 + kh + ki*2;
            float v = (float)d1pre[(size_t)b*32768 + (size_t)d*512 + n0 + qv];
            Bs[kh + ki*2][qv] = lrelu(fmaf(scd[d], v, shd[d]));
        }
        __syncthreads();
        #pragma unroll
        for (int kq = 0; kq < 16; ++kq) {
            const float4 av = *reinterpret_cast<const float4*>(&As[kq][ty*4]);
            const float4 bv = *reinterpret_cast<const float4*>(&Bs[kq][tx*4]);
            FMA44(av, bv);
        }
        __syncthreads();
    }
    #pragma unroll
    for (int i = 0; i < 4; ++i) {
        float s = 0.f, s2 = 0.f;
        #pragma unroll
        for (int j = 0; j < 4; ++j) {
            float v = acc[i][j];
            d2pre[(size_t)b*16384 + (size_t)(ty*4 + i)*512 + n0 + tx*4 + j] = (f16)v;
            s += v; s2 += v*v;
        }
        s  += __shfl_xor(s,1);  s  += __shfl_xor(s,2);
        s  += __shfl_xor(s,4);  s  += __shfl_xor(s,8);
        s2 += __shfl_xor(s2,1); s2 += __shfl_xor(s2,2);
        s2 += __shfl_xor(s2,4); s2 += __shfl_xor(s2,8);
        if (tx == 0) {
            int e = ty*4 + i;
            sred[e] = s; sred[32 + e] = s2;
        }
    }
    __syncthreads();
    if (t < 64) pD2[((size_t)(blockIdx.y*8 + blockIdx.x))*64 + t] = sred[t];
}

__global__ __launch_bounds__(256) void k_d3(
    const f16* __restrict__ d2pre, const float* __restrict__ dW3,
    const float* __restrict__ sce, const float* __restrict__ she,
    const float* __restrict__ dbias3, float* __restrict__ out)
{
    const int idx = blockIdx.x*256 + threadIdx.x;
    const int b = idx >> 9, o = idx & 511;
    float s = dbias3[0];
    for (int e = 0; e < 32; ++e) {
        float v = (float)d2pre[(size_t)b*16384 + e*512 + o];
        s = fmaf(dW3[e], lrelu(fmaf(v, sce[e], she[e])), s);
    }
    out[idx] = s;
}

extern "C" void kernel_launch(void* const* d_in, const int* in_sizes, int n_in,
                              void* d_out, int out_size, void* d_ws, size_t ws_size,
                              hipStream_t stream)
{
    (void)in_sizes; (void)n_in; (void)out_size;
    const float* x      = (const float*)d_in[0];
    const float* gumbel = (const float*)d_in[1];
    const float* cW1 = (const float*)d_in[2];
    const float* cg1 = (const float*)d_in[3];
    const float* cb1 = (const float*)d_in[4];
    const float* cW2 = (const float*)d_in[5];
    const float* cg2 = (const float*)d_in[6];
    const float* cb2 = (const float*)d_in[7];
    const float* cW3 = (const float*)d_in[8];
    const float* cg3 = (const float*)d_in[9];
    const float* cb3 = (const float*)d_in[10];
    const float* eW1 = (const float*)d_in[11];
    const float* eg1 = (const float*)d_in[12];
    const float* eb1 = (const float*)d_in[13];
    const float* eW2 = (const float*)d_in[14];
    const float* eg2 = (const float*)d_in[15];
    const float* eb2 = (const float*)d_in[16];
    const float* eW3 = (const float*)d_in[17];
    const float* eg3 = (const float*)d_in[18];
    const float* eb3 = (const float*)d_in[19];
    const float* fW1 = (const float*)d_in[20];
    const float* fg1 = (const float*)d_in[21];
    const float* fb1 = (const float*)d_in[22];
    const float* fW2 = (const float*)d_in[23];
    const float* fbias2 = (const float*)d_in[24];
    const float* dW1 = (const float*)d_in[25];
    const float* dg1 = (const float*)d_in[26];
    const float* db1 = (const float*)d_in[27];
    const float* dW2 = (const float*)d_in[28];
    const float* dg2 = (const float*)d_in[29];
    const float* db2 = (const float*)d_in[30];
    const float* dW3 = (const float*)d_in[31];
    const float* dbias3 = (const float*)d_in[32];
    float* out = (float*)d_out;
    float* ws  = (float*)d_ws;

    if (ws_size < O_END * sizeof(float)) {
        k_sentinel<<<1024,256,0,stream>>>(out);
        return;
    }

    float* H1  = ws + O_H1;
    float* H2  = ws + O_H2;
    float* L   = ws + O_L;
    int*   sel = (int*)(ws + O_SEL);
    float* S   = ws + O_S;
    float* S2  = ws + O_S2;
    float* val = ws + O_VAL;
    float* prm = ws + O_PRM;
    f16*   fW1h= (f16*)(ws + O_FW1H);
    f16*   fW2h= (f16*)(ws + O_FW2H);
    float* accF= ws + O_ACCF;
    f16*   dW1h= (f16*)(ws + O_DW1H);
    f16*   eW3h= (f16*)(ws + O_EW3H);
    float* V2s = ws + O_V2SS;
    float* u1  = ws + O_U1;
    float* P1  = ws + O_P1;
    f16*   fzT = (f16*)(ws + O_FZT);    // f16 now
    float* V3s = ws + O_V3S;
    float* pF  = ws + O_PF;             // fw1 stats partials (H1+H2)
    float* pFT = ws + O_H1;             // ftot partials: 16 x 1024 f32 (H1, free post c-path)
    float* pD1 = ws + O_PD1;            // d1 stats partials (H2; pF dead by then)
    float* pD2 = ws + O_PD2;
    float* p2d = ws + O_P1;             // c-stats partials (P1 written later)
    float* pE3 = ws + O_FZT;            // e3 stats partials (fzT dead after k_p1)
    f16*   V3xT= (f16*)(ws + O_BIG1);
    f16*   out7= (f16*)(ws + O_BIG1);   // aliases V3xT (dead after fw1)
    f16*   out6T=(f16*)(ws + O_BIG2);
    f16*   V2x = (f16*)(ws + O_BIG2);   // aliases out6T
    f16*   d1p = (f16*)(ws + O_D1);     // f16; aliases out6T (dead after fw2)
    f16*   d2p = (f16*)(ws + O_D2);     // f16

    const float invN_e = 1.0f/1310720.f;

    // ---- c-path (deterministic fp32; feeds argmax); stats fused into gemm ----
    k_gemm_c<<<dim3(16,8),256,0,stream>>>(x,  cW1, H1, 1024, 512,  nullptr,     nullptr, p2d);
    k_finalize_p<<<4,256,0,stream>>>(p2d, 1024, 8, 1.0f/512.f, cg1, cb1,
                                     prm+P_SC1, prm+P_SH1, nullptr, nullptr);
    k_gemm_c<<<dim3(16,8),256,0,stream>>>(H1, cW2, H2, 1024, 1024, prm+P_SC1, prm+P_SH1, p2d);
    k_finalize_p<<<4,256,0,stream>>>(p2d, 1024, 8, 1.0f/512.f, cg2, cb2,
                                     prm+P_SC2, prm+P_SH2, nullptr, nullptr);
    k_gemm_c<<<dim3(32,8),256,0,stream>>>(H2, cW3, L,  2048, 1024, prm+P_SC2, prm+P_SH2, p2d);
    k_finalize_p<<<8,256,0,stream>>>(p2d, 2048, 8, 1.0f/512.f, cg3, cb3,
                                     prm+P_SC3, prm+P_SH3, nullptr, nullptr);
    k_sel<<<512,256,0,stream>>>(L, gumbel, prm+P_SC3, prm+P_SH3, sel);

    // ---- weight prep (overwrites L region) + selection-derived helpers ----
    k_prep<<<2048,256,0,stream>>>(fW1, fW2, dW1, eW3, fW1h, fW2h, dW1h, eW3h, accF);
    k_val<<<512,256,0,stream>>>(x, S, S2, val);
    k_e1params<<<1,256,0,stream>>>(S, S2, val, eW1, eg1, eb1, prm+P_A1, prm+P_C1, prm+P_ACC2);
    k_transpose_fz<<<dim3(32,16),256,0,stream>>>(fW1, fzT);
    k_wtrans2<<<1,256,0,stream>>>(eW2, prm+P_EW2T);
    k_ftot_p<<<dim3(4,16),256,0,stream>>>(fzT, pFT);
    k_ftot_s<<<4,256,0,stream>>>(pFT, prm+P_FTOT);
    k_p1<<<512,256,0,stream>>>(fzT, sel, P1);

    // ---- e-path ----
    k_epass2<<<1024,256,0,stream>>>(x, prm+P_A1, prm+P_C1, prm+P_EW2T, V2x);
    k_esupport2<<<513,64,0,stream>>>(val, prm+P_A1, prm+P_C1, prm+P_EW2T, V2s);
    k_stats_v2scan<<<64,256,0,stream>>>(V2x, prm+P_ACC2);
    k_wstats<<<64,64,0,stream>>>(V2s, 64, prm+P_ACC2);
    k_finalize<<<1,256,0,stream>>>(prm+P_ACC2, 64, invN_e, eg2, eb2, prm+P_SCE2, prm+P_SHE2,
                                   (f16*)(prm+P_SCE2H), (f16*)(prm+P_SHE2H));
    k_mfma_e3<<<dim3(4,512),256,0,stream>>>(eW3h, V2x,
                                            (const f16*)(prm+P_SCE2H), (const f16*)(prm+P_SHE2H),
                                            V3xT, pE3);
    k_esupport3<<<513,128,0,stream>>>(V2s, prm+P_SCE2, prm+P_SHE2, eW3, V3s);
    k_wstats<<<128,64,0,stream>>>(V3s, 128, prm+P_ACC3);
    k_finalize_e3<<<1,256,0,stream>>>(pE3, prm+P_ACC3, eg3, eb3, prm+P_SCE3, prm+P_SHE3,
                                      (f16*)(prm+P_SCE3H), (f16*)(prm+P_SHE3H));
    k_u<<<257,256,0,stream>>>(V3s, prm+P_SCE3, prm+P_SHE3, u1, prm+P_U0);

    // ---- f-path (MFMA f16) ----
    k_mfma_fw1T<<<dim3(8,512),256,0,stream>>>(fW1h, V3xT,
                                              (const f16*)(prm+P_SCE3H), (const f16*)(prm+P_SHE3H),
                                              u1, prm+P_U0, P1, prm+P_FTOT, out6T, pF);
    k_finalize_f<<<4,256,0,stream>>>(pF, fg1, fb1, prm+P_SCF1, prm+P_SHF1,
                                     (f16*)(prm+P_SCF1H), (f16*)(prm+P_SHF1H));
    k_mfma_fw2T<<<dim3(4,512),256,0,stream>>>(fW2h, out6T,
                                              (const f16*)(prm+P_SCF1H), (const f16*)(prm+P_SHF1H),
                                              fbias2, out7);

    // ---- d-path ----
    k_mfma_d1<<<dim3(4,512),256,0,stream>>>(dW1h, out7, d1p, pD1);
    k_finalize_d1<<<1,256,0,stream>>>(pD1, dg1, db1, prm+P_SCD1, prm+P_SHD1);
    k_gemm_d2<<<dim3(8,512),128,0,stream>>>(dW2, d1p, prm+P_SCD1, prm+P_SHD1, d2p, pD2);
    k_finalize_d2<<<1,256,0,stream>>>(pD2, dg2, db2, prm+P_SCD2, prm+P_SHD2);
    k_d3<<<1024,256,0,stream>>>(d2p, dW3, prm+P_SCD2, prm+P_SHD2, dbias3, out);
}